// Round 1
// baseline (4584.002 us; speedup 1.0000x reference)
//
#include <hip/hip_runtime.h>

constexpr int B_  = 8;
constexpr int N_  = 4096;
constexpr int NP1 = 512;
constexpr int NP2 = 256;
constexpr float EPS_ = 1e-5f;

// stats layout (floats): [sum, sumsq] pairs per stage
constexpr int S_BN1 = 0;      // 64+64
constexpr int S_BN2 = 128;    // 64+64
constexpr int S_L0A = 256;    // 128+128
constexpr int S_L0B = 512;    // 128+128
constexpr int S_L1A = 768;    // 256+256
constexpr int S_L1B = 1280;   // 256+256
constexpr int S_TOTAL = 1792;

// ws layout (float offsets)
constexpr size_t OFF_T1   = 0;                          // 2,097,152  (t1; later 'pts')
constexpr size_t OFF_YBUF = OFF_T1   + 2097152;         // 16,777,216 (t2 aliases start)
constexpr size_t OFF_PTS1 = OFF_YBUF + 16777216;        // 524,288
constexpr size_t OFF_NXYZ = OFF_PTS1 + 524288;          // 12,288
constexpr size_t OFF_WT0A = OFF_NXYZ + 12288;           // 16,384
constexpr size_t OFF_WT0B = OFF_WT0A + 16384;           // 16,384
constexpr size_t OFF_WT1A = OFF_WT0B + 16384;           // 65,536
constexpr size_t OFF_WT1B = OFF_WT1A + 65536;           // 65,536
constexpr size_t OFF_WT2C = OFF_WT1B + 65536;           // 4,096
constexpr size_t OFF_STAT = OFF_WT2C + 4096;            // 1,792
constexpr size_t OFF_INT  = OFF_STAT + 1792;            // ints from here

// ---------------- weight transposes (w[o][d] -> wt[d][o]) ----------------
__global__ void wtrans_kernel(const float* __restrict__ le0w1, const float* __restrict__ le0w2,
                              const float* __restrict__ le1w1, const float* __restrict__ le1w2,
                              const float* __restrict__ conv2w,
                              float* __restrict__ wt0a, float* __restrict__ wt0b,
                              float* __restrict__ wt1a, float* __restrict__ wt1b,
                              float* __restrict__ wt2c) {
  int idx = blockIdx.x * 256 + threadIdx.x;
  if (idx < 16384)       { int i = idx;          int d = i >> 7, o = i & 127; wt0a[i] = le0w1[o*128 + d]; }
  else if (idx < 32768)  { int i = idx - 16384;  int d = i >> 7, o = i & 127; wt0b[i] = le0w2[o*128 + d]; }
  else if (idx < 98304)  { int i = idx - 32768;  int d = i >> 8, o = i & 255; wt1a[i] = le1w1[o*256 + d]; }
  else if (idx < 163840) { int i = idx - 98304;  int d = i >> 8, o = i & 255; wt1b[i] = le1w2[o*256 + d]; }
  else if (idx < 167936) { int i = idx - 163840; int d = i >> 6, o = i & 63;  wt2c[i] = conv2w[o*64 + d]; }
}

// ---------------- conv1 (3->64) + bn1 stats ----------------
__global__ __launch_bounds__(256) void conv1_kernel(
    const float* __restrict__ x, const float* __restrict__ w,
    float* __restrict__ t1, float* __restrict__ stats) {
  __shared__ float xs[3][64];
  __shared__ float redS[4][64], redQ[4][64];
  int blk = blockIdx.x;
  int b = blk >> 6, n0 = (blk & 63) << 6;
  int t = threadIdx.x;
  if (t < 192) { int c = t >> 6, nl = t & 63; xs[c][nl] = x[((size_t)b*3 + c)*N_ + n0 + nl]; }
  __syncthreads();
  int o = t & 63, ng = t >> 6;
  float w0 = w[o*3+0], w1 = w[o*3+1], w2 = w[o*3+2];
  float ls = 0.f, lq = 0.f;
#pragma unroll
  for (int k = 0; k < 16; ++k) {
    int nl = ng*16 + k;
    float y = xs[0][nl]*w0 + xs[1][nl]*w1 + xs[2][nl]*w2;
    t1[((size_t)b*N_ + n0 + nl)*64 + o] = y;
    ls += y; lq += y*y;
  }
  redS[ng][o] = ls; redQ[ng][o] = lq;
  __syncthreads();
  if (t < 64) {
    float s = redS[0][t]+redS[1][t]+redS[2][t]+redS[3][t];
    float q = redQ[0][t]+redQ[1][t]+redQ[2][t]+redQ[3][t];
    atomicAdd(&stats[S_BN1 + t], s);
    atomicAdd(&stats[S_BN1 + 64 + t], q);
  }
}

// ---------------- bn1+relu + conv2 (64->64) + bn2 stats ----------------
__global__ __launch_bounds__(256) void conv2_kernel(
    const float* __restrict__ t1, const float* __restrict__ g1, const float* __restrict__ b1,
    const float* __restrict__ wt2c, float* __restrict__ t2, float* __restrict__ stats) {
  constexpr int P = 68;
  __shared__ float at[64*P];
  __shared__ float sc[64], sh[64];
  __shared__ float redS[4][64], redQ[4][64];
  int blk = blockIdx.x;
  int b = blk >> 6, n0 = (blk & 63) << 6;
  int t = threadIdx.x;
  if (t < 64) {
    float m = stats[S_BN1 + t] * (1.f/32768.f);
    float v = stats[S_BN1 + 64 + t] * (1.f/32768.f) - m*m;
    float s = g1[t] * rsqrtf(v + EPS_);
    sc[t] = s; sh[t] = b1[t] - m*s;
  }
  __syncthreads();
  for (int e = t; e < 4096; e += 256) {
    int nl = e >> 6, c = e & 63;
    float v = t1[((size_t)b*N_ + n0 + nl)*64 + c];
    at[c*P + nl] = fmaxf(v*sc[c] + sh[c], 0.f);
  }
  __syncthreads();
  int o = t & 63, ng = t >> 6;
  float acc[16];
#pragma unroll
  for (int k = 0; k < 16; ++k) acc[k] = 0.f;
  for (int i = 0; i < 64; ++i) {
    float wv = wt2c[i*64 + o];
    const float* ar = &at[i*P + ng*16];
#pragma unroll
    for (int k = 0; k < 16; k += 4) {
      float4 a4 = *(const float4*)(ar + k);
      acc[k+0] += a4.x*wv; acc[k+1] += a4.y*wv;
      acc[k+2] += a4.z*wv; acc[k+3] += a4.w*wv;
    }
  }
  float ls = 0.f, lq = 0.f;
#pragma unroll
  for (int k = 0; k < 16; ++k) {
    float y = acc[k];
    t2[((size_t)b*N_ + n0 + ng*16 + k)*64 + o] = y;
    ls += y; lq += y*y;
  }
  redS[ng][o] = ls; redQ[ng][o] = lq;
  __syncthreads();
  if (t < 64) {
    float s = redS[0][t]+redS[1][t]+redS[2][t]+redS[3][t];
    float q = redQ[0][t]+redQ[1][t]+redQ[2][t]+redQ[3][t];
    atomicAdd(&stats[S_BN2 + t], s);
    atomicAdd(&stats[S_BN2 + 64 + t], q);
  }
}

// ---------------- bn2 finalize + relu -> pts ----------------
__global__ __launch_bounds__(256) void bn2fin_kernel(
    const float* __restrict__ t2, const float* __restrict__ g2, const float* __restrict__ b2,
    const float* __restrict__ stats, float* __restrict__ pts) {
  int idx = blockIdx.x*256 + threadIdx.x;
  int o = idx & 63;
  float m = stats[S_BN2 + o] * (1.f/32768.f);
  float v = stats[S_BN2 + 64 + o] * (1.f/32768.f) - m*m;
  float s = g2[o] * rsqrtf(v + EPS_);
  pts[idx] = fmaxf(t2[idx]*s + (b2[o] - m*s), 0.f);
}

// ---------------- farthest point sampling ----------------
// matches jax scan: sel[0]=0; sel[i] = argmax(dist_min) after update with centroid sel[i-1]
template<int NPTS, int NSEL, int NT, bool XLAY>
__global__ __launch_bounds__(NT) void fps_kernel(
    const float* __restrict__ coords, int* __restrict__ sel, float* __restrict__ selxyz) {
  constexpr int K = NPTS / NT;
  constexpr int NW = NT / 64;
  __shared__ float cent[3];
  __shared__ float wvs[NW]; __shared__ int wis[NW];
  int b = blockIdx.x, t = threadIdx.x;
  const float* cb = coords + (size_t)b * (XLAY ? 3*NPTS : NPTS*3);
  float px[K], py[K], pz[K], dm[K];
#pragma unroll
  for (int k = 0; k < K; ++k) {
    int p = t + k*NT;
    if (XLAY) { px[k] = cb[p]; py[k] = cb[NPTS + p]; pz[k] = cb[2*NPTS + p]; }
    else      { px[k] = cb[p*3]; py[k] = cb[p*3+1]; pz[k] = cb[p*3+2]; }
    dm[k] = 1e10f;
  }
  if (t == 0) {
    sel[(size_t)b*NSEL] = 0;
    float cx, cy, cz;
    if (XLAY) { cx = cb[0]; cy = cb[NPTS]; cz = cb[2*NPTS]; }
    else      { cx = cb[0]; cy = cb[1];    cz = cb[2]; }
    cent[0] = cx; cent[1] = cy; cent[2] = cz;
    if (selxyz) { float* sp = selxyz + (size_t)b*NSEL*3; sp[0]=cx; sp[1]=cy; sp[2]=cz; }
  }
  __syncthreads();
  int lane = t & 63, wid = t >> 6;
  for (int it = 1; it < NSEL; ++it) {
    float cx = cent[0], cy = cent[1], cz = cent[2];
    float bv = -1.f; int bi = 0x7fffffff;
#pragma unroll
    for (int k = 0; k < K; ++k) {
      float dx = px[k]-cx, dy = py[k]-cy, dz = pz[k]-cz;
      float d = dx*dx + dy*dy + dz*dz;
      float nd = fminf(dm[k], d);
      dm[k] = nd;
      if (nd > bv) { bv = nd; bi = t + k*NT; }   // k ascending => lowest index kept on tie
    }
#pragma unroll
    for (int off = 1; off < 64; off <<= 1) {
      float ov = __shfl_xor(bv, off);
      int   oi = __shfl_xor(bi, off);
      if (ov > bv || (ov == bv && oi < bi)) { bv = ov; bi = oi; }
    }
    if (lane == 0) { wvs[wid] = bv; wis[wid] = bi; }
    __syncthreads();
    if (t == 0) {
      float Bv = wvs[0]; int Bi = wis[0];
      for (int w = 1; w < NW; ++w)
        if (wvs[w] > Bv || (wvs[w] == Bv && wis[w] < Bi)) { Bv = wvs[w]; Bi = wis[w]; }
      sel[(size_t)b*NSEL + it] = Bi;
      float cx2, cy2, cz2;
      if (XLAY) { cx2 = cb[Bi]; cy2 = cb[NPTS + Bi]; cz2 = cb[2*NPTS + Bi]; }
      else      { cx2 = cb[Bi*3]; cy2 = cb[Bi*3+1]; cz2 = cb[Bi*3+2]; }
      cent[0] = cx2; cent[1] = cy2; cent[2] = cz2;
      if (selxyz) { float* sp = selxyz + ((size_t)b*NSEL + it)*3; sp[0]=cx2; sp[1]=cy2; sp[2]=cz2; }
    }
    __syncthreads();
  }
}

// ---------------- kNN (32 smallest d2, top_k-stable ties) ----------------
template<int NDST, int NQ, int NT, bool XLAY>
__global__ __launch_bounds__(NT) void knn_kernel(
    const float* __restrict__ dst, const float* __restrict__ nxyz,
    const int* __restrict__ qmap, int* __restrict__ knn_out) {
  constexpr int K = NDST / NT;
  constexpr int NW = NT / 64;
  __shared__ float d2s[NDST];
  __shared__ float wvs[NW]; __shared__ int wis[NW];
  int blk = blockIdx.x, t = threadIdx.x;
  int b = blk / NQ, q = blk % NQ;
  int qrow = b*NP1 + (qmap ? qmap[b*NQ + q] : q);
  float qx = nxyz[qrow*3+0], qy = nxyz[qrow*3+1], qz = nxyz[qrow*3+2];
  float q2 = (qx*qx + qy*qy) + qz*qz;
  const float* db = dst + (size_t)b * (XLAY ? 3*NDST : NDST*3);
#pragma unroll
  for (int k = 0; k < K; ++k) {
    int j = t + k*NT;
    float xx, yy, zz;
    if (XLAY) { xx = db[j]; yy = db[NDST + j]; zz = db[2*NDST + j]; }
    else      { xx = db[j*3]; yy = db[j*3+1]; zz = db[j*3+2]; }
    float dot = (qx*xx + qy*yy) + qz*zz;
    float p2  = (xx*xx + yy*yy) + zz*zz;
    d2s[j] = (q2 - 2.f*dot) + p2;   // same expansion as reference
  }
  __syncthreads();
  int lane = t & 63, wid = t >> 6;
  int* ko = knn_out + ((size_t)b*NQ + q)*32;
  for (int r = 0; r < 32; ++r) {
    float bv = 3e38f; int bi = NDST;
#pragma unroll
    for (int k = 0; k < K; ++k) {
      int j = t + k*NT;
      float v = d2s[j];
      if (v < bv || (v == bv && j < bi)) { bv = v; bi = j; }
    }
#pragma unroll
    for (int off = 1; off < 64; off <<= 1) {
      float ov = __shfl_xor(bv, off);
      int   oi = __shfl_xor(bi, off);
      if (ov < bv || (ov == bv && oi < bi)) { bv = ov; bi = oi; }
    }
    if (lane == 0) { wvs[wid] = bv; wis[wid] = bi; }
    __syncthreads();
    if (t == 0) {
      float Bv = wvs[0]; int Bi = wis[0];
      for (int w = 1; w < NW; ++w)
        if (wvs[w] < Bv || (wvs[w] == Bv && wis[w] < Bi)) { Bv = wvs[w]; Bi = wis[w]; }
      ko[r] = Bi;
      d2s[Bi] = 3e38f;
    }
    __syncthreads();
  }
}

// ---------------- local encoder layer 1: gather feat + matmul + stats ----------------
template<int DIN, int NP, int SRCN, int PW, int SOFF>
__global__ __launch_bounds__(256) void le1_kernel(
    const float* __restrict__ pts, const int* __restrict__ knn,
    const int* __restrict__ cent, const float* __restrict__ wt,
    float* __restrict__ ybuf, float* __restrict__ stats) {
  constexpr int P = DIN + 4;
  __shared__ float feat[32*P];
  __shared__ float cen[PW];
  __shared__ int kid[32];
  int blk = blockIdx.x, t = threadIdx.x;
  int b = blk / NP, n = blk % NP;
  const float* base = pts + (size_t)b*SRCN*PW;
  if (t < 32) kid[t] = knn[((size_t)b*NP + n)*32 + t];
  int ci = cent[b*NP + n];
  for (int j = t; j < PW; j += 256) cen[j] = base[(size_t)ci*PW + j];
  __syncthreads();
  for (int e = t; e < 32*DIN; e += 256) {
    int s = e / DIN, d = e % DIN;
    float v = (d < PW) ? (base[(size_t)kid[s]*PW + d] - cen[d]) : cen[d - PW];
    feat[s*P + d] = v;
  }
  __syncthreads();
  int og = t >> 5, s = t & 31;
  float* yb = ybuf + ((size_t)b*NP + n)*DIN*32;
  const float* fr = &feat[s*P];
  for (int p = 0; p < DIN/32; ++p) {
    int o0 = og*4 + p*32;
    float a0=0.f, a1=0.f, a2=0.f, a3=0.f;
    const float* wp = wt + o0;
    for (int d = 0; d < DIN; d += 4) {
      float4 f  = *(const float4*)(fr + d);
      float4 w0 = *(const float4*)(wp + (size_t)(d+0)*DIN);
      float4 w1 = *(const float4*)(wp + (size_t)(d+1)*DIN);
      float4 w2 = *(const float4*)(wp + (size_t)(d+2)*DIN);
      float4 w3 = *(const float4*)(wp + (size_t)(d+3)*DIN);
      a0 += f.x*w0.x + f.y*w1.x + f.z*w2.x + f.w*w3.x;
      a1 += f.x*w0.y + f.y*w1.y + f.z*w2.y + f.w*w3.y;
      a2 += f.x*w0.z + f.y*w1.z + f.z*w2.z + f.w*w3.z;
      a3 += f.x*w0.w + f.y*w1.w + f.z*w2.w + f.w*w3.w;
    }
    yb[(o0+0)*32 + s] = a0;
    yb[(o0+1)*32 + s] = a1;
    yb[(o0+2)*32 + s] = a2;
    yb[(o0+3)*32 + s] = a3;
    float s0=a0,s1=a1,s2=a2,s3=a3;
    float q0=a0*a0,q1=a1*a1,q2=a2*a2,q3=a3*a3;
#pragma unroll
    for (int off = 16; off >= 1; off >>= 1) {
      s0 += __shfl_xor(s0, off); q0 += __shfl_xor(q0, off);
      s1 += __shfl_xor(s1, off); q1 += __shfl_xor(q1, off);
      s2 += __shfl_xor(s2, off); q2 += __shfl_xor(q2, off);
      s3 += __shfl_xor(s3, off); q3 += __shfl_xor(q3, off);
    }
    if (s == 0) {
      atomicAdd(&stats[SOFF + o0+0], s0); atomicAdd(&stats[SOFF + DIN + o0+0], q0);
      atomicAdd(&stats[SOFF + o0+1], s1); atomicAdd(&stats[SOFF + DIN + o0+1], q1);
      atomicAdd(&stats[SOFF + o0+2], s2); atomicAdd(&stats[SOFF + DIN + o0+2], q2);
      atomicAdd(&stats[SOFF + o0+3], s3); atomicAdd(&stats[SOFF + DIN + o0+3], q3);
    }
  }
}

// ---------------- local encoder layer 2: bn1+relu + matmul (in-place) + stats ----------------
template<int D, int NP, int SIN, int SOUT, int CNT>
__global__ __launch_bounds__(256) void le2_kernel(
    const float* __restrict__ g1, const float* __restrict__ b1,
    const float* __restrict__ wt, float* __restrict__ ybuf, float* __restrict__ stats) {
  constexpr int P = D + 4;
  __shared__ float at[32*P];     // act^T : at[s][i]
  __shared__ float sc[D], sh[D];
  int blk = blockIdx.x, t = threadIdx.x;
  int b = blk / NP, n = blk % NP;
  for (int i = t; i < D; i += 256) {
    float m = stats[SIN + i] * (1.f/(float)CNT);
    float v = stats[SIN + D + i] * (1.f/(float)CNT) - m*m;
    float s = g1[i] * rsqrtf(v + EPS_);
    sc[i] = s; sh[i] = b1[i] - m*s;
  }
  __syncthreads();
  float* yb = ybuf + ((size_t)b*NP + n)*D*32;
  for (int e = t; e < D*32; e += 256) {
    int i = e >> 5, s = e & 31;
    at[s*P + i] = fmaxf(yb[e]*sc[i] + sh[i], 0.f);
  }
  __syncthreads();
  int og = t >> 5, s = t & 31;
  const float* fr = &at[s*P];
  for (int p = 0; p < D/32; ++p) {
    int o0 = og*4 + p*32;
    float a0=0.f, a1=0.f, a2=0.f, a3=0.f;
    const float* wp = wt + o0;
    for (int d = 0; d < D; d += 4) {
      float4 f  = *(const float4*)(fr + d);
      float4 w0 = *(const float4*)(wp + (size_t)(d+0)*D);
      float4 w1 = *(const float4*)(wp + (size_t)(d+1)*D);
      float4 w2 = *(const float4*)(wp + (size_t)(d+2)*D);
      float4 w3 = *(const float4*)(wp + (size_t)(d+3)*D);
      a0 += f.x*w0.x + f.y*w1.x + f.z*w2.x + f.w*w3.x;
      a1 += f.x*w0.y + f.y*w1.y + f.z*w2.y + f.w*w3.y;
      a2 += f.x*w0.z + f.y*w1.z + f.z*w2.z + f.w*w3.z;
      a3 += f.x*w0.w + f.y*w1.w + f.z*w2.w + f.w*w3.w;
    }
    yb[(o0+0)*32 + s] = a0;
    yb[(o0+1)*32 + s] = a1;
    yb[(o0+2)*32 + s] = a2;
    yb[(o0+3)*32 + s] = a3;
    float s0=a0,s1=a1,s2=a2,s3=a3;
    float q0=a0*a0,q1=a1*a1,q2=a2*a2,q3=a3*a3;
#pragma unroll
    for (int off = 16; off >= 1; off >>= 1) {
      s0 += __shfl_xor(s0, off); q0 += __shfl_xor(q0, off);
      s1 += __shfl_xor(s1, off); q1 += __shfl_xor(q1, off);
      s2 += __shfl_xor(s2, off); q2 += __shfl_xor(q2, off);
      s3 += __shfl_xor(s3, off); q3 += __shfl_xor(q3, off);
    }
    if (s == 0) {
      atomicAdd(&stats[SOUT + o0+0], s0); atomicAdd(&stats[SOUT + D + o0+0], q0);
      atomicAdd(&stats[SOUT + o0+1], s1); atomicAdd(&stats[SOUT + D + o0+1], q1);
      atomicAdd(&stats[SOUT + o0+2], s2); atomicAdd(&stats[SOUT + D + o0+2], q2);
      atomicAdd(&stats[SOUT + o0+3], s3); atomicAdd(&stats[SOUT + D + o0+3], q3);
    }
  }
}

// ---------------- local encoder finish: bn2+relu + max over s (+optional transpose out) ----------------
template<int D, int NP, int SOFF, int CNT, bool TR>
__global__ void le3_kernel(const float* __restrict__ g2, const float* __restrict__ b2,
                           const float* __restrict__ ybuf, const float* __restrict__ stats,
                           float* __restrict__ out) {
  int blk = blockIdx.x, o = threadIdx.x;   // blockDim == D
  int b = blk / NP, n = blk % NP;
  float m = stats[SOFF + o] * (1.f/(float)CNT);
  float v = stats[SOFF + D + o] * (1.f/(float)CNT) - m*m;
  float s = g2[o] * rsqrtf(v + EPS_);
  float sh = b2[o] - m*s;
  const float* yb = ybuf + (((size_t)b*NP + n)*D + o)*32;
  float mx = 0.f;  // relu floor
#pragma unroll
  for (int k = 0; k < 32; ++k) mx = fmaxf(mx, yb[k]*s + sh);
  if (TR) out[((size_t)b*D + o)*NP + n] = mx;
  else    out[((size_t)b*NP + n)*D + o] = mx;
}

// ---------------- host ----------------
extern "C" void kernel_launch(void* const* d_in, const int* in_sizes, int n_in,
                              void* d_out, int out_size, void* d_ws, size_t ws_size,
                              hipStream_t stream) {
  (void)in_sizes; (void)n_in; (void)out_size; (void)ws_size;
  const float* x       = (const float*)d_in[0];
  const float* conv1_w = (const float*)d_in[1];
  const float* bn1_g   = (const float*)d_in[2];
  const float* bn1_b   = (const float*)d_in[3];
  const float* conv2_w = (const float*)d_in[4];
  const float* bn2_g   = (const float*)d_in[5];
  const float* bn2_b   = (const float*)d_in[6];
  const float* le0_w1  = (const float*)d_in[7];
  const float* le0_g1  = (const float*)d_in[8];
  const float* le0_b1  = (const float*)d_in[9];
  const float* le0_w2  = (const float*)d_in[10];
  const float* le0_g2  = (const float*)d_in[11];
  const float* le0_b2  = (const float*)d_in[12];
  const float* le1_w1  = (const float*)d_in[13];
  const float* le1_g1  = (const float*)d_in[14];
  const float* le1_b1  = (const float*)d_in[15];
  const float* le1_w2  = (const float*)d_in[16];
  const float* le1_g2  = (const float*)d_in[17];
  const float* le1_b2  = (const float*)d_in[18];

  float* ws   = (float*)d_ws;
  float* t1   = ws + OFF_T1;      // conv1 out; later overwritten with 'pts' (bn2 output)
  float* ybuf = ws + OFF_YBUF;    // LE y buffer; t2 aliases its start
  float* t2   = ybuf;
  float* pts1 = ws + OFF_PTS1;
  float* nxyz = ws + OFF_NXYZ;
  float* wt0a = ws + OFF_WT0A;
  float* wt0b = ws + OFF_WT0B;
  float* wt1a = ws + OFF_WT1A;
  float* wt1b = ws + OFF_WT1B;
  float* wt2c = ws + OFF_WT2C;
  float* stats = ws + OFF_STAT;
  int* fps1 = (int*)(ws + OFF_INT);
  int* fps2 = fps1 + 4096;
  int* knn1 = fps2 + 2048;
  int* knn2 = knn1 + 131072;

  hipMemsetAsync(stats, 0, S_TOTAL*sizeof(float), stream);
  wtrans_kernel<<<656, 256, 0, stream>>>(le0_w1, le0_w2, le1_w1, le1_w2, conv2_w,
                                         wt0a, wt0b, wt1a, wt1b, wt2c);
  conv1_kernel<<<512, 256, 0, stream>>>(x, conv1_w, t1, stats);
  conv2_kernel<<<512, 256, 0, stream>>>(t1, bn1_g, bn1_b, wt2c, t2, stats);
  bn2fin_kernel<<<8192, 256, 0, stream>>>(t2, bn2_g, bn2_b, stats, t1);  // pts -> t1 region

  fps_kernel<4096, 512, 512, true ><<<8, 512, 0, stream>>>(x, fps1, nxyz);
  knn_kernel<4096, 512, 256, true ><<<4096, 256, 0, stream>>>(x, nxyz, nullptr, knn1);
  fps_kernel< 512, 256, 256, false><<<8, 256, 0, stream>>>(nxyz, fps2, nullptr);
  knn_kernel< 512, 256, 256, false><<<2048, 256, 0, stream>>>(nxyz, nxyz, fps2, knn2);

  le1_kernel<128, 512, 4096,  64, S_L0A><<<4096, 256, 0, stream>>>(t1, knn1, fps1, wt0a, ybuf, stats);
  le2_kernel<128, 512, S_L0A, S_L0B, 131072><<<4096, 256, 0, stream>>>(le0_g1, le0_b1, wt0b, ybuf, stats);
  le3_kernel<128, 512, S_L0B, 131072, false><<<4096, 128, 0, stream>>>(le0_g2, le0_b2, ybuf, stats, pts1);

  le1_kernel<256, 256,  512, 128, S_L1A><<<2048, 256, 0, stream>>>(pts1, knn2, fps2, wt1a, ybuf, stats);
  le2_kernel<256, 256, S_L1A, S_L1B, 65536><<<2048, 256, 0, stream>>>(le1_g1, le1_b1, wt1b, ybuf, stats);
  le3_kernel<256, 256, S_L1B, 65536, true><<<2048, 256, 0, stream>>>(le1_g2, le1_b2, ybuf, stats, (float*)d_out);
}

// Round 2
// 1628.691 us; speedup vs baseline: 2.8145x; 2.8145x over previous
//
#include <hip/hip_runtime.h>

constexpr int B_  = 8;
constexpr int N_  = 4096;
constexpr int NP1 = 512;
constexpr int NP2 = 256;
constexpr float EPS_ = 1e-5f;

typedef __attribute__((ext_vector_type(8))) short bhalf8;
typedef __attribute__((ext_vector_type(4))) float f32x4;

__device__ inline short f2bf(float f) {
  union { float fv; unsigned u; } v; v.fv = f;
  unsigned r = v.u + 0x7FFFu + ((v.u >> 16) & 1u);
  return (short)(r >> 16);
}

// stats layout (floats): [sum, sumsq] pairs per stage
constexpr int S_BN1 = 0;      // 64+64
constexpr int S_BN2 = 128;    // 64+64
constexpr int S_L0A = 256;    // 128+128
constexpr int S_L0B = 512;    // 128+128
constexpr int S_L1A = 768;    // 256+256
constexpr int S_L1B = 1280;   // 256+256
constexpr int S_TOTAL = 1792;

// ws layout (float offsets)
constexpr size_t OFF_T1   = 0;                          // 2,097,152  (t1; later 'pts')
constexpr size_t OFF_YBUF = OFF_T1   + 2097152;         // 16,777,216 (t2 aliases start)
constexpr size_t OFF_PTS1 = OFF_YBUF + 16777216;        // 524,288
constexpr size_t OFF_NXYZ = OFF_PTS1 + 524288;          // 12,288
constexpr size_t OFF_WT2C = OFF_NXYZ + 12288;           // 4,096
constexpr size_t OFF_BW0A = OFF_WT2C + 4096;            // 8,192 floats (128*128 bf16)
constexpr size_t OFF_BW0B = OFF_BW0A + 8192;            // 8,192
constexpr size_t OFF_BW1A = OFF_BW0B + 8192;            // 32,768 (256*256 bf16)
constexpr size_t OFF_BW1B = OFF_BW1A + 32768;           // 32,768
constexpr size_t OFF_STAT = OFF_BW1B + 32768;           // 1,792
constexpr size_t OFF_INT  = OFF_STAT + 1792;            // ints from here

// ---------------- weight prep: conv2 transpose + bf16 fragment-order weights ----------------
// bf16 layout: dst[(kblk*D + o)*8 + j] = bf16(w[o][kblk*8+j])  (16B per (kblk,o) = one B-frag lane chunk)
__global__ void prep_kernel(const float* __restrict__ conv2w,
                            const float* __restrict__ w0a, const float* __restrict__ w0b,
                            const float* __restrict__ w1a, const float* __restrict__ w1b,
                            float* __restrict__ wt2c,
                            short* __restrict__ b0a, short* __restrict__ b0b,
                            short* __restrict__ b1a, short* __restrict__ b1b) {
  int idx = blockIdx.x * 256 + threadIdx.x;
  if (idx < 4096) { int d = idx >> 6, o = idx & 63; wt2c[idx] = conv2w[o*64 + d]; return; }
  idx -= 4096;
  const float* w; short* dst; int D;
  if      (idx <  2048) { w = w0a; dst = b0a; D = 128; }
  else if (idx <  4096) { w = w0b; dst = b0b; D = 128; idx -= 2048; }
  else if (idx < 12288) { w = w1a; dst = b1a; D = 256; idx -= 4096; }
  else if (idx < 20480) { w = w1b; dst = b1b; D = 256; idx -= 12288; }
  else return;
  int kblk = idx / D, o = idx % D;
  const float* src = w + (size_t)o*D + kblk*8;
  bhalf8 pk;
#pragma unroll
  for (int j = 0; j < 8; ++j) pk[j] = f2bf(src[j]);
  *(bhalf8*)&dst[(size_t)idx*8] = pk;
}

// ---------------- conv1 (3->64) + bn1 stats ----------------
__global__ __launch_bounds__(256) void conv1_kernel(
    const float* __restrict__ x, const float* __restrict__ w,
    float* __restrict__ t1, float* __restrict__ stats) {
  __shared__ float xs[3][64];
  __shared__ float redS[4][64], redQ[4][64];
  int blk = blockIdx.x;
  int b = blk >> 6, n0 = (blk & 63) << 6;
  int t = threadIdx.x;
  if (t < 192) { int c = t >> 6, nl = t & 63; xs[c][nl] = x[((size_t)b*3 + c)*N_ + n0 + nl]; }
  __syncthreads();
  int o = t & 63, ng = t >> 6;
  float w0 = w[o*3+0], w1 = w[o*3+1], w2 = w[o*3+2];
  float ls = 0.f, lq = 0.f;
#pragma unroll
  for (int k = 0; k < 16; ++k) {
    int nl = ng*16 + k;
    float y = xs[0][nl]*w0 + xs[1][nl]*w1 + xs[2][nl]*w2;
    t1[((size_t)b*N_ + n0 + nl)*64 + o] = y;
    ls += y; lq += y*y;
  }
  redS[ng][o] = ls; redQ[ng][o] = lq;
  __syncthreads();
  if (t < 64) {
    float s = redS[0][t]+redS[1][t]+redS[2][t]+redS[3][t];
    float q = redQ[0][t]+redQ[1][t]+redQ[2][t]+redQ[3][t];
    atomicAdd(&stats[S_BN1 + t], s);
    atomicAdd(&stats[S_BN1 + 64 + t], q);
  }
}

// ---------------- bn1+relu + conv2 (64->64) + bn2 stats ----------------
__global__ __launch_bounds__(256) void conv2_kernel(
    const float* __restrict__ t1, const float* __restrict__ g1, const float* __restrict__ b1,
    const float* __restrict__ wt2c, float* __restrict__ t2, float* __restrict__ stats) {
  constexpr int P = 68;
  __shared__ float at[64*P];
  __shared__ float sc[64], sh[64];
  __shared__ float redS[4][64], redQ[4][64];
  int blk = blockIdx.x;
  int b = blk >> 6, n0 = (blk & 63) << 6;
  int t = threadIdx.x;
  if (t < 64) {
    float m = stats[S_BN1 + t] * (1.f/32768.f);
    float v = stats[S_BN1 + 64 + t] * (1.f/32768.f) - m*m;
    float s = g1[t] * rsqrtf(v + EPS_);
    sc[t] = s; sh[t] = b1[t] - m*s;
  }
  __syncthreads();
  for (int e = t; e < 4096; e += 256) {
    int nl = e >> 6, c = e & 63;
    float v = t1[((size_t)b*N_ + n0 + nl)*64 + c];
    at[c*P + nl] = fmaxf(v*sc[c] + sh[c], 0.f);
  }
  __syncthreads();
  int o = t & 63, ng = t >> 6;
  float acc[16];
#pragma unroll
  for (int k = 0; k < 16; ++k) acc[k] = 0.f;
  for (int i = 0; i < 64; ++i) {
    float wv = wt2c[i*64 + o];
    const float* ar = &at[i*P + ng*16];
#pragma unroll
    for (int k = 0; k < 16; k += 4) {
      float4 a4 = *(const float4*)(ar + k);
      acc[k+0] += a4.x*wv; acc[k+1] += a4.y*wv;
      acc[k+2] += a4.z*wv; acc[k+3] += a4.w*wv;
    }
  }
  float ls = 0.f, lq = 0.f;
#pragma unroll
  for (int k = 0; k < 16; ++k) {
    float y = acc[k];
    t2[((size_t)b*N_ + n0 + ng*16 + k)*64 + o] = y;
    ls += y; lq += y*y;
  }
  redS[ng][o] = ls; redQ[ng][o] = lq;
  __syncthreads();
  if (t < 64) {
    float s = redS[0][t]+redS[1][t]+redS[2][t]+redS[3][t];
    float q = redQ[0][t]+redQ[1][t]+redQ[2][t]+redQ[3][t];
    atomicAdd(&stats[S_BN2 + t], s);
    atomicAdd(&stats[S_BN2 + 64 + t], q);
  }
}

// ---------------- bn2 finalize + relu -> pts ----------------
__global__ __launch_bounds__(256) void bn2fin_kernel(
    const float* __restrict__ t2, const float* __restrict__ g2, const float* __restrict__ b2,
    const float* __restrict__ stats, float* __restrict__ pts) {
  int idx = blockIdx.x*256 + threadIdx.x;
  int o = idx & 63;
  float m = stats[S_BN2 + o] * (1.f/32768.f);
  float v = stats[S_BN2 + 64 + o] * (1.f/32768.f) - m*m;
  float s = g2[o] * rsqrtf(v + EPS_);
  pts[idx] = fmaxf(t2[idx]*s + (b2[o] - m*s), 0.f);
}

// ---------------- farthest point sampling ----------------
template<int NPTS, int NSEL, int NT, bool XLAY>
__global__ __launch_bounds__(NT) void fps_kernel(
    const float* __restrict__ coords, int* __restrict__ sel, float* __restrict__ selxyz) {
  constexpr int K = NPTS / NT;
  constexpr int NW = NT / 64;
  __shared__ float cent[3];
  __shared__ float wvs[NW]; __shared__ int wis[NW];
  int b = blockIdx.x, t = threadIdx.x;
  const float* cb = coords + (size_t)b * (XLAY ? 3*NPTS : NPTS*3);
  float px[K], py[K], pz[K], dm[K];
#pragma unroll
  for (int k = 0; k < K; ++k) {
    int p = t + k*NT;
    if (XLAY) { px[k] = cb[p]; py[k] = cb[NPTS + p]; pz[k] = cb[2*NPTS + p]; }
    else      { px[k] = cb[p*3]; py[k] = cb[p*3+1]; pz[k] = cb[p*3+2]; }
    dm[k] = 1e10f;
  }
  if (t == 0) {
    sel[(size_t)b*NSEL] = 0;
    float cx, cy, cz;
    if (XLAY) { cx = cb[0]; cy = cb[NPTS]; cz = cb[2*NPTS]; }
    else      { cx = cb[0]; cy = cb[1];    cz = cb[2]; }
    cent[0] = cx; cent[1] = cy; cent[2] = cz;
    if (selxyz) { float* sp = selxyz + (size_t)b*NSEL*3; sp[0]=cx; sp[1]=cy; sp[2]=cz; }
  }
  __syncthreads();
  int lane = t & 63, wid = t >> 6;
  for (int it = 1; it < NSEL; ++it) {
    float cx = cent[0], cy = cent[1], cz = cent[2];
    float bv = -1.f; int bi = 0x7fffffff;
#pragma unroll
    for (int k = 0; k < K; ++k) {
      float dx = px[k]-cx, dy = py[k]-cy, dz = pz[k]-cz;
      float d = dx*dx + dy*dy + dz*dz;
      float nd = fminf(dm[k], d);
      dm[k] = nd;
      if (nd > bv) { bv = nd; bi = t + k*NT; }
    }
#pragma unroll
    for (int off = 1; off < 64; off <<= 1) {
      float ov = __shfl_xor(bv, off);
      int   oi = __shfl_xor(bi, off);
      if (ov > bv || (ov == bv && oi < bi)) { bv = ov; bi = oi; }
    }
    if (lane == 0) { wvs[wid] = bv; wis[wid] = bi; }
    __syncthreads();
    if (t == 0) {
      float Bv = wvs[0]; int Bi = wis[0];
      for (int w = 1; w < NW; ++w)
        if (wvs[w] > Bv || (wvs[w] == Bv && wis[w] < Bi)) { Bv = wvs[w]; Bi = wis[w]; }
      sel[(size_t)b*NSEL + it] = Bi;
      float cx2, cy2, cz2;
      if (XLAY) { cx2 = cb[Bi]; cy2 = cb[NPTS + Bi]; cz2 = cb[2*NPTS + Bi]; }
      else      { cx2 = cb[Bi*3]; cy2 = cb[Bi*3+1]; cz2 = cb[Bi*3+2]; }
      cent[0] = cx2; cent[1] = cy2; cent[2] = cz2;
      if (selxyz) { float* sp = selxyz + ((size_t)b*NSEL + it)*3; sp[0]=cx2; sp[1]=cy2; sp[2]=cz2; }
    }
    __syncthreads();
  }
}

// ---------------- kNN (32 smallest d2, top_k-stable ties) ----------------
template<int NDST, int NQ, int NT, bool XLAY>
__global__ __launch_bounds__(NT) void knn_kernel(
    const float* __restrict__ dst, const float* __restrict__ nxyz,
    const int* __restrict__ qmap, int* __restrict__ knn_out) {
  constexpr int K = NDST / NT;
  constexpr int NW = NT / 64;
  __shared__ float d2s[NDST];
  __shared__ float wvs[NW]; __shared__ int wis[NW];
  int blk = blockIdx.x, t = threadIdx.x;
  int b = blk / NQ, q = blk % NQ;
  int qrow = b*NP1 + (qmap ? qmap[b*NQ + q] : q);
  float qx = nxyz[qrow*3+0], qy = nxyz[qrow*3+1], qz = nxyz[qrow*3+2];
  float q2 = (qx*qx + qy*qy) + qz*qz;
  const float* db = dst + (size_t)b * (XLAY ? 3*NDST : NDST*3);
#pragma unroll
  for (int k = 0; k < K; ++k) {
    int j = t + k*NT;
    float xx, yy, zz;
    if (XLAY) { xx = db[j]; yy = db[NDST + j]; zz = db[2*NDST + j]; }
    else      { xx = db[j*3]; yy = db[j*3+1]; zz = db[j*3+2]; }
    float dot = (qx*xx + qy*yy) + qz*zz;
    float p2  = (xx*xx + yy*yy) + zz*zz;
    d2s[j] = (q2 - 2.f*dot) + p2;
  }
  __syncthreads();
  int lane = t & 63, wid = t >> 6;
  int* ko = knn_out + ((size_t)b*NQ + q)*32;
  for (int r = 0; r < 32; ++r) {
    float bv = 3e38f; int bi = NDST;
#pragma unroll
    for (int k = 0; k < K; ++k) {
      int j = t + k*NT;
      float v = d2s[j];
      if (v < bv || (v == bv && j < bi)) { bv = v; bi = j; }
    }
#pragma unroll
    for (int off = 1; off < 64; off <<= 1) {
      float ov = __shfl_xor(bv, off);
      int   oi = __shfl_xor(bi, off);
      if (ov < bv || (ov == bv && oi < bi)) { bv = ov; bi = oi; }
    }
    if (lane == 0) { wvs[wid] = bv; wis[wid] = bi; }
    __syncthreads();
    if (t == 0) {
      float Bv = wvs[0]; int Bi = wis[0];
      for (int w = 1; w < NW; ++w)
        if (wvs[w] < Bv || (wvs[w] == Bv && wis[w] < Bi)) { Bv = wvs[w]; Bi = wis[w]; }
      ko[r] = Bi;
      d2s[Bi] = 3e38f;
    }
    __syncthreads();
  }
}

// ---------------- GEMM1: gather(+center-sub) -> bf16 MFMA -> y + stats ----------------
// Y[M x D] = A[M x D] * W[D x D]; M rows = (b,n,s) flat; block = 64 rows (2 n-groups).
// A staged in LDS, bf16, XOR-swizzled 16B blocks. B read direct from prepped global bf16.
template<int D, int PW, int NP, int SRCN, int SOFF>
__global__ __launch_bounds__(256) void gemm1_kernel(
    const float* __restrict__ pts, const int* __restrict__ knn,
    const int* __restrict__ cent, const short* __restrict__ bw,
    float* __restrict__ ybuf, float* __restrict__ stats) {
  constexpr int KB = D/8;
  __shared__ __align__(16) short As[64*D];
  __shared__ float cen_s[2*PW];
  __shared__ int kid_s[64];
  __shared__ float sstat[2*D];
  int t = threadIdx.x, blk = blockIdx.x;
  int g0 = blk*2;
  if (t < 64) {
    int grp = t >> 5, s = t & 31;
    kid_s[t] = knn[((size_t)(g0+grp))*32 + s];
  }
  for (int i = t; i < 2*PW; i += 256) {
    int grp = i / PW, d = i % PW;
    int g = g0 + grp; int b = g / NP; int ci = cent[g];
    cen_s[i] = pts[((size_t)b*SRCN + ci)*PW + d];
  }
  for (int i = t; i < 2*D; i += 256) sstat[i] = 0.f;
  __syncthreads();
  // stage A (gather + center concat), bf16 swizzled
  for (int task = t; task < 64*KB; task += 256) {
    int row = task / KB, c = task % KB;
    int grp = row >> 5;
    int g = g0 + grp; int b = g / NP;
    int d = c*8;
    float v0,v1,v2,v3,v4,v5,v6,v7;
    if (d < PW) {
      const float* src = pts + ((size_t)b*SRCN + kid_s[row])*PW + d;
      float4 x0 = *(const float4*)src, x1 = *(const float4*)(src+4);
      const float* cc = &cen_s[grp*PW + d];
      v0=x0.x-cc[0]; v1=x0.y-cc[1]; v2=x0.z-cc[2]; v3=x0.w-cc[3];
      v4=x1.x-cc[4]; v5=x1.y-cc[5]; v6=x1.z-cc[6]; v7=x1.w-cc[7];
    } else {
      const float* cc = &cen_s[grp*PW + d - PW];
      v0=cc[0]; v1=cc[1]; v2=cc[2]; v3=cc[3]; v4=cc[4]; v5=cc[5]; v6=cc[6]; v7=cc[7];
    }
    bhalf8 pk;
    pk[0]=f2bf(v0); pk[1]=f2bf(v1); pk[2]=f2bf(v2); pk[3]=f2bf(v3);
    pk[4]=f2bf(v4); pk[5]=f2bf(v5); pk[6]=f2bf(v6); pk[7]=f2bf(v7);
    int a16 = row*KB + (c ^ (row & 7));
    *(bhalf8*)&As[a16*8] = pk;
  }
  __syncthreads();
  int w = t >> 6, l = t & 63, lr = l & 15, lg = l >> 4;
  f32x4 acc[D/16];
#pragma unroll
  for (int ct = 0; ct < D/16; ++ct) acc[ct] = (f32x4){0.f,0.f,0.f,0.f};
  int r = w*16 + lr;
#pragma unroll
  for (int kg = 0; kg < D/32; ++kg) {
    int c = (kg*4 + lg) ^ (r & 7);
    bhalf8 af = *(const bhalf8*)&As[(r*KB + c)*8];
#pragma unroll
    for (int ct = 0; ct < D/16; ++ct) {
      bhalf8 bf = *(const bhalf8*)&bw[((size_t)(kg*4 + lg)*D + ct*16 + lr)*8];
      acc[ct] = __builtin_amdgcn_mfma_f32_16x16x32_bf16(af, bf, acc[ct], 0, 0, 0);
    }
  }
  // epilogue: C store + stats
  size_t rb = (size_t)blk*64 + w*16 + lg*4;
#pragma unroll
  for (int ct = 0; ct < D/16; ++ct) {
    int col = ct*16 + lr;
    f32x4 a = acc[ct];
    float* yp = ybuf + rb*D + col;
    yp[0] = a[0]; yp[(size_t)D] = a[1]; yp[(size_t)2*D] = a[2]; yp[(size_t)3*D] = a[3];
    float s = a[0]+a[1]+a[2]+a[3];
    float q = a[0]*a[0]+a[1]*a[1]+a[2]*a[2]+a[3]*a[3];
    s += __shfl_xor(s, 16); q += __shfl_xor(q, 16);
    s += __shfl_xor(s, 32); q += __shfl_xor(q, 32);
    if (lg == 0) { atomicAdd(&sstat[col], s); atomicAdd(&sstat[D+col], q); }
  }
  __syncthreads();
  for (int i = t; i < 2*D; i += 256) atomicAdd(&stats[SOFF+i], sstat[i]);
}

// ---------------- GEMM2: bn+relu on the fly -> bf16 MFMA -> y in-place + stats ----------------
template<int D, int SIN, int SOUT, int CNT>
__global__ __launch_bounds__(256) void gemm2_kernel(
    const float* __restrict__ g1, const float* __restrict__ b1,
    const short* __restrict__ bw, float* __restrict__ ybuf, float* __restrict__ stats) {
  __shared__ __align__(16) float scsh[2*D];
  __shared__ float sstat[2*D];
  int t = threadIdx.x, blk = blockIdx.x;
  for (int i = t; i < D; i += 256) {
    float m = stats[SIN + i] * (1.f/(float)CNT);
    float v = stats[SIN + D + i] * (1.f/(float)CNT) - m*m;
    float s = g1[i] * rsqrtf(v + EPS_);
    scsh[i] = s; scsh[D+i] = b1[i] - m*s;
  }
  for (int i = t; i < 2*D; i += 256) sstat[i] = 0.f;
  __syncthreads();
  int w = t >> 6, l = t & 63, lr = l & 15, lg = l >> 4;
  size_t row = (size_t)blk*64 + w*16 + lr;
  const float* yrow = ybuf + row*D;
  f32x4 acc[D/16];
#pragma unroll
  for (int ct = 0; ct < D/16; ++ct) acc[ct] = (f32x4){0.f,0.f,0.f,0.f};
#pragma unroll
  for (int kg = 0; kg < D/32; ++kg) {
    int k = kg*32 + lg*8;
    float4 y0 = *(const float4*)(yrow + k);
    float4 y1 = *(const float4*)(yrow + k + 4);
    bhalf8 af;
    af[0] = f2bf(fmaxf(y0.x*scsh[k+0] + scsh[D+k+0], 0.f));
    af[1] = f2bf(fmaxf(y0.y*scsh[k+1] + scsh[D+k+1], 0.f));
    af[2] = f2bf(fmaxf(y0.z*scsh[k+2] + scsh[D+k+2], 0.f));
    af[3] = f2bf(fmaxf(y0.w*scsh[k+3] + scsh[D+k+3], 0.f));
    af[4] = f2bf(fmaxf(y1.x*scsh[k+4] + scsh[D+k+4], 0.f));
    af[5] = f2bf(fmaxf(y1.y*scsh[k+5] + scsh[D+k+5], 0.f));
    af[6] = f2bf(fmaxf(y1.z*scsh[k+6] + scsh[D+k+6], 0.f));
    af[7] = f2bf(fmaxf(y1.w*scsh[k+7] + scsh[D+k+7], 0.f));
#pragma unroll
    for (int ct = 0; ct < D/16; ++ct) {
      bhalf8 bf = *(const bhalf8*)&bw[((size_t)(kg*4 + lg)*D + ct*16 + lr)*8];
      acc[ct] = __builtin_amdgcn_mfma_f32_16x16x32_bf16(af, bf, acc[ct], 0, 0, 0);
    }
  }
  size_t rb = (size_t)blk*64 + w*16 + lg*4;
#pragma unroll
  for (int ct = 0; ct < D/16; ++ct) {
    int col = ct*16 + lr;
    f32x4 a = acc[ct];
    float* yp = ybuf + rb*D + col;
    yp[0] = a[0]; yp[(size_t)D] = a[1]; yp[(size_t)2*D] = a[2]; yp[(size_t)3*D] = a[3];
    float s = a[0]+a[1]+a[2]+a[3];
    float q = a[0]*a[0]+a[1]*a[1]+a[2]*a[2]+a[3]*a[3];
    s += __shfl_xor(s, 16); q += __shfl_xor(q, 16);
    s += __shfl_xor(s, 32); q += __shfl_xor(q, 32);
    if (lg == 0) { atomicAdd(&sstat[col], s); atomicAdd(&sstat[D+col], q); }
  }
  __syncthreads();
  for (int i = t; i < 2*D; i += 256) atomicAdd(&stats[SOUT+i], sstat[i]);
}

// ---------------- finish: bn2+relu + max over s (+optional transpose out) ----------------
template<int D, int NP, int SOFF, int CNT, bool TR>
__global__ void le3_kernel(const float* __restrict__ g2, const float* __restrict__ b2,
                           const float* __restrict__ ybuf, const float* __restrict__ stats,
                           float* __restrict__ out) {
  int blk = blockIdx.x, o = threadIdx.x;   // blockDim == D
  int b = blk / NP, n = blk % NP;
  float m = stats[SOFF + o] * (1.f/(float)CNT);
  float v = stats[SOFF + D + o] * (1.f/(float)CNT) - m*m;
  float s = g2[o] * rsqrtf(v + EPS_);
  float sh = b2[o] - m*s;
  const float* yb = ybuf + ((size_t)(b*NP + n)*32)*D + o;
  float mx = 0.f;  // relu floor
#pragma unroll
  for (int k = 0; k < 32; ++k) mx = fmaxf(mx, yb[(size_t)k*D]*s + sh);
  if (TR) out[((size_t)b*D + o)*NP + n] = mx;
  else    out[((size_t)b*NP + n)*D + o] = mx;
}

// ---------------- host ----------------
extern "C" void kernel_launch(void* const* d_in, const int* in_sizes, int n_in,
                              void* d_out, int out_size, void* d_ws, size_t ws_size,
                              hipStream_t stream) {
  (void)in_sizes; (void)n_in; (void)out_size; (void)ws_size;
  const float* x       = (const float*)d_in[0];
  const float* conv1_w = (const float*)d_in[1];
  const float* bn1_g   = (const float*)d_in[2];
  const float* bn1_b   = (const float*)d_in[3];
  const float* conv2_w = (const float*)d_in[4];
  const float* bn2_g   = (const float*)d_in[5];
  const float* bn2_b   = (const float*)d_in[6];
  const float* le0_w1  = (const float*)d_in[7];
  const float* le0_g1  = (const float*)d_in[8];
  const float* le0_b1  = (const float*)d_in[9];
  const float* le0_w2  = (const float*)d_in[10];
  const float* le0_g2  = (const float*)d_in[11];
  const float* le0_b2  = (const float*)d_in[12];
  const float* le1_w1  = (const float*)d_in[13];
  const float* le1_g1  = (const float*)d_in[14];
  const float* le1_b1  = (const float*)d_in[15];
  const float* le1_w2  = (const float*)d_in[16];
  const float* le1_g2  = (const float*)d_in[17];
  const float* le1_b2  = (const float*)d_in[18];

  float* ws   = (float*)d_ws;
  float* t1   = ws + OFF_T1;      // conv1 out; later 'pts' (bn2 output)
  float* ybuf = ws + OFF_YBUF;    // LE y buffer; t2 aliases its start
  float* t2   = ybuf;
  float* pts1 = ws + OFF_PTS1;
  float* nxyz = ws + OFF_NXYZ;
  float* wt2c = ws + OFF_WT2C;
  short* bw0a = (short*)(ws + OFF_BW0A);
  short* bw0b = (short*)(ws + OFF_BW0B);
  short* bw1a = (short*)(ws + OFF_BW1A);
  short* bw1b = (short*)(ws + OFF_BW1B);
  float* stats = ws + OFF_STAT;
  int* fps1 = (int*)(ws + OFF_INT);
  int* fps2 = fps1 + 4096;
  int* knn1 = fps2 + 2048;
  int* knn2 = knn1 + 131072;

  hipMemsetAsync(stats, 0, S_TOTAL*sizeof(float), stream);
  prep_kernel<<<96, 256, 0, stream>>>(conv2_w, le0_w1, le0_w2, le1_w1, le1_w2,
                                      wt2c, bw0a, bw0b, bw1a, bw1b);
  conv1_kernel<<<512, 256, 0, stream>>>(x, conv1_w, t1, stats);
  conv2_kernel<<<512, 256, 0, stream>>>(t1, bn1_g, bn1_b, wt2c, t2, stats);
  bn2fin_kernel<<<8192, 256, 0, stream>>>(t2, bn2_g, bn2_b, stats, t1);  // pts -> t1

  fps_kernel<4096, 512, 512, true ><<<8, 512, 0, stream>>>(x, fps1, nxyz);
  knn_kernel<4096, 512, 256, true ><<<4096, 256, 0, stream>>>(x, nxyz, nullptr, knn1);
  fps_kernel< 512, 256, 256, false><<<8, 256, 0, stream>>>(nxyz, fps2, nullptr);
  knn_kernel< 512, 256, 256, false><<<2048, 256, 0, stream>>>(nxyz, nxyz, fps2, knn2);

  gemm1_kernel<128,  64, 512, 4096, S_L0A><<<2048, 256, 0, stream>>>(t1, knn1, fps1, bw0a, ybuf, stats);
  gemm2_kernel<128, S_L0A, S_L0B, 131072><<<2048, 256, 0, stream>>>(le0_g1, le0_b1, bw0b, ybuf, stats);
  le3_kernel<128, 512, S_L0B, 131072, false><<<4096, 128, 0, stream>>>(le0_g2, le0_b2, ybuf, stats, pts1);

  gemm1_kernel<256, 128, 256,  512, S_L1A><<<1024, 256, 0, stream>>>(pts1, knn2, fps2, bw1a, ybuf, stats);
  gemm2_kernel<256, S_L1A, S_L1B, 65536><<<1024, 256, 0, stream>>>(le1_g1, le1_b1, bw1b, ybuf, stats);
  le3_kernel<256, 256, S_L1B, 65536, true><<<2048, 256, 0, stream>>>(le1_g2, le1_b2, ybuf, stats, (float*)d_out);
}

// Round 3
// 1588.058 us; speedup vs baseline: 2.8865x; 1.0256x over previous
//
#include <hip/hip_runtime.h>

constexpr int B_  = 8;
constexpr int N_  = 4096;
constexpr int NP1 = 512;
constexpr int NP2 = 256;
constexpr float EPS_ = 1e-5f;

typedef __attribute__((ext_vector_type(8))) short bhalf8;
typedef __attribute__((ext_vector_type(4))) float f32x4;

__device__ inline short f2bf(float f) {
  union { float fv; unsigned u; } v; v.fv = f;
  unsigned r = v.u + 0x7FFFu + ((v.u >> 16) & 1u);
  return (short)(r >> 16);
}

// stats layout (floats): [sum, sumsq] pairs per stage
constexpr int S_BN1 = 0;      // 64+64
constexpr int S_BN2 = 128;    // 64+64
constexpr int S_L0A = 256;    // 128+128
constexpr int S_L0B = 512;    // 128+128
constexpr int S_L1A = 768;    // 256+256
constexpr int S_L1B = 1280;   // 256+256
constexpr int S_TOTAL = 1792;

// ws layout (float offsets)
constexpr size_t OFF_T1   = 0;                          // 2,097,152  (t1; later 'pts')
constexpr size_t OFF_YBUF = OFF_T1   + 2097152;         // 16,777,216 (t2 aliases start)
constexpr size_t OFF_PTS1 = OFF_YBUF + 16777216;        // 524,288
constexpr size_t OFF_NXYZ = OFF_PTS1 + 524288;          // 12,288
constexpr size_t OFF_WT2C = OFF_NXYZ + 12288;           // 4,096
constexpr size_t OFF_BW0A = OFF_WT2C + 4096;            // 8,192 floats (128*128 bf16)
constexpr size_t OFF_BW0B = OFF_BW0A + 8192;            // 8,192
constexpr size_t OFF_BW1A = OFF_BW0B + 8192;            // 32,768 (256*256 bf16)
constexpr size_t OFF_BW1B = OFF_BW1A + 32768;           // 32,768
constexpr size_t OFF_STAT = OFF_BW1B + 32768;           // 1,792
constexpr size_t OFF_INT  = OFF_STAT + 1792;            // ints from here

// ---------------- weight prep: conv2 transpose + bf16 fragment-order weights ----------------
__global__ void prep_kernel(const float* __restrict__ conv2w,
                            const float* __restrict__ w0a, const float* __restrict__ w0b,
                            const float* __restrict__ w1a, const float* __restrict__ w1b,
                            float* __restrict__ wt2c,
                            short* __restrict__ b0a, short* __restrict__ b0b,
                            short* __restrict__ b1a, short* __restrict__ b1b) {
  int idx = blockIdx.x * 256 + threadIdx.x;
  if (idx < 4096) { int d = idx >> 6, o = idx & 63; wt2c[idx] = conv2w[o*64 + d]; return; }
  idx -= 4096;
  const float* w; short* dst; int D;
  if      (idx <  2048) { w = w0a; dst = b0a; D = 128; }
  else if (idx <  4096) { w = w0b; dst = b0b; D = 128; idx -= 2048; }
  else if (idx < 12288) { w = w1a; dst = b1a; D = 256; idx -= 4096; }
  else if (idx < 20480) { w = w1b; dst = b1b; D = 256; idx -= 12288; }
  else return;
  int kblk = idx / D, o = idx % D;
  const float* src = w + (size_t)o*D + kblk*8;
  bhalf8 pk;
#pragma unroll
  for (int j = 0; j < 8; ++j) pk[j] = f2bf(src[j]);
  *(bhalf8*)&dst[(size_t)idx*8] = pk;
}

// ---------------- conv1 (3->64) + bn1 stats ----------------
__global__ __launch_bounds__(256) void conv1_kernel(
    const float* __restrict__ x, const float* __restrict__ w,
    float* __restrict__ t1, float* __restrict__ stats) {
  __shared__ float xs[3][64];
  __shared__ float redS[4][64], redQ[4][64];
  int blk = blockIdx.x;
  int b = blk >> 6, n0 = (blk & 63) << 6;
  int t = threadIdx.x;
  if (t < 192) { int c = t >> 6, nl = t & 63; xs[c][nl] = x[((size_t)b*3 + c)*N_ + n0 + nl]; }
  __syncthreads();
  int o = t & 63, ng = t >> 6;
  float w0 = w[o*3+0], w1 = w[o*3+1], w2 = w[o*3+2];
  float ls = 0.f, lq = 0.f;
#pragma unroll
  for (int k = 0; k < 16; ++k) {
    int nl = ng*16 + k;
    float y = xs[0][nl]*w0 + xs[1][nl]*w1 + xs[2][nl]*w2;
    t1[((size_t)b*N_ + n0 + nl)*64 + o] = y;
    ls += y; lq += y*y;
  }
  redS[ng][o] = ls; redQ[ng][o] = lq;
  __syncthreads();
  if (t < 64) {
    float s = redS[0][t]+redS[1][t]+redS[2][t]+redS[3][t];
    float q = redQ[0][t]+redQ[1][t]+redQ[2][t]+redQ[3][t];
    atomicAdd(&stats[S_BN1 + t], s);
    atomicAdd(&stats[S_BN1 + 64 + t], q);
  }
}

// ---------------- bn1+relu + conv2 (64->64) + bn2 stats ----------------
__global__ __launch_bounds__(256) void conv2_kernel(
    const float* __restrict__ t1, const float* __restrict__ g1, const float* __restrict__ b1,
    const float* __restrict__ wt2c, float* __restrict__ t2, float* __restrict__ stats) {
  constexpr int P = 68;
  __shared__ float at[64*P];
  __shared__ float sc[64], sh[64];
  __shared__ float redS[4][64], redQ[4][64];
  int blk = blockIdx.x;
  int b = blk >> 6, n0 = (blk & 63) << 6;
  int t = threadIdx.x;
  if (t < 64) {
    float m = stats[S_BN1 + t] * (1.f/32768.f);
    float v = stats[S_BN1 + 64 + t] * (1.f/32768.f) - m*m;
    float s = g1[t] * rsqrtf(v + EPS_);
    sc[t] = s; sh[t] = b1[t] - m*s;
  }
  __syncthreads();
  for (int e = t; e < 4096; e += 256) {
    int nl = e >> 6, c = e & 63;
    float v = t1[((size_t)b*N_ + n0 + nl)*64 + c];
    at[c*P + nl] = fmaxf(v*sc[c] + sh[c], 0.f);
  }
  __syncthreads();
  int o = t & 63, ng = t >> 6;
  float acc[16];
#pragma unroll
  for (int k = 0; k < 16; ++k) acc[k] = 0.f;
  for (int i = 0; i < 64; ++i) {
    float wv = wt2c[i*64 + o];
    const float* ar = &at[i*P + ng*16];
#pragma unroll
    for (int k = 0; k < 16; k += 4) {
      float4 a4 = *(const float4*)(ar + k);
      acc[k+0] += a4.x*wv; acc[k+1] += a4.y*wv;
      acc[k+2] += a4.z*wv; acc[k+3] += a4.w*wv;
    }
  }
  float ls = 0.f, lq = 0.f;
#pragma unroll
  for (int k = 0; k < 16; ++k) {
    float y = acc[k];
    t2[((size_t)b*N_ + n0 + ng*16 + k)*64 + o] = y;
    ls += y; lq += y*y;
  }
  redS[ng][o] = ls; redQ[ng][o] = lq;
  __syncthreads();
  if (t < 64) {
    float s = redS[0][t]+redS[1][t]+redS[2][t]+redS[3][t];
    float q = redQ[0][t]+redQ[1][t]+redQ[2][t]+redQ[3][t];
    atomicAdd(&stats[S_BN2 + t], s);
    atomicAdd(&stats[S_BN2 + 64 + t], q);
  }
}

// ---------------- bn2 finalize + relu -> pts ----------------
__global__ __launch_bounds__(256) void bn2fin_kernel(
    const float* __restrict__ t2, const float* __restrict__ g2, const float* __restrict__ b2,
    const float* __restrict__ stats, float* __restrict__ pts) {
  int idx = blockIdx.x*256 + threadIdx.x;
  int o = idx & 63;
  float m = stats[S_BN2 + o] * (1.f/32768.f);
  float v = stats[S_BN2 + 64 + o] * (1.f/32768.f) - m*m;
  float s = g2[o] * rsqrtf(v + EPS_);
  pts[idx] = fmaxf(t2[idx]*s + (b2[o] - m*s), 0.f);
}

// ---------------- fused farthest point sampling: level1 (4096->512) + level2 (512->256) ----------------
// One block per batch. Single barrier per iteration:
//   per-wave butterfly -> parity-double-buffered LDS slot -> barrier -> ALL threads
//   redundantly scan slots + fetch next centroid from LDS coords. No serial t0 section.
template<int NPTS, int NSEL1, int NSEL2, int NT>
__global__ __launch_bounds__(NT) void fps_fused_kernel(
    const float* __restrict__ x,      // (B,3,NPTS)
    int* __restrict__ sel1, float* __restrict__ nxyz, int* __restrict__ sel2) {
  constexpr int K = NPTS / NT;
  constexpr int NW = NT / 64;
  __shared__ float lx[NPTS], ly[NPTS], lz[NPTS];       // full cloud copy (48KB)
  __shared__ float sx[NSEL1], sy[NSEL1], sz[NSEL1];    // level-1 selections (6KB)
  __shared__ float wv[2][NW];
  __shared__ int   wi[2][NW];
  int b = blockIdx.x, t = threadIdx.x;
  int lane = t & 63, wid = t >> 6;
  const float* cb = x + (size_t)b * 3 * NPTS;
  for (int i = t; i < NPTS; i += NT) {
    lx[i] = cb[i]; ly[i] = cb[NPTS + i]; lz[i] = cb[2*NPTS + i];
  }
  __syncthreads();
  float px[K], py[K], pz[K], dm[K];
#pragma unroll
  for (int k = 0; k < K; ++k) {
    int p = t + k*NT;
    px[k] = lx[p]; py[k] = ly[p]; pz[k] = lz[p];
    dm[k] = 1e10f;
  }
  float cx = lx[0], cy = ly[0], cz = lz[0];
  if (t == 0) {
    sel1[(size_t)b*NSEL1] = 0;
    float* q = nxyz + (size_t)b*NSEL1*3;
    q[0] = cx; q[1] = cy; q[2] = cz;
    sx[0] = cx; sy[0] = cy; sz[0] = cz;
  }
  for (int it = 1; it < NSEL1; ++it) {
    float bv = -1.f; int bi = 0;
#pragma unroll
    for (int k = 0; k < K; ++k) {
      float dx = px[k]-cx, dy = py[k]-cy, dz = pz[k]-cz;
      float d = dx*dx + dy*dy + dz*dz;
      float nd = fminf(dm[k], d);
      dm[k] = nd;
      if (nd > bv) { bv = nd; bi = t + k*NT; }   // k ascending => lowest index kept on tie
    }
#pragma unroll
    for (int off = 1; off < 64; off <<= 1) {
      float ov = __shfl_xor(bv, off);
      int   oi = __shfl_xor(bi, off);
      if (ov > bv || (ov == bv && oi < bi)) { bv = ov; bi = oi; }
    }
    int p = it & 1;
    if (lane == 0) { wv[p][wid] = bv; wi[p][wid] = bi; }
    __syncthreads();
    float Bv = wv[p][0]; int Bi = wi[p][0];
#pragma unroll
    for (int w2 = 1; w2 < NW; ++w2) {
      float v2 = wv[p][w2]; int i2 = wi[p][w2];
      if (v2 > Bv || (v2 == Bv && i2 < Bi)) { Bv = v2; Bi = i2; }
    }
    cx = lx[Bi]; cy = ly[Bi]; cz = lz[Bi];   // all threads, LDS broadcast
    if (t == 0) {
      sel1[(size_t)b*NSEL1 + it] = Bi;
      float* q = nxyz + ((size_t)b*NSEL1 + it)*3;
      q[0] = cx; q[1] = cy; q[2] = cz;
      sx[it] = cx; sy[it] = cy; sz[it] = cz;
    }
  }
  __syncthreads();
  // ---- level 2 on the NSEL1 selected points (coords already in LDS) ----
  constexpr int K2 = NSEL1 / NT;
  float qx[K2], qy[K2], qz[K2], dm2[K2];
#pragma unroll
  for (int k = 0; k < K2; ++k) {
    int p = t + k*NT;
    qx[k] = sx[p]; qy[k] = sy[p]; qz[k] = sz[p];
    dm2[k] = 1e10f;
  }
  cx = sx[0]; cy = sy[0]; cz = sz[0];
  if (t == 0) sel2[(size_t)b*NSEL2] = 0;
  for (int it = 1; it < NSEL2; ++it) {
    float bv = -1.f; int bi = 0;
#pragma unroll
    for (int k = 0; k < K2; ++k) {
      float dx = qx[k]-cx, dy = qy[k]-cy, dz = qz[k]-cz;
      float d = dx*dx + dy*dy + dz*dz;
      float nd = fminf(dm2[k], d);
      dm2[k] = nd;
      if (nd > bv) { bv = nd; bi = t + k*NT; }
    }
#pragma unroll
    for (int off = 1; off < 64; off <<= 1) {
      float ov = __shfl_xor(bv, off);
      int   oi = __shfl_xor(bi, off);
      if (ov > bv || (ov == bv && oi < bi)) { bv = ov; bi = oi; }
    }
    int p = it & 1;
    if (lane == 0) { wv[p][wid] = bv; wi[p][wid] = bi; }
    __syncthreads();
    float Bv = wv[p][0]; int Bi = wi[p][0];
#pragma unroll
    for (int w2 = 1; w2 < NW; ++w2) {
      float v2 = wv[p][w2]; int i2 = wi[p][w2];
      if (v2 > Bv || (v2 == Bv && i2 < Bi)) { Bv = v2; Bi = i2; }
    }
    cx = sx[Bi]; cy = sy[Bi]; cz = sz[Bi];
    if (t == 0) sel2[(size_t)b*NSEL2 + it] = Bi;
  }
}

// ---------------- kNN (32 smallest d2, top_k-stable ties) ----------------
template<int NDST, int NQ, int NT, bool XLAY>
__global__ __launch_bounds__(NT) void knn_kernel(
    const float* __restrict__ dst, const float* __restrict__ nxyz,
    const int* __restrict__ qmap, int* __restrict__ knn_out) {
  constexpr int K = NDST / NT;
  constexpr int NW = NT / 64;
  __shared__ float d2s[NDST];
  __shared__ float wvs[NW]; __shared__ int wis[NW];
  int blk = blockIdx.x, t = threadIdx.x;
  int b = blk / NQ, q = blk % NQ;
  int qrow = b*NP1 + (qmap ? qmap[b*NQ + q] : q);
  float qx = nxyz[qrow*3+0], qy = nxyz[qrow*3+1], qz = nxyz[qrow*3+2];
  float q2 = (qx*qx + qy*qy) + qz*qz;
  const float* db = dst + (size_t)b * (XLAY ? 3*NDST : NDST*3);
#pragma unroll
  for (int k = 0; k < K; ++k) {
    int j = t + k*NT;
    float xx, yy, zz;
    if (XLAY) { xx = db[j]; yy = db[NDST + j]; zz = db[2*NDST + j]; }
    else      { xx = db[j*3]; yy = db[j*3+1]; zz = db[j*3+2]; }
    float dot = (qx*xx + qy*yy) + qz*zz;
    float p2  = (xx*xx + yy*yy) + zz*zz;
    d2s[j] = (q2 - 2.f*dot) + p2;
  }
  __syncthreads();
  int lane = t & 63, wid = t >> 6;
  int* ko = knn_out + ((size_t)b*NQ + q)*32;
  for (int r = 0; r < 32; ++r) {
    float bv = 3e38f; int bi = NDST;
#pragma unroll
    for (int k = 0; k < K; ++k) {
      int j = t + k*NT;
      float v = d2s[j];
      if (v < bv || (v == bv && j < bi)) { bv = v; bi = j; }
    }
#pragma unroll
    for (int off = 1; off < 64; off <<= 1) {
      float ov = __shfl_xor(bv, off);
      int   oi = __shfl_xor(bi, off);
      if (ov < bv || (ov == bv && oi < bi)) { bv = ov; bi = oi; }
    }
    if (lane == 0) { wvs[wid] = bv; wis[wid] = bi; }
    __syncthreads();
    if (t == 0) {
      float Bv = wvs[0]; int Bi = wis[0];
      for (int w = 1; w < NW; ++w)
        if (wvs[w] < Bv || (wvs[w] == Bv && wis[w] < Bi)) { Bv = wvs[w]; Bi = wis[w]; }
      ko[r] = Bi;
      d2s[Bi] = 3e38f;
    }
    __syncthreads();
  }
}

// ---------------- GEMM1: gather(+center-sub) -> bf16 MFMA -> y + stats ----------------
template<int D, int PW, int NP, int SRCN, int SOFF>
__global__ __launch_bounds__(256) void gemm1_kernel(
    const float* __restrict__ pts, const int* __restrict__ knn,
    const int* __restrict__ cent, const short* __restrict__ bw,
    float* __restrict__ ybuf, float* __restrict__ stats) {
  constexpr int KB = D/8;
  __shared__ __align__(16) short As[64*D];
  __shared__ float cen_s[2*PW];
  __shared__ int kid_s[64];
  __shared__ float sstat[2*D];
  int t = threadIdx.x, blk = blockIdx.x;
  int g0 = blk*2;
  if (t < 64) {
    int grp = t >> 5, s = t & 31;
    kid_s[t] = knn[((size_t)(g0+grp))*32 + s];
  }
  for (int i = t; i < 2*PW; i += 256) {
    int grp = i / PW, d = i % PW;
    int g = g0 + grp; int b = g / NP; int ci = cent[g];
    cen_s[i] = pts[((size_t)b*SRCN + ci)*PW + d];
  }
  for (int i = t; i < 2*D; i += 256) sstat[i] = 0.f;
  __syncthreads();
  for (int task = t; task < 64*KB; task += 256) {
    int row = task / KB, c = task % KB;
    int grp = row >> 5;
    int g = g0 + grp; int b = g / NP;
    int d = c*8;
    float v0,v1,v2,v3,v4,v5,v6,v7;
    if (d < PW) {
      const float* src = pts + ((size_t)b*SRCN + kid_s[row])*PW + d;
      float4 x0 = *(const float4*)src, x1 = *(const float4*)(src+4);
      const float* cc = &cen_s[grp*PW + d];
      v0=x0.x-cc[0]; v1=x0.y-cc[1]; v2=x0.z-cc[2]; v3=x0.w-cc[3];
      v4=x1.x-cc[4]; v5=x1.y-cc[5]; v6=x1.z-cc[6]; v7=x1.w-cc[7];
    } else {
      const float* cc = &cen_s[grp*PW + d - PW];
      v0=cc[0]; v1=cc[1]; v2=cc[2]; v3=cc[3]; v4=cc[4]; v5=cc[5]; v6=cc[6]; v7=cc[7];
    }
    bhalf8 pk;
    pk[0]=f2bf(v0); pk[1]=f2bf(v1); pk[2]=f2bf(v2); pk[3]=f2bf(v3);
    pk[4]=f2bf(v4); pk[5]=f2bf(v5); pk[6]=f2bf(v6); pk[7]=f2bf(v7);
    int a16 = row*KB + (c ^ (row & 7));
    *(bhalf8*)&As[a16*8] = pk;
  }
  __syncthreads();
  int w = t >> 6, l = t & 63, lr = l & 15, lg = l >> 4;
  f32x4 acc[D/16];
#pragma unroll
  for (int ct = 0; ct < D/16; ++ct) acc[ct] = (f32x4){0.f,0.f,0.f,0.f};
  int r = w*16 + lr;
#pragma unroll
  for (int kg = 0; kg < D/32; ++kg) {
    int c = (kg*4 + lg) ^ (r & 7);
    bhalf8 af = *(const bhalf8*)&As[(r*KB + c)*8];
#pragma unroll
    for (int ct = 0; ct < D/16; ++ct) {
      bhalf8 bf = *(const bhalf8*)&bw[((size_t)(kg*4 + lg)*D + ct*16 + lr)*8];
      acc[ct] = __builtin_amdgcn_mfma_f32_16x16x32_bf16(af, bf, acc[ct], 0, 0, 0);
    }
  }
  size_t rb = (size_t)blk*64 + w*16 + lg*4;
#pragma unroll
  for (int ct = 0; ct < D/16; ++ct) {
    int col = ct*16 + lr;
    f32x4 a = acc[ct];
    float* yp = ybuf + rb*D + col;
    yp[0] = a[0]; yp[(size_t)D] = a[1]; yp[(size_t)2*D] = a[2]; yp[(size_t)3*D] = a[3];
    float s = a[0]+a[1]+a[2]+a[3];
    float q = a[0]*a[0]+a[1]*a[1]+a[2]*a[2]+a[3]*a[3];
    s += __shfl_xor(s, 16); q += __shfl_xor(q, 16);
    s += __shfl_xor(s, 32); q += __shfl_xor(q, 32);
    if (lg == 0) { atomicAdd(&sstat[col], s); atomicAdd(&sstat[D+col], q); }
  }
  __syncthreads();
  for (int i = t; i < 2*D; i += 256) atomicAdd(&stats[SOFF+i], sstat[i]);
}

// ---------------- GEMM2: bn+relu on the fly -> bf16 MFMA -> y in-place + stats ----------------
template<int D, int SIN, int SOUT, int CNT>
__global__ __launch_bounds__(256) void gemm2_kernel(
    const float* __restrict__ g1, const float* __restrict__ b1,
    const short* __restrict__ bw, float* __restrict__ ybuf, float* __restrict__ stats) {
  __shared__ __align__(16) float scsh[2*D];
  __shared__ float sstat[2*D];
  int t = threadIdx.x, blk = blockIdx.x;
  for (int i = t; i < D; i += 256) {
    float m = stats[SIN + i] * (1.f/(float)CNT);
    float v = stats[SIN + D + i] * (1.f/(float)CNT) - m*m;
    float s = g1[i] * rsqrtf(v + EPS_);
    scsh[i] = s; scsh[D+i] = b1[i] - m*s;
  }
  for (int i = t; i < 2*D; i += 256) sstat[i] = 0.f;
  __syncthreads();
  int w = t >> 6, l = t & 63, lr = l & 15, lg = l >> 4;
  size_t row = (size_t)blk*64 + w*16 + lr;
  const float* yrow = ybuf + row*D;
  f32x4 acc[D/16];
#pragma unroll
  for (int ct = 0; ct < D/16; ++ct) acc[ct] = (f32x4){0.f,0.f,0.f,0.f};
#pragma unroll
  for (int kg = 0; kg < D/32; ++kg) {
    int k = kg*32 + lg*8;
    float4 y0 = *(const float4*)(yrow + k);
    float4 y1 = *(const float4*)(yrow + k + 4);
    bhalf8 af;
    af[0] = f2bf(fmaxf(y0.x*scsh[k+0] + scsh[D+k+0], 0.f));
    af[1] = f2bf(fmaxf(y0.y*scsh[k+1] + scsh[D+k+1], 0.f));
    af[2] = f2bf(fmaxf(y0.z*scsh[k+2] + scsh[D+k+2], 0.f));
    af[3] = f2bf(fmaxf(y0.w*scsh[k+3] + scsh[D+k+3], 0.f));
    af[4] = f2bf(fmaxf(y1.x*scsh[k+4] + scsh[D+k+4], 0.f));
    af[5] = f2bf(fmaxf(y1.y*scsh[k+5] + scsh[D+k+5], 0.f));
    af[6] = f2bf(fmaxf(y1.z*scsh[k+6] + scsh[D+k+6], 0.f));
    af[7] = f2bf(fmaxf(y1.w*scsh[k+7] + scsh[D+k+7], 0.f));
#pragma unroll
    for (int ct = 0; ct < D/16; ++ct) {
      bhalf8 bf = *(const bhalf8*)&bw[((size_t)(kg*4 + lg)*D + ct*16 + lr)*8];
      acc[ct] = __builtin_amdgcn_mfma_f32_16x16x32_bf16(af, bf, acc[ct], 0, 0, 0);
    }
  }
  size_t rb = (size_t)blk*64 + w*16 + lg*4;
#pragma unroll
  for (int ct = 0; ct < D/16; ++ct) {
    int col = ct*16 + lr;
    f32x4 a = acc[ct];
    float* yp = ybuf + rb*D + col;
    yp[0] = a[0]; yp[(size_t)D] = a[1]; yp[(size_t)2*D] = a[2]; yp[(size_t)3*D] = a[3];
    float s = a[0]+a[1]+a[2]+a[3];
    float q = a[0]*a[0]+a[1]*a[1]+a[2]*a[2]+a[3]*a[3];
    s += __shfl_xor(s, 16); q += __shfl_xor(q, 16);
    s += __shfl_xor(s, 32); q += __shfl_xor(q, 32);
    if (lg == 0) { atomicAdd(&sstat[col], s); atomicAdd(&sstat[D+col], q); }
  }
  __syncthreads();
  for (int i = t; i < 2*D; i += 256) atomicAdd(&stats[SOUT+i], sstat[i]);
}

// ---------------- finish: bn2+relu + max over s (+optional transpose out) ----------------
template<int D, int NP, int SOFF, int CNT, bool TR>
__global__ void le3_kernel(const float* __restrict__ g2, const float* __restrict__ b2,
                           const float* __restrict__ ybuf, const float* __restrict__ stats,
                           float* __restrict__ out) {
  int blk = blockIdx.x, o = threadIdx.x;   // blockDim == D
  int b = blk / NP, n = blk % NP;
  float m = stats[SOFF + o] * (1.f/(float)CNT);
  float v = stats[SOFF + D + o] * (1.f/(float)CNT) - m*m;
  float s = g2[o] * rsqrtf(v + EPS_);
  float sh = b2[o] - m*s;
  const float* yb = ybuf + ((size_t)(b*NP + n)*32)*D + o;
  float mx = 0.f;  // relu floor
#pragma unroll
  for (int k = 0; k < 32; ++k) mx = fmaxf(mx, yb[(size_t)k*D]*s + sh);
  if (TR) out[((size_t)b*D + o)*NP + n] = mx;
  else    out[((size_t)b*NP + n)*D + o] = mx;
}

// ---------------- host ----------------
extern "C" void kernel_launch(void* const* d_in, const int* in_sizes, int n_in,
                              void* d_out, int out_size, void* d_ws, size_t ws_size,
                              hipStream_t stream) {
  (void)in_sizes; (void)n_in; (void)out_size; (void)ws_size;
  const float* x       = (const float*)d_in[0];
  const float* conv1_w = (const float*)d_in[1];
  const float* bn1_g   = (const float*)d_in[2];
  const float* bn1_b   = (const float*)d_in[3];
  const float* conv2_w = (const float*)d_in[4];
  const float* bn2_g   = (const float*)d_in[5];
  const float* bn2_b   = (const float*)d_in[6];
  const float* le0_w1  = (const float*)d_in[7];
  const float* le0_g1  = (const float*)d_in[8];
  const float* le0_b1  = (const float*)d_in[9];
  const float* le0_w2  = (const float*)d_in[10];
  const float* le0_g2  = (const float*)d_in[11];
  const float* le0_b2  = (const float*)d_in[12];
  const float* le1_w1  = (const float*)d_in[13];
  const float* le1_g1  = (const float*)d_in[14];
  const float* le1_b1  = (const float*)d_in[15];
  const float* le1_w2  = (const float*)d_in[16];
  const float* le1_g2  = (const float*)d_in[17];
  const float* le1_b2  = (const float*)d_in[18];

  float* ws   = (float*)d_ws;
  float* t1   = ws + OFF_T1;      // conv1 out; later 'pts' (bn2 output)
  float* ybuf = ws + OFF_YBUF;    // LE y buffer; t2 aliases its start
  float* t2   = ybuf;
  float* pts1 = ws + OFF_PTS1;
  float* nxyz = ws + OFF_NXYZ;
  float* wt2c = ws + OFF_WT2C;
  short* bw0a = (short*)(ws + OFF_BW0A);
  short* bw0b = (short*)(ws + OFF_BW0B);
  short* bw1a = (short*)(ws + OFF_BW1A);
  short* bw1b = (short*)(ws + OFF_BW1B);
  float* stats = ws + OFF_STAT;
  int* fps1 = (int*)(ws + OFF_INT);
  int* fps2 = fps1 + 4096;
  int* knn1 = fps2 + 2048;
  int* knn2 = knn1 + 131072;

  hipMemsetAsync(stats, 0, S_TOTAL*sizeof(float), stream);
  prep_kernel<<<96, 256, 0, stream>>>(conv2_w, le0_w1, le0_w2, le1_w1, le1_w2,
                                      wt2c, bw0a, bw0b, bw1a, bw1b);
  conv1_kernel<<<512, 256, 0, stream>>>(x, conv1_w, t1, stats);
  conv2_kernel<<<512, 256, 0, stream>>>(t1, bn1_g, bn1_b, wt2c, t2, stats);
  bn2fin_kernel<<<8192, 256, 0, stream>>>(t2, bn2_g, bn2_b, stats, t1);  // pts -> t1

  fps_fused_kernel<4096, 512, 256, 512><<<8, 512, 0, stream>>>(x, fps1, nxyz, fps2);
  knn_kernel<4096, 512, 256, true ><<<4096, 256, 0, stream>>>(x, nxyz, nullptr, knn1);
  knn_kernel< 512, 256, 256, false><<<2048, 256, 0, stream>>>(nxyz, nxyz, fps2, knn2);

  gemm1_kernel<128,  64, 512, 4096, S_L0A><<<2048, 256, 0, stream>>>(t1, knn1, fps1, bw0a, ybuf, stats);
  gemm2_kernel<128, S_L0A, S_L0B, 131072><<<2048, 256, 0, stream>>>(le0_g1, le0_b1, bw0b, ybuf, stats);
  le3_kernel<128, 512, S_L0B, 131072, false><<<4096, 128, 0, stream>>>(le0_g2, le0_b2, ybuf, stats, pts1);

  gemm1_kernel<256, 128, 256,  512, S_L1A><<<1024, 256, 0, stream>>>(pts1, knn2, fps2, bw1a, ybuf, stats);
  gemm2_kernel<256, S_L1A, S_L1B, 65536><<<1024, 256, 0, stream>>>(le1_g1, le1_b1, bw1b, ybuf, stats);
  le3_kernel<256, 256, S_L1B, 65536, true><<<2048, 256, 0, stream>>>(le1_g2, le1_b2, ybuf, stats, (float*)d_out);
}

// Round 4
// 1227.116 us; speedup vs baseline: 3.7356x; 1.2941x over previous
//
#include <hip/hip_runtime.h>

constexpr int B_  = 8;
constexpr int N_  = 4096;
constexpr int NP1 = 512;
constexpr int NP2 = 256;
constexpr float EPS_ = 1e-5f;

typedef __attribute__((ext_vector_type(8))) short bhalf8;
typedef __attribute__((ext_vector_type(4))) float f32x4;

__device__ inline short f2bf(float f) {
  union { float fv; unsigned u; } v; v.fv = f;
  unsigned r = v.u + 0x7FFFu + ((v.u >> 16) & 1u);
  return (short)(r >> 16);
}

// packed argmax helpers: key = (value_bits<<32) | ~index  (value >= 0)
template<int CTRL>
__device__ inline void dpp_amax(unsigned &khi, unsigned &klo) {
  unsigned ohi = (unsigned)__builtin_amdgcn_mov_dpp((int)khi, CTRL, 0xF, 0xF, false);
  unsigned olo = (unsigned)__builtin_amdgcn_mov_dpp((int)klo, CTRL, 0xF, 0xF, false);
  if (ohi > khi || (ohi == khi && olo > klo)) { khi = ohi; klo = olo; }
}
__device__ inline void swz16_amax(unsigned &khi, unsigned &klo) {
  unsigned ohi = (unsigned)__builtin_amdgcn_ds_swizzle((int)khi, 0x401F);
  unsigned olo = (unsigned)__builtin_amdgcn_ds_swizzle((int)klo, 0x401F);
  if (ohi > khi || (ohi == khi && olo > klo)) { khi = ohi; klo = olo; }
}

// stats layout (floats): [sum, sumsq] pairs per stage
constexpr int S_BN1 = 0;      // 64+64
constexpr int S_BN2 = 128;    // 64+64
constexpr int S_L0A = 256;    // 128+128
constexpr int S_L0B = 512;    // 128+128
constexpr int S_L1A = 768;    // 256+256
constexpr int S_L1B = 1280;   // 256+256
constexpr int S_TOTAL = 1792;

// ws layout (float offsets)
constexpr size_t OFF_T1   = 0;                          // 2,097,152  (t1; later 'pts')
constexpr size_t OFF_YBUF = OFF_T1   + 2097152;         // 16,777,216 (t2 aliases start)
constexpr size_t OFF_PTS1 = OFF_YBUF + 16777216;        // 524,288
constexpr size_t OFF_NXYZ = OFF_PTS1 + 524288;          // 12,288
constexpr size_t OFF_WT2C = OFF_NXYZ + 12288;           // 4,096
constexpr size_t OFF_BW0A = OFF_WT2C + 4096;            // 8,192 floats (128*128 bf16)
constexpr size_t OFF_BW0B = OFF_BW0A + 8192;            // 8,192
constexpr size_t OFF_BW1A = OFF_BW0B + 8192;            // 32,768 (256*256 bf16)
constexpr size_t OFF_BW1B = OFF_BW1A + 32768;           // 32,768
constexpr size_t OFF_STAT = OFF_BW1B + 32768;           // 1,792
constexpr size_t OFF_INT  = OFF_STAT + 1792;            // ints from here

// ---------------- weight prep: conv2 transpose + bf16 fragment-order weights ----------------
__global__ void prep_kernel(const float* __restrict__ conv2w,
                            const float* __restrict__ w0a, const float* __restrict__ w0b,
                            const float* __restrict__ w1a, const float* __restrict__ w1b,
                            float* __restrict__ wt2c,
                            short* __restrict__ b0a, short* __restrict__ b0b,
                            short* __restrict__ b1a, short* __restrict__ b1b) {
  int idx = blockIdx.x * 256 + threadIdx.x;
  if (idx < 4096) { int d = idx >> 6, o = idx & 63; wt2c[idx] = conv2w[o*64 + d]; return; }
  idx -= 4096;
  const float* w; short* dst; int D;
  if      (idx <  2048) { w = w0a; dst = b0a; D = 128; }
  else if (idx <  4096) { w = w0b; dst = b0b; D = 128; idx -= 2048; }
  else if (idx < 12288) { w = w1a; dst = b1a; D = 256; idx -= 4096; }
  else if (idx < 20480) { w = w1b; dst = b1b; D = 256; idx -= 12288; }
  else return;
  int kblk = idx / D, o = idx % D;
  const float* src = w + (size_t)o*D + kblk*8;
  bhalf8 pk;
#pragma unroll
  for (int j = 0; j < 8; ++j) pk[j] = f2bf(src[j]);
  *(bhalf8*)&dst[(size_t)idx*8] = pk;
}

// ---------------- conv1 (3->64) + bn1 stats ----------------
__global__ __launch_bounds__(256) void conv1_kernel(
    const float* __restrict__ x, const float* __restrict__ w,
    float* __restrict__ t1, float* __restrict__ stats) {
  __shared__ float xs[3][64];
  __shared__ float redS[4][64], redQ[4][64];
  int blk = blockIdx.x;
  int b = blk >> 6, n0 = (blk & 63) << 6;
  int t = threadIdx.x;
  if (t < 192) { int c = t >> 6, nl = t & 63; xs[c][nl] = x[((size_t)b*3 + c)*N_ + n0 + nl]; }
  __syncthreads();
  int o = t & 63, ng = t >> 6;
  float w0 = w[o*3+0], w1 = w[o*3+1], w2 = w[o*3+2];
  float ls = 0.f, lq = 0.f;
#pragma unroll
  for (int k = 0; k < 16; ++k) {
    int nl = ng*16 + k;
    float y = xs[0][nl]*w0 + xs[1][nl]*w1 + xs[2][nl]*w2;
    t1[((size_t)b*N_ + n0 + nl)*64 + o] = y;
    ls += y; lq += y*y;
  }
  redS[ng][o] = ls; redQ[ng][o] = lq;
  __syncthreads();
  if (t < 64) {
    float s = redS[0][t]+redS[1][t]+redS[2][t]+redS[3][t];
    float q = redQ[0][t]+redQ[1][t]+redQ[2][t]+redQ[3][t];
    atomicAdd(&stats[S_BN1 + t], s);
    atomicAdd(&stats[S_BN1 + 64 + t], q);
  }
}

// ---------------- bn1+relu + conv2 (64->64) + bn2 stats ----------------
__global__ __launch_bounds__(256) void conv2_kernel(
    const float* __restrict__ t1, const float* __restrict__ g1, const float* __restrict__ b1,
    const float* __restrict__ wt2c, float* __restrict__ t2, float* __restrict__ stats) {
  constexpr int P = 68;
  __shared__ float at[64*P];
  __shared__ float sc[64], sh[64];
  __shared__ float redS[4][64], redQ[4][64];
  int blk = blockIdx.x;
  int b = blk >> 6, n0 = (blk & 63) << 6;
  int t = threadIdx.x;
  if (t < 64) {
    float m = stats[S_BN1 + t] * (1.f/32768.f);
    float v = stats[S_BN1 + 64 + t] * (1.f/32768.f) - m*m;
    float s = g1[t] * rsqrtf(v + EPS_);
    sc[t] = s; sh[t] = b1[t] - m*s;
  }
  __syncthreads();
  for (int e = t; e < 4096; e += 256) {
    int nl = e >> 6, c = e & 63;
    float v = t1[((size_t)b*N_ + n0 + nl)*64 + c];
    at[c*P + nl] = fmaxf(v*sc[c] + sh[c], 0.f);
  }
  __syncthreads();
  int o = t & 63, ng = t >> 6;
  float acc[16];
#pragma unroll
  for (int k = 0; k < 16; ++k) acc[k] = 0.f;
  for (int i = 0; i < 64; ++i) {
    float wv = wt2c[i*64 + o];
    const float* ar = &at[i*P + ng*16];
#pragma unroll
    for (int k = 0; k < 16; k += 4) {
      float4 a4 = *(const float4*)(ar + k);
      acc[k+0] += a4.x*wv; acc[k+1] += a4.y*wv;
      acc[k+2] += a4.z*wv; acc[k+3] += a4.w*wv;
    }
  }
  float ls = 0.f, lq = 0.f;
#pragma unroll
  for (int k = 0; k < 16; ++k) {
    float y = acc[k];
    t2[((size_t)b*N_ + n0 + ng*16 + k)*64 + o] = y;
    ls += y; lq += y*y;
  }
  redS[ng][o] = ls; redQ[ng][o] = lq;
  __syncthreads();
  if (t < 64) {
    float s = redS[0][t]+redS[1][t]+redS[2][t]+redS[3][t];
    float q = redQ[0][t]+redQ[1][t]+redQ[2][t]+redQ[3][t];
    atomicAdd(&stats[S_BN2 + t], s);
    atomicAdd(&stats[S_BN2 + 64 + t], q);
  }
}

// ---------------- bn2 finalize + relu -> pts ----------------
__global__ __launch_bounds__(256) void bn2fin_kernel(
    const float* __restrict__ t2, const float* __restrict__ g2, const float* __restrict__ b2,
    const float* __restrict__ stats, float* __restrict__ pts) {
  int idx = blockIdx.x*256 + threadIdx.x;
  int o = idx & 63;
  float m = stats[S_BN2 + o] * (1.f/32768.f);
  float v = stats[S_BN2 + 64 + o] * (1.f/32768.f) - m*m;
  float s = g2[o] * rsqrtf(v + EPS_);
  pts[idx] = fmaxf(t2[idx]*s + (b2[o] - m*s), 0.f);
}

// ---------------- fused FPS: level1 (4096->512) + level2 (512->256) ----------------
// One block per batch. Per iteration: reg K-loop -> DPP row argmax (xor1/2/4/8)
// -> ds_swizzle xor16 -> per-32 winner key (u64) to parity LDS slot -> ONE barrier
// -> all threads scan slots + fetch centroid from LDS. NO global stores in loop
// (avoids the compiler's vmcnt(0)-drain-before-s_barrier on the critical path).
template<int NPTS, int NSEL1, int NSEL2, int NT>
__global__ __launch_bounds__(NT) void fps_fused_kernel(
    const float* __restrict__ x,      // (B,3,NPTS)
    int* __restrict__ sel1, float* __restrict__ nxyz, int* __restrict__ sel2) {
  constexpr int K  = NPTS / NT;
  constexpr int NS = NT / 32;        // u64 winner slots per parity
  __shared__ float lx[NPTS], ly[NPTS], lz[NPTS];
  __shared__ float sx[NSEL1], sy[NSEL1], sz[NSEL1];
  __shared__ unsigned long long wk[2][NS];
  __shared__ int seli1[NSEL1];
  __shared__ int seli2[NSEL2];
  int b = blockIdx.x, t = threadIdx.x;
  int lane = t & 63, wid = t >> 6;
  const float* cb = x + (size_t)b * 3 * NPTS;
  for (int i = t; i < NPTS; i += NT) {
    lx[i] = cb[i]; ly[i] = cb[NPTS + i]; lz[i] = cb[2*NPTS + i];
  }
  __syncthreads();
  float px[K], py[K], pz[K], dm[K];
#pragma unroll
  for (int k = 0; k < K; ++k) {
    int p = t + k*NT;
    px[k] = lx[p]; py[k] = ly[p]; pz[k] = lz[p];
    dm[k] = 1e10f;
  }
  float cx = lx[0], cy = ly[0], cz = lz[0];
  if (t == 0) { seli1[0] = 0; sx[0] = cx; sy[0] = cy; sz[0] = cz; }
  for (int it = 1; it < NSEL1; ++it) {
    float bv = -1.f; int bi = 0;
#pragma unroll
    for (int k = 0; k < K; ++k) {
      float dx = px[k]-cx, dy = py[k]-cy, dz = pz[k]-cz;
      float d = dx*dx + dy*dy + dz*dz;
      float nd = fminf(dm[k], d);
      dm[k] = nd;
      if (nd > bv) { bv = nd; bi = t + k*NT; }   // k ascending => lowest index on tie
    }
    unsigned khi = __float_as_uint(bv);
    unsigned klo = ~(unsigned)bi;
    dpp_amax<0xB1>(khi, klo);    // quad_perm [1,0,3,2]  = xor1
    dpp_amax<0x4E>(khi, klo);    // quad_perm [2,3,0,1]  = xor2
    dpp_amax<0x141>(khi, klo);   // row_half_mirror       ~ xor4 (groups-of-4 uniform)
    dpp_amax<0x140>(khi, klo);   // row_mirror            ~ xor8 (groups-of-8 uniform)
    swz16_amax(khi, klo);        // ds_swizzle xor16 -> 32-lane uniform
    int p = it & 1;
    if ((lane & 31) == 0)
      wk[p][wid*2 + (lane >> 5)] = ((unsigned long long)khi << 32) | klo;
    __syncthreads();
    unsigned long long best = wk[p][0];
#pragma unroll
    for (int i2 = 1; i2 < NS; ++i2) { unsigned long long v2 = wk[p][i2]; if (v2 > best) best = v2; }
    int Bi = (int)(~(unsigned)best);
    cx = lx[Bi]; cy = ly[Bi]; cz = lz[Bi];     // LDS broadcast, all threads
    if (t == 0) { seli1[it] = Bi; sx[it] = cx; sy[it] = cy; sz[it] = cz; }
  }
  __syncthreads();
  // ---- level 2 on the NSEL1 selected points (coords already in LDS) ----
  constexpr int K2 = NSEL1 / NT;
  float qx[K2], qy[K2], qz[K2], dm2[K2];
#pragma unroll
  for (int k = 0; k < K2; ++k) {
    int p = t + k*NT;
    qx[k] = sx[p]; qy[k] = sy[p]; qz[k] = sz[p];
    dm2[k] = 1e10f;
  }
  cx = sx[0]; cy = sy[0]; cz = sz[0];
  if (t == 0) seli2[0] = 0;
  for (int it = 1; it < NSEL2; ++it) {
    float bv = -1.f; int bi = 0;
#pragma unroll
    for (int k = 0; k < K2; ++k) {
      float dx = qx[k]-cx, dy = qy[k]-cy, dz = qz[k]-cz;
      float d = dx*dx + dy*dy + dz*dz;
      float nd = fminf(dm2[k], d);
      dm2[k] = nd;
      if (nd > bv) { bv = nd; bi = t + k*NT; }
    }
    unsigned khi = __float_as_uint(bv);
    unsigned klo = ~(unsigned)bi;
    dpp_amax<0xB1>(khi, klo);
    dpp_amax<0x4E>(khi, klo);
    dpp_amax<0x141>(khi, klo);
    dpp_amax<0x140>(khi, klo);
    swz16_amax(khi, klo);
    int p = it & 1;
    if ((lane & 31) == 0)
      wk[p][wid*2 + (lane >> 5)] = ((unsigned long long)khi << 32) | klo;
    __syncthreads();
    unsigned long long best = wk[p][0];
#pragma unroll
    for (int i2 = 1; i2 < NS; ++i2) { unsigned long long v2 = wk[p][i2]; if (v2 > best) best = v2; }
    int Bi = (int)(~(unsigned)best);
    cx = sx[Bi]; cy = sy[Bi]; cz = sz[Bi];
    if (t == 0) seli2[it] = Bi;
  }
  __syncthreads();
  // ---- single bulk write-out ----
  for (int i = t; i < NSEL1; i += NT) {
    sel1[(size_t)b*NSEL1 + i] = seli1[i];
    float* q = nxyz + ((size_t)b*NSEL1 + i)*3;
    q[0] = sx[i]; q[1] = sy[i]; q[2] = sz[i];
  }
  for (int i = t; i < NSEL2; i += NT) sel2[(size_t)b*NSEL2 + i] = seli2[i];
}

// ---------------- kNN (32 smallest d2, top_k-stable ties) ----------------
template<int NDST, int NQ, int NT, bool XLAY>
__global__ __launch_bounds__(NT) void knn_kernel(
    const float* __restrict__ dst, const float* __restrict__ nxyz,
    const int* __restrict__ qmap, int* __restrict__ knn_out) {
  constexpr int K = NDST / NT;
  constexpr int NW = NT / 64;
  __shared__ float d2s[NDST];
  __shared__ float wvs[NW]; __shared__ int wis[NW];
  int blk = blockIdx.x, t = threadIdx.x;
  int b = blk / NQ, q = blk % NQ;
  int qrow = b*NP1 + (qmap ? qmap[b*NQ + q] : q);
  float qx = nxyz[qrow*3+0], qy = nxyz[qrow*3+1], qz = nxyz[qrow*3+2];
  float q2 = (qx*qx + qy*qy) + qz*qz;
  const float* db = dst + (size_t)b * (XLAY ? 3*NDST : NDST*3);
#pragma unroll
  for (int k = 0; k < K; ++k) {
    int j = t + k*NT;
    float xx, yy, zz;
    if (XLAY) { xx = db[j]; yy = db[NDST + j]; zz = db[2*NDST + j]; }
    else      { xx = db[j*3]; yy = db[j*3+1]; zz = db[j*3+2]; }
    float dot = (qx*xx + qy*yy) + qz*zz;
    float p2  = (xx*xx + yy*yy) + zz*zz;
    d2s[j] = (q2 - 2.f*dot) + p2;
  }
  __syncthreads();
  int lane = t & 63, wid = t >> 6;
  int* ko = knn_out + ((size_t)b*NQ + q)*32;
  for (int r = 0; r < 32; ++r) {
    float bv = 3e38f; int bi = NDST;
#pragma unroll
    for (int k = 0; k < K; ++k) {
      int j = t + k*NT;
      float v = d2s[j];
      if (v < bv || (v == bv && j < bi)) { bv = v; bi = j; }
    }
#pragma unroll
    for (int off = 1; off < 64; off <<= 1) {
      float ov = __shfl_xor(bv, off);
      int   oi = __shfl_xor(bi, off);
      if (ov < bv || (ov == bv && oi < bi)) { bv = ov; bi = oi; }
    }
    if (lane == 0) { wvs[wid] = bv; wis[wid] = bi; }
    __syncthreads();
    if (t == 0) {
      float Bv = wvs[0]; int Bi = wis[0];
      for (int w = 1; w < NW; ++w)
        if (wvs[w] < Bv || (wvs[w] == Bv && wis[w] < Bi)) { Bv = wvs[w]; Bi = wis[w]; }
      ko[r] = Bi;
      d2s[Bi] = 3e38f;
    }
    __syncthreads();
  }
}

// ---------------- GEMM1: gather(+center-sub) -> bf16 MFMA -> y + stats ----------------
template<int D, int PW, int NP, int SRCN, int SOFF>
__global__ __launch_bounds__(256) void gemm1_kernel(
    const float* __restrict__ pts, const int* __restrict__ knn,
    const int* __restrict__ cent, const short* __restrict__ bw,
    float* __restrict__ ybuf, float* __restrict__ stats) {
  constexpr int KB = D/8;
  __shared__ __align__(16) short As[64*D];
  __shared__ float cen_s[2*PW];
  __shared__ int kid_s[64];
  __shared__ float sstat[2*D];
  int t = threadIdx.x, blk = blockIdx.x;
  int g0 = blk*2;
  if (t < 64) {
    int grp = t >> 5, s = t & 31;
    kid_s[t] = knn[((size_t)(g0+grp))*32 + s];
  }
  for (int i = t; i < 2*PW; i += 256) {
    int grp = i / PW, d = i % PW;
    int g = g0 + grp; int b = g / NP; int ci = cent[g];
    cen_s[i] = pts[((size_t)b*SRCN + ci)*PW + d];
  }
  for (int i = t; i < 2*D; i += 256) sstat[i] = 0.f;
  __syncthreads();
  for (int task = t; task < 64*KB; task += 256) {
    int row = task / KB, c = task % KB;
    int grp = row >> 5;
    int g = g0 + grp; int b = g / NP;
    int d = c*8;
    float v0,v1,v2,v3,v4,v5,v6,v7;
    if (d < PW) {
      const float* src = pts + ((size_t)b*SRCN + kid_s[row])*PW + d;
      float4 x0 = *(const float4*)src, x1 = *(const float4*)(src+4);
      const float* cc = &cen_s[grp*PW + d];
      v0=x0.x-cc[0]; v1=x0.y-cc[1]; v2=x0.z-cc[2]; v3=x0.w-cc[3];
      v4=x1.x-cc[4]; v5=x1.y-cc[5]; v6=x1.z-cc[6]; v7=x1.w-cc[7];
    } else {
      const float* cc = &cen_s[grp*PW + d - PW];
      v0=cc[0]; v1=cc[1]; v2=cc[2]; v3=cc[3]; v4=cc[4]; v5=cc[5]; v6=cc[6]; v7=cc[7];
    }
    bhalf8 pk;
    pk[0]=f2bf(v0); pk[1]=f2bf(v1); pk[2]=f2bf(v2); pk[3]=f2bf(v3);
    pk[4]=f2bf(v4); pk[5]=f2bf(v5); pk[6]=f2bf(v6); pk[7]=f2bf(v7);
    int a16 = row*KB + (c ^ (row & 7));
    *(bhalf8*)&As[a16*8] = pk;
  }
  __syncthreads();
  int w = t >> 6, l = t & 63, lr = l & 15, lg = l >> 4;
  f32x4 acc[D/16];
#pragma unroll
  for (int ct = 0; ct < D/16; ++ct) acc[ct] = (f32x4){0.f,0.f,0.f,0.f};
  int r = w*16 + lr;
#pragma unroll
  for (int kg = 0; kg < D/32; ++kg) {
    int c = (kg*4 + lg) ^ (r & 7);
    bhalf8 af = *(const bhalf8*)&As[(r*KB + c)*8];
#pragma unroll
    for (int ct = 0; ct < D/16; ++ct) {
      bhalf8 bf = *(const bhalf8*)&bw[((size_t)(kg*4 + lg)*D + ct*16 + lr)*8];
      acc[ct] = __builtin_amdgcn_mfma_f32_16x16x32_bf16(af, bf, acc[ct], 0, 0, 0);
    }
  }
  size_t rb = (size_t)blk*64 + w*16 + lg*4;
#pragma unroll
  for (int ct = 0; ct < D/16; ++ct) {
    int col = ct*16 + lr;
    f32x4 a = acc[ct];
    float* yp = ybuf + rb*D + col;
    yp[0] = a[0]; yp[(size_t)D] = a[1]; yp[(size_t)2*D] = a[2]; yp[(size_t)3*D] = a[3];
    float s = a[0]+a[1]+a[2]+a[3];
    float q = a[0]*a[0]+a[1]*a[1]+a[2]*a[2]+a[3]*a[3];
    s += __shfl_xor(s, 16); q += __shfl_xor(q, 16);
    s += __shfl_xor(s, 32); q += __shfl_xor(q, 32);
    if (lg == 0) { atomicAdd(&sstat[col], s); atomicAdd(&sstat[D+col], q); }
  }
  __syncthreads();
  for (int i = t; i < 2*D; i += 256) atomicAdd(&stats[SOFF+i], sstat[i]);
}

// ---------------- GEMM2: bn+relu on the fly -> bf16 MFMA -> y in-place + stats ----------------
template<int D, int SIN, int SOUT, int CNT>
__global__ __launch_bounds__(256) void gemm2_kernel(
    const float* __restrict__ g1, const float* __restrict__ b1,
    const short* __restrict__ bw, float* __restrict__ ybuf, float* __restrict__ stats) {
  __shared__ __align__(16) float scsh[2*D];
  __shared__ float sstat[2*D];
  int t = threadIdx.x, blk = blockIdx.x;
  for (int i = t; i < D; i += 256) {
    float m = stats[SIN + i] * (1.f/(float)CNT);
    float v = stats[SIN + D + i] * (1.f/(float)CNT) - m*m;
    float s = g1[i] * rsqrtf(v + EPS_);
    scsh[i] = s; scsh[D+i] = b1[i] - m*s;
  }
  for (int i = t; i < 2*D; i += 256) sstat[i] = 0.f;
  __syncthreads();
  int w = t >> 6, l = t & 63, lr = l & 15, lg = l >> 4;
  size_t row = (size_t)blk*64 + w*16 + lr;
  const float* yrow = ybuf + row*D;
  f32x4 acc[D/16];
#pragma unroll
  for (int ct = 0; ct < D/16; ++ct) acc[ct] = (f32x4){0.f,0.f,0.f,0.f};
#pragma unroll
  for (int kg = 0; kg < D/32; ++kg) {
    int k = kg*32 + lg*8;
    float4 y0 = *(const float4*)(yrow + k);
    float4 y1 = *(const float4*)(yrow + k + 4);
    bhalf8 af;
    af[0] = f2bf(fmaxf(y0.x*scsh[k+0] + scsh[D+k+0], 0.f));
    af[1] = f2bf(fmaxf(y0.y*scsh[k+1] + scsh[D+k+1], 0.f));
    af[2] = f2bf(fmaxf(y0.z*scsh[k+2] + scsh[D+k+2], 0.f));
    af[3] = f2bf(fmaxf(y0.w*scsh[k+3] + scsh[D+k+3], 0.f));
    af[4] = f2bf(fmaxf(y1.x*scsh[k+4] + scsh[D+k+4], 0.f));
    af[5] = f2bf(fmaxf(y1.y*scsh[k+5] + scsh[D+k+5], 0.f));
    af[6] = f2bf(fmaxf(y1.z*scsh[k+6] + scsh[D+k+6], 0.f));
    af[7] = f2bf(fmaxf(y1.w*scsh[k+7] + scsh[D+k+7], 0.f));
#pragma unroll
    for (int ct = 0; ct < D/16; ++ct) {
      bhalf8 bf = *(const bhalf8*)&bw[((size_t)(kg*4 + lg)*D + ct*16 + lr)*8];
      acc[ct] = __builtin_amdgcn_mfma_f32_16x16x32_bf16(af, bf, acc[ct], 0, 0, 0);
    }
  }
  size_t rb = (size_t)blk*64 + w*16 + lg*4;
#pragma unroll
  for (int ct = 0; ct < D/16; ++ct) {
    int col = ct*16 + lr;
    f32x4 a = acc[ct];
    float* yp = ybuf + rb*D + col;
    yp[0] = a[0]; yp[(size_t)D] = a[1]; yp[(size_t)2*D] = a[2]; yp[(size_t)3*D] = a[3];
    float s = a[0]+a[1]+a[2]+a[3];
    float q = a[0]*a[0]+a[1]*a[1]+a[2]*a[2]+a[3]*a[3];
    s += __shfl_xor(s, 16); q += __shfl_xor(q, 16);
    s += __shfl_xor(s, 32); q += __shfl_xor(q, 32);
    if (lg == 0) { atomicAdd(&sstat[col], s); atomicAdd(&sstat[D+col], q); }
  }
  __syncthreads();
  for (int i = t; i < 2*D; i += 256) atomicAdd(&stats[SOUT+i], sstat[i]);
}

// ---------------- finish: bn2+relu + max over s (+optional transpose out) ----------------
template<int D, int NP, int SOFF, int CNT, bool TR>
__global__ void le3_kernel(const float* __restrict__ g2, const float* __restrict__ b2,
                           const float* __restrict__ ybuf, const float* __restrict__ stats,
                           float* __restrict__ out) {
  int blk = blockIdx.x, o = threadIdx.x;   // blockDim == D
  int b = blk / NP, n = blk % NP;
  float m = stats[SOFF + o] * (1.f/(float)CNT);
  float v = stats[SOFF + D + o] * (1.f/(float)CNT) - m*m;
  float s = g2[o] * rsqrtf(v + EPS_);
  float sh = b2[o] - m*s;
  const float* yb = ybuf + ((size_t)(b*NP + n)*32)*D + o;
  float mx = 0.f;  // relu floor
#pragma unroll
  for (int k = 0; k < 32; ++k) mx = fmaxf(mx, yb[(size_t)k*D]*s + sh);
  if (TR) out[((size_t)b*D + o)*NP + n] = mx;
  else    out[((size_t)b*NP + n)*D + o] = mx;
}

// ---------------- host ----------------
extern "C" void kernel_launch(void* const* d_in, const int* in_sizes, int n_in,
                              void* d_out, int out_size, void* d_ws, size_t ws_size,
                              hipStream_t stream) {
  (void)in_sizes; (void)n_in; (void)out_size; (void)ws_size;
  const float* x       = (const float*)d_in[0];
  const float* conv1_w = (const float*)d_in[1];
  const float* bn1_g   = (const float*)d_in[2];
  const float* bn1_b   = (const float*)d_in[3];
  const float* conv2_w = (const float*)d_in[4];
  const float* bn2_g   = (const float*)d_in[5];
  const float* bn2_b   = (const float*)d_in[6];
  const float* le0_w1  = (const float*)d_in[7];
  const float* le0_g1  = (const float*)d_in[8];
  const float* le0_b1  = (const float*)d_in[9];
  const float* le0_w2  = (const float*)d_in[10];
  const float* le0_g2  = (const float*)d_in[11];
  const float* le0_b2  = (const float*)d_in[12];
  const float* le1_w1  = (const float*)d_in[13];
  const float* le1_g1  = (const float*)d_in[14];
  const float* le1_b1  = (const float*)d_in[15];
  const float* le1_w2  = (const float*)d_in[16];
  const float* le1_g2  = (const float*)d_in[17];
  const float* le1_b2  = (const float*)d_in[18];

  float* ws   = (float*)d_ws;
  float* t1   = ws + OFF_T1;      // conv1 out; later 'pts' (bn2 output)
  float* ybuf = ws + OFF_YBUF;    // LE y buffer; t2 aliases its start
  float* t2   = ybuf;
  float* pts1 = ws + OFF_PTS1;
  float* nxyz = ws + OFF_NXYZ;
  float* wt2c = ws + OFF_WT2C;
  short* bw0a = (short*)(ws + OFF_BW0A);
  short* bw0b = (short*)(ws + OFF_BW0B);
  short* bw1a = (short*)(ws + OFF_BW1A);
  short* bw1b = (short*)(ws + OFF_BW1B);
  float* stats = ws + OFF_STAT;
  int* fps1 = (int*)(ws + OFF_INT);
  int* fps2 = fps1 + 4096;
  int* knn1 = fps2 + 2048;
  int* knn2 = knn1 + 131072;

  hipMemsetAsync(stats, 0, S_TOTAL*sizeof(float), stream);
  prep_kernel<<<96, 256, 0, stream>>>(conv2_w, le0_w1, le0_w2, le1_w1, le1_w2,
                                      wt2c, bw0a, bw0b, bw1a, bw1b);
  conv1_kernel<<<512, 256, 0, stream>>>(x, conv1_w, t1, stats);
  conv2_kernel<<<512, 256, 0, stream>>>(t1, bn1_g, bn1_b, wt2c, t2, stats);
  bn2fin_kernel<<<8192, 256, 0, stream>>>(t2, bn2_g, bn2_b, stats, t1);  // pts -> t1

  fps_fused_kernel<4096, 512, 256, 512><<<8, 512, 0, stream>>>(x, fps1, nxyz, fps2);
  knn_kernel<4096, 512, 256, true ><<<4096, 256, 0, stream>>>(x, nxyz, nullptr, knn1);
  knn_kernel< 512, 256, 256, false><<<2048, 256, 0, stream>>>(nxyz, nxyz, fps2, knn2);

  gemm1_kernel<128,  64, 512, 4096, S_L0A><<<2048, 256, 0, stream>>>(t1, knn1, fps1, bw0a, ybuf, stats);
  gemm2_kernel<128, S_L0A, S_L0B, 131072><<<2048, 256, 0, stream>>>(le0_g1, le0_b1, bw0b, ybuf, stats);
  le3_kernel<128, 512, S_L0B, 131072, false><<<4096, 128, 0, stream>>>(le0_g2, le0_b2, ybuf, stats, pts1);

  gemm1_kernel<256, 128, 256,  512, S_L1A><<<1024, 256, 0, stream>>>(pts1, knn2, fps2, bw1a, ybuf, stats);
  gemm2_kernel<256, S_L1A, S_L1B, 65536><<<1024, 256, 0, stream>>>(le1_g1, le1_b1, bw1b, ybuf, stats);
  le3_kernel<256, 256, S_L1B, 65536, true><<<2048, 256, 0, stream>>>(le1_g2, le1_b2, ybuf, stats, (float*)d_out);
}

// Round 6
// 1129.780 us; speedup vs baseline: 4.0574x; 1.0862x over previous
//
#include <hip/hip_runtime.h>

constexpr int B_  = 8;
constexpr int N_  = 4096;
constexpr int NP1 = 512;
constexpr int NP2 = 256;
constexpr float EPS_ = 1e-5f;

typedef __attribute__((ext_vector_type(8))) short bhalf8;
typedef __attribute__((ext_vector_type(4))) float f32x4;

__device__ inline short f2bf(float f) {
  union { float fv; unsigned u; } v; v.fv = f;
  unsigned r = v.u + 0x7FFFu + ((v.u >> 16) & 1u);
  return (short)(r >> 16);
}

// packed argmax helpers: key = (value_bits<<32) | ~index  (value >= 0)
template<int CTRL>
__device__ inline void dpp_amax(unsigned &khi, unsigned &klo) {
  unsigned ohi = (unsigned)__builtin_amdgcn_mov_dpp((int)khi, CTRL, 0xF, 0xF, false);
  unsigned olo = (unsigned)__builtin_amdgcn_mov_dpp((int)klo, CTRL, 0xF, 0xF, false);
  if (ohi > khi || (ohi == khi && olo > klo)) { khi = ohi; klo = olo; }
}
__device__ inline void swz16_amax(unsigned &khi, unsigned &klo) {
  unsigned ohi = (unsigned)__builtin_amdgcn_ds_swizzle((int)khi, 0x401F);
  unsigned olo = (unsigned)__builtin_amdgcn_ds_swizzle((int)klo, 0x401F);
  if (ohi > khi || (ohi == khi && olo > klo)) { khi = ohi; klo = olo; }
}
__device__ inline void x32_amax(unsigned &khi, unsigned &klo) {
  unsigned ohi = (unsigned)__shfl_xor((int)khi, 32);
  unsigned olo = (unsigned)__shfl_xor((int)klo, 32);
  if (ohi > khi || (ohi == khi && olo > klo)) { khi = ohi; klo = olo; }
}

// stats layout (floats): [sum, sumsq] pairs per stage
constexpr int S_BN1 = 0;      // 64+64
constexpr int S_BN2 = 128;    // 64+64
constexpr int S_L0A = 256;    // 128+128
constexpr int S_L0B = 512;    // 128+128
constexpr int S_L1A = 768;    // 256+256
constexpr int S_L1B = 1280;   // 256+256
constexpr int S_TOTAL = 1792;

// ws layout (float offsets)
constexpr size_t OFF_T1   = 0;                          // 2,097,152  (t1; later 'pts')
constexpr size_t OFF_YBUF = OFF_T1   + 2097152;         // 16,777,216 (t2 aliases start)
constexpr size_t OFF_PTS1 = OFF_YBUF + 16777216;        // 524,288
constexpr size_t OFF_NXYZ = OFF_PTS1 + 524288;          // 12,288
constexpr size_t OFF_WT2C = OFF_NXYZ + 12288;           // 4,096
constexpr size_t OFF_BW0A = OFF_WT2C + 4096;            // 8,192 floats (128*128 bf16)
constexpr size_t OFF_BW0B = OFF_BW0A + 8192;            // 8,192
constexpr size_t OFF_BW1A = OFF_BW0B + 8192;            // 32,768 (256*256 bf16)
constexpr size_t OFF_BW1B = OFF_BW1A + 32768;           // 32,768
constexpr size_t OFF_STAT = OFF_BW1B + 32768;           // 1,792
constexpr size_t OFF_INT  = OFF_STAT + 1792;            // ints from here

// ---------------- weight prep: conv2 transpose + bf16 fragment-order weights ----------------
__global__ void prep_kernel(const float* __restrict__ conv2w,
                            const float* __restrict__ w0a, const float* __restrict__ w0b,
                            const float* __restrict__ w1a, const float* __restrict__ w1b,
                            float* __restrict__ wt2c,
                            short* __restrict__ b0a, short* __restrict__ b0b,
                            short* __restrict__ b1a, short* __restrict__ b1b) {
  int idx = blockIdx.x * 256 + threadIdx.x;
  if (idx < 4096) { int d = idx >> 6, o = idx & 63; wt2c[idx] = conv2w[o*64 + d]; return; }
  idx -= 4096;
  const float* w; short* dst; int D;
  if      (idx <  2048) { w = w0a; dst = b0a; D = 128; }
  else if (idx <  4096) { w = w0b; dst = b0b; D = 128; idx -= 2048; }
  else if (idx < 12288) { w = w1a; dst = b1a; D = 256; idx -= 4096; }
  else if (idx < 20480) { w = w1b; dst = b1b; D = 256; idx -= 12288; }
  else return;
  int kblk = idx / D, o = idx % D;
  const float* src = w + (size_t)o*D + kblk*8;
  bhalf8 pk;
#pragma unroll
  for (int j = 0; j < 8; ++j) pk[j] = f2bf(src[j]);
  *(bhalf8*)&dst[(size_t)idx*8] = pk;
}

// ---------------- conv1 (3->64) + bn1 stats ----------------
__global__ __launch_bounds__(256) void conv1_kernel(
    const float* __restrict__ x, const float* __restrict__ w,
    float* __restrict__ t1, float* __restrict__ stats) {
  __shared__ float xs[3][64];
  __shared__ float redS[4][64], redQ[4][64];
  int blk = blockIdx.x;
  int b = blk >> 6, n0 = (blk & 63) << 6;
  int t = threadIdx.x;
  if (t < 192) { int c = t >> 6, nl = t & 63; xs[c][nl] = x[((size_t)b*3 + c)*N_ + n0 + nl]; }
  __syncthreads();
  int o = t & 63, ng = t >> 6;
  float w0 = w[o*3+0], w1 = w[o*3+1], w2 = w[o*3+2];
  float ls = 0.f, lq = 0.f;
#pragma unroll
  for (int k = 0; k < 16; ++k) {
    int nl = ng*16 + k;
    float y = xs[0][nl]*w0 + xs[1][nl]*w1 + xs[2][nl]*w2;
    t1[((size_t)b*N_ + n0 + nl)*64 + o] = y;
    ls += y; lq += y*y;
  }
  redS[ng][o] = ls; redQ[ng][o] = lq;
  __syncthreads();
  if (t < 64) {
    float s = redS[0][t]+redS[1][t]+redS[2][t]+redS[3][t];
    float q = redQ[0][t]+redQ[1][t]+redQ[2][t]+redQ[3][t];
    atomicAdd(&stats[S_BN1 + t], s);
    atomicAdd(&stats[S_BN1 + 64 + t], q);
  }
}

// ---------------- bn1+relu + conv2 (64->64) + bn2 stats ----------------
__global__ __launch_bounds__(256) void conv2_kernel(
    const float* __restrict__ t1, const float* __restrict__ g1, const float* __restrict__ b1,
    const float* __restrict__ wt2c, float* __restrict__ t2, float* __restrict__ stats) {
  constexpr int P = 68;
  __shared__ float at[64*P];
  __shared__ float sc[64], sh[64];
  __shared__ float redS[4][64], redQ[4][64];
  int blk = blockIdx.x;
  int b = blk >> 6, n0 = (blk & 63) << 6;
  int t = threadIdx.x;
  if (t < 64) {
    float m = stats[S_BN1 + t] * (1.f/32768.f);
    float v = stats[S_BN1 + 64 + t] * (1.f/32768.f) - m*m;
    float s = g1[t] * rsqrtf(v + EPS_);
    sc[t] = s; sh[t] = b1[t] - m*s;
  }
  __syncthreads();
  for (int e = t; e < 4096; e += 256) {
    int nl = e >> 6, c = e & 63;
    float v = t1[((size_t)b*N_ + n0 + nl)*64 + c];
    at[c*P + nl] = fmaxf(v*sc[c] + sh[c], 0.f);
  }
  __syncthreads();
  int o = t & 63, ng = t >> 6;
  float acc[16];
#pragma unroll
  for (int k = 0; k < 16; ++k) acc[k] = 0.f;
  for (int i = 0; i < 64; ++i) {
    float wv = wt2c[i*64 + o];
    const float* ar = &at[i*P + ng*16];
#pragma unroll
    for (int k = 0; k < 16; k += 4) {
      float4 a4 = *(const float4*)(ar + k);
      acc[k+0] += a4.x*wv; acc[k+1] += a4.y*wv;
      acc[k+2] += a4.z*wv; acc[k+3] += a4.w*wv;
    }
  }
  float ls = 0.f, lq = 0.f;
#pragma unroll
  for (int k = 0; k < 16; ++k) {
    float y = acc[k];
    t2[((size_t)b*N_ + n0 + ng*16 + k)*64 + o] = y;
    ls += y; lq += y*y;
  }
  redS[ng][o] = ls; redQ[ng][o] = lq;
  __syncthreads();
  if (t < 64) {
    float s = redS[0][t]+redS[1][t]+redS[2][t]+redS[3][t];
    float q = redQ[0][t]+redQ[1][t]+redQ[2][t]+redQ[3][t];
    atomicAdd(&stats[S_BN2 + t], s);
    atomicAdd(&stats[S_BN2 + 64 + t], q);
  }
}

// ---------------- bn2 finalize + relu -> pts ----------------
__global__ __launch_bounds__(256) void bn2fin_kernel(
    const float* __restrict__ t2, const float* __restrict__ g2, const float* __restrict__ b2,
    const float* __restrict__ stats, float* __restrict__ pts) {
  int idx = blockIdx.x*256 + threadIdx.x;
  int o = idx & 63;
  float m = stats[S_BN2 + o] * (1.f/32768.f);
  float v = stats[S_BN2 + 64 + o] * (1.f/32768.f) - m*m;
  float s = g2[o] * rsqrtf(v + EPS_);
  pts[idx] = fmaxf(t2[idx]*s + (b2[o] - m*s), 0.f);
}

// ---------------- fused FPS: level1 (4096->512, 4 waves) + level2 (512->256, 1 wave) ----------------
// Round-4 proven structure, NT=256 (1 wave/SIMD, 8 slots). Level 2 runs in wave 0
// with zero barriers (key-only dpp+swz16+shfl_xor32, then uniform sx[Bi] broadcast),
// while waves 1-3 concurrently write sel1/nxyz to global. No global ops in loops.
template<int NPTS, int NSEL1, int NSEL2, int NT>
__global__ __launch_bounds__(NT) void fps_fused_kernel(
    const float* __restrict__ x,      // (B,3,NPTS)
    int* __restrict__ sel1, float* __restrict__ nxyz, int* __restrict__ sel2) {
  constexpr int K  = NPTS / NT;
  constexpr int NS = NT / 32;        // u64 winner slots per parity
  __shared__ float lx[NPTS], ly[NPTS], lz[NPTS];
  __shared__ float sx[NSEL1], sy[NSEL1], sz[NSEL1];
  __shared__ unsigned long long wk[2][NS];
  __shared__ int seli1[NSEL1];
  __shared__ int seli2[NSEL2];
  int b = blockIdx.x, t = threadIdx.x;
  int lane = t & 63, wid = t >> 6;
  const float* cb = x + (size_t)b * 3 * NPTS;
  for (int i = t; i < NPTS; i += NT) {
    lx[i] = cb[i]; ly[i] = cb[NPTS + i]; lz[i] = cb[2*NPTS + i];
  }
  __syncthreads();
  float px[K], py[K], pz[K], dm[K];
#pragma unroll
  for (int k = 0; k < K; ++k) {
    int p = t + k*NT;
    px[k] = lx[p]; py[k] = ly[p]; pz[k] = lz[p];
    dm[k] = 1e10f;
  }
  float cx = lx[0], cy = ly[0], cz = lz[0];
  if (t == 0) { seli1[0] = 0; sx[0] = cx; sy[0] = cy; sz[0] = cz; }
  for (int it = 1; it < NSEL1; ++it) {
    float bv = -1.f; int bi = 0;
#pragma unroll
    for (int k = 0; k < K; ++k) {
      float dx = px[k]-cx, dy = py[k]-cy, dz = pz[k]-cz;
      float d = dx*dx + dy*dy + dz*dz;
      float nd = fminf(dm[k], d);
      dm[k] = nd;
      if (nd > bv) { bv = nd; bi = t + k*NT; }   // k ascending => lowest index on tie
    }
    unsigned khi = __float_as_uint(bv), klo = ~(unsigned)bi;
    dpp_amax<0xB1>(khi, klo);    // quad_perm [1,0,3,2]  = xor1
    dpp_amax<0x4E>(khi, klo);    // quad_perm [2,3,0,1]  = xor2
    dpp_amax<0x141>(khi, klo);   // row_half_mirror       ~ xor4
    dpp_amax<0x140>(khi, klo);   // row_mirror            ~ xor8
    swz16_amax(khi, klo);        // xor16 -> 32-lane uniform
    int p = it & 1;
    if ((lane & 31) == 0)
      wk[p][wid*2 + (lane >> 5)] = ((unsigned long long)khi << 32) | klo;
    __syncthreads();
    unsigned long long best = wk[p][0];
#pragma unroll
    for (int i2 = 1; i2 < NS; ++i2) { unsigned long long v2 = wk[p][i2]; if (v2 > best) best = v2; }
    int Bi = (int)(~(unsigned)best);
    cx = lx[Bi]; cy = ly[Bi]; cz = lz[Bi];     // LDS broadcast, all threads
    if (t == 0) { seli1[it] = Bi; sx[it] = cx; sy[it] = cy; sz[it] = cz; }
  }
  __syncthreads();
  if (t < 64) {
    // ---- level 2, single wave (wave 0), zero barriers ----
    constexpr int K2 = NSEL1 / 64;
    float qx[K2], qy[K2], qz[K2], dm2[K2];
#pragma unroll
    for (int k = 0; k < K2; ++k) {
      int p = t + k*64;
      qx[k] = sx[p]; qy[k] = sy[p]; qz[k] = sz[p];
      dm2[k] = 1e10f;
    }
    cx = sx[0]; cy = sy[0]; cz = sz[0];
    if (t == 0) seli2[0] = 0;
    for (int it = 1; it < NSEL2; ++it) {
      float bv = -1.f; int bi = 0;
#pragma unroll
      for (int k = 0; k < K2; ++k) {
        float dx = qx[k]-cx, dy = qy[k]-cy, dz = qz[k]-cz;
        float d = dx*dx + dy*dy + dz*dz;
        float nd = fminf(dm2[k], d);
        dm2[k] = nd;
        if (nd > bv) { bv = nd; bi = t + k*64; }
      }
      unsigned khi = __float_as_uint(bv), klo = ~(unsigned)bi;
      dpp_amax<0xB1>(khi, klo);
      dpp_amax<0x4E>(khi, klo);
      dpp_amax<0x141>(khi, klo);
      dpp_amax<0x140>(khi, klo);
      swz16_amax(khi, klo);
      x32_amax(khi, klo);                      // cross-32 -> wave uniform
      int Bi = (int)~klo;
      cx = sx[Bi]; cy = sy[Bi]; cz = sz[Bi];   // uniform in-wave LDS broadcast
      if (t == 0) seli2[it] = Bi;
    }
  } else {
    // ---- waves 1-3: write sel1 + nxyz while wave 0 runs level 2 ----
    for (int i = t - 64; i < NSEL1; i += NT - 64) {
      sel1[(size_t)b*NSEL1 + i] = seli1[i];
      float* q = nxyz + ((size_t)b*NSEL1 + i)*3;
      q[0] = sx[i]; q[1] = sy[i]; q[2] = sz[i];
    }
  }
  __syncthreads();
  for (int i = t; i < NSEL2; i += NT) sel2[(size_t)b*NSEL2 + i] = seli2[i];
}

// ---------------- kNN (32 smallest d2, top_k-stable ties) ----------------
template<int NDST, int NQ, int NT, bool XLAY>
__global__ __launch_bounds__(NT) void knn_kernel(
    const float* __restrict__ dst, const float* __restrict__ nxyz,
    const int* __restrict__ qmap, int* __restrict__ knn_out) {
  constexpr int K = NDST / NT;
  constexpr int NW = NT / 64;
  __shared__ float d2s[NDST];
  __shared__ float wvs[NW]; __shared__ int wis[NW];
  int blk = blockIdx.x, t = threadIdx.x;
  int b = blk / NQ, q = blk % NQ;
  int qrow = b*NP1 + (qmap ? qmap[b*NQ + q] : q);
  float qx = nxyz[qrow*3+0], qy = nxyz[qrow*3+1], qz = nxyz[qrow*3+2];
  float q2 = (qx*qx + qy*qy) + qz*qz;
  const float* db = dst + (size_t)b * (XLAY ? 3*NDST : NDST*3);
#pragma unroll
  for (int k = 0; k < K; ++k) {
    int j = t + k*NT;
    float xx, yy, zz;
    if (XLAY) { xx = db[j]; yy = db[NDST + j]; zz = db[2*NDST + j]; }
    else      { xx = db[j*3]; yy = db[j*3+1]; zz = db[j*3+2]; }
    float dot = (qx*xx + qy*yy) + qz*zz;
    float p2  = (xx*xx + yy*yy) + zz*zz;
    d2s[j] = (q2 - 2.f*dot) + p2;
  }
  __syncthreads();
  int lane = t & 63, wid = t >> 6;
  int* ko = knn_out + ((size_t)b*NQ + q)*32;
  for (int r = 0; r < 32; ++r) {
    float bv = 3e38f; int bi = NDST;
#pragma unroll
    for (int k = 0; k < K; ++k) {
      int j = t + k*NT;
      float v = d2s[j];
      if (v < bv || (v == bv && j < bi)) { bv = v; bi = j; }
    }
#pragma unroll
    for (int off = 1; off < 64; off <<= 1) {
      float ov = __shfl_xor(bv, off);
      int   oi = __shfl_xor(bi, off);
      if (ov < bv || (ov == bv && oi < bi)) { bv = ov; bi = oi; }
    }
    if (lane == 0) { wvs[wid] = bv; wis[wid] = bi; }
    __syncthreads();
    if (t == 0) {
      float Bv = wvs[0]; int Bi = wis[0];
      for (int w = 1; w < NW; ++w)
        if (wvs[w] < Bv || (wvs[w] == Bv && wis[w] < Bi)) { Bv = wvs[w]; Bi = wis[w]; }
      ko[r] = Bi;
      d2s[Bi] = 3e38f;
    }
    __syncthreads();
  }
}

// ---------------- GEMM1: gather(+center-sub) -> bf16 MFMA -> y + stats ----------------
template<int D, int PW, int NP, int SRCN, int SOFF>
__global__ __launch_bounds__(256) void gemm1_kernel(
    const float* __restrict__ pts, const int* __restrict__ knn,
    const int* __restrict__ cent, const short* __restrict__ bw,
    float* __restrict__ ybuf, float* __restrict__ stats) {
  constexpr int KB = D/8;
  __shared__ __align__(16) short As[64*D];
  __shared__ float cen_s[2*PW];
  __shared__ int kid_s[64];
  __shared__ float sstat[2*D];
  int t = threadIdx.x, blk = blockIdx.x;
  int g0 = blk*2;
  if (t < 64) {
    int grp = t >> 5, s = t & 31;
    kid_s[t] = knn[((size_t)(g0+grp))*32 + s];
  }
  for (int i = t; i < 2*PW; i += 256) {
    int grp = i / PW, d = i % PW;
    int g = g0 + grp; int b = g / NP; int ci = cent[g];
    cen_s[i] = pts[((size_t)b*SRCN + ci)*PW + d];
  }
  for (int i = t; i < 2*D; i += 256) sstat[i] = 0.f;
  __syncthreads();
  for (int task = t; task < 64*KB; task += 256) {
    int row = task / KB, c = task % KB;
    int grp = row >> 5;
    int g = g0 + grp; int b = g / NP;
    int d = c*8;
    float v0,v1,v2,v3,v4,v5,v6,v7;
    if (d < PW) {
      const float* src = pts + ((size_t)b*SRCN + kid_s[row])*PW + d;
      float4 x0 = *(const float4*)src, x1 = *(const float4*)(src+4);
      const float* cc = &cen_s[grp*PW + d];
      v0=x0.x-cc[0]; v1=x0.y-cc[1]; v2=x0.z-cc[2]; v3=x0.w-cc[3];
      v4=x1.x-cc[4]; v5=x1.y-cc[5]; v6=x1.z-cc[6]; v7=x1.w-cc[7];
    } else {
      const float* cc = &cen_s[grp*PW + d - PW];
      v0=cc[0]; v1=cc[1]; v2=cc[2]; v3=cc[3]; v4=cc[4]; v5=cc[5]; v6=cc[6]; v7=cc[7];
    }
    bhalf8 pk;
    pk[0]=f2bf(v0); pk[1]=f2bf(v1); pk[2]=f2bf(v2); pk[3]=f2bf(v3);
    pk[4]=f2bf(v4); pk[5]=f2bf(v5); pk[6]=f2bf(v6); pk[7]=f2bf(v7);
    int a16 = row*KB + (c ^ (row & 7));
    *(bhalf8*)&As[a16*8] = pk;
  }
  __syncthreads();
  int w = t >> 6, l = t & 63, lr = l & 15, lg = l >> 4;
  f32x4 acc[D/16];
#pragma unroll
  for (int ct = 0; ct < D/16; ++ct) acc[ct] = (f32x4){0.f,0.f,0.f,0.f};
  int r = w*16 + lr;
#pragma unroll
  for (int kg = 0; kg < D/32; ++kg) {
    int c = (kg*4 + lg) ^ (r & 7);
    bhalf8 af = *(const bhalf8*)&As[(r*KB + c)*8];
#pragma unroll
    for (int ct = 0; ct < D/16; ++ct) {
      bhalf8 bf = *(const bhalf8*)&bw[((size_t)(kg*4 + lg)*D + ct*16 + lr)*8];
      acc[ct] = __builtin_amdgcn_mfma_f32_16x16x32_bf16(af, bf, acc[ct], 0, 0, 0);
    }
  }
  size_t rb = (size_t)blk*64 + w*16 + lg*4;
#pragma unroll
  for (int ct = 0; ct < D/16; ++ct) {
    int col = ct*16 + lr;
    f32x4 a = acc[ct];
    float* yp = ybuf + rb*D + col;
    yp[0] = a[0]; yp[(size_t)D] = a[1]; yp[(size_t)2*D] = a[2]; yp[(size_t)3*D] = a[3];
    float s = a[0]+a[1]+a[2]+a[3];
    float q = a[0]*a[0]+a[1]*a[1]+a[2]*a[2]+a[3]*a[3];
    s += __shfl_xor(s, 16); q += __shfl_xor(q, 16);
    s += __shfl_xor(s, 32); q += __shfl_xor(q, 32);
    if (lg == 0) { atomicAdd(&sstat[col], s); atomicAdd(&sstat[D+col], q); }
  }
  __syncthreads();
  for (int i = t; i < 2*D; i += 256) atomicAdd(&stats[SOFF+i], sstat[i]);
}

// ---------------- GEMM2: bn+relu on the fly -> bf16 MFMA -> y in-place + stats ----------------
template<int D, int SIN, int SOUT, int CNT>
__global__ __launch_bounds__(256) void gemm2_kernel(
    const float* __restrict__ g1, const float* __restrict__ b1,
    const short* __restrict__ bw, float* __restrict__ ybuf, float* __restrict__ stats) {
  __shared__ __align__(16) float scsh[2*D];
  __shared__ float sstat[2*D];
  int t = threadIdx.x, blk = blockIdx.x;
  for (int i = t; i < D; i += 256) {
    float m = stats[SIN + i] * (1.f/(float)CNT);
    float v = stats[SIN + D + i] * (1.f/(float)CNT) - m*m;
    float s = g1[i] * rsqrtf(v + EPS_);
    scsh[i] = s; scsh[D+i] = b1[i] - m*s;
  }
  for (int i = t; i < 2*D; i += 256) sstat[i] = 0.f;
  __syncthreads();
  int w = t >> 6, l = t & 63, lr = l & 15, lg = l >> 4;
  size_t row = (size_t)blk*64 + w*16 + lr;
  const float* yrow = ybuf + row*D;
  f32x4 acc[D/16];
#pragma unroll
  for (int ct = 0; ct < D/16; ++ct) acc[ct] = (f32x4){0.f,0.f,0.f,0.f};
#pragma unroll
  for (int kg = 0; kg < D/32; ++kg) {
    int k = kg*32 + lg*8;
    float4 y0 = *(const float4*)(yrow + k);
    float4 y1 = *(const float4*)(yrow + k + 4);
    bhalf8 af;
    af[0] = f2bf(fmaxf(y0.x*scsh[k+0] + scsh[D+k+0], 0.f));
    af[1] = f2bf(fmaxf(y0.y*scsh[k+1] + scsh[D+k+1], 0.f));
    af[2] = f2bf(fmaxf(y0.z*scsh[k+2] + scsh[D+k+2], 0.f));
    af[3] = f2bf(fmaxf(y0.w*scsh[k+3] + scsh[D+k+3], 0.f));
    af[4] = f2bf(fmaxf(y1.x*scsh[k+4] + scsh[D+k+4], 0.f));
    af[5] = f2bf(fmaxf(y1.y*scsh[k+5] + scsh[D+k+5], 0.f));
    af[6] = f2bf(fmaxf(y1.z*scsh[k+6] + scsh[D+k+6], 0.f));
    af[7] = f2bf(fmaxf(y1.w*scsh[k+7] + scsh[D+k+7], 0.f));
#pragma unroll
    for (int ct = 0; ct < D/16; ++ct) {
      bhalf8 bf = *(const bhalf8*)&bw[((size_t)(kg*4 + lg)*D + ct*16 + lr)*8];
      acc[ct] = __builtin_amdgcn_mfma_f32_16x16x32_bf16(af, bf, acc[ct], 0, 0, 0);
    }
  }
  size_t rb = (size_t)blk*64 + w*16 + lg*4;
#pragma unroll
  for (int ct = 0; ct < D/16; ++ct) {
    int col = ct*16 + lr;
    f32x4 a = acc[ct];
    float* yp = ybuf + rb*D + col;
    yp[0] = a[0]; yp[(size_t)D] = a[1]; yp[(size_t)2*D] = a[2]; yp[(size_t)3*D] = a[3];
    float s = a[0]+a[1]+a[2]+a[3];
    float q = a[0]*a[0]+a[1]*a[1]+a[2]*a[2]+a[3]*a[3];
    s += __shfl_xor(s, 16); q += __shfl_xor(q, 16);
    s += __shfl_xor(s, 32); q += __shfl_xor(q, 32);
    if (lg == 0) { atomicAdd(&sstat[col], s); atomicAdd(&sstat[D+col], q); }
  }
  __syncthreads();
  for (int i = t; i < 2*D; i += 256) atomicAdd(&stats[SOUT+i], sstat[i]);
}

// ---------------- finish: bn2+relu + max over s (+optional transpose out) ----------------
template<int D, int NP, int SOFF, int CNT, bool TR>
__global__ void le3_kernel(const float* __restrict__ g2, const float* __restrict__ b2,
                           const float* __restrict__ ybuf, const float* __restrict__ stats,
                           float* __restrict__ out) {
  int blk = blockIdx.x, o = threadIdx.x;   // blockDim == D
  int b = blk / NP, n = blk % NP;
  float m = stats[SOFF + o] * (1.f/(float)CNT);
  float v = stats[SOFF + D + o] * (1.f/(float)CNT) - m*m;
  float s = g2[o] * rsqrtf(v + EPS_);
  float sh = b2[o] - m*s;
  const float* yb = ybuf + ((size_t)(b*NP + n)*32)*D + o;
  float mx = 0.f;  // relu floor
#pragma unroll
  for (int k = 0; k < 32; ++k) mx = fmaxf(mx, yb[(size_t)k*D]*s + sh);
  if (TR) out[((size_t)b*D + o)*NP + n] = mx;
  else    out[((size_t)b*NP + n)*D + o] = mx;
}

// ---------------- host ----------------
extern "C" void kernel_launch(void* const* d_in, const int* in_sizes, int n_in,
                              void* d_out, int out_size, void* d_ws, size_t ws_size,
                              hipStream_t stream) {
  (void)in_sizes; (void)n_in; (void)out_size; (void)ws_size;
  const float* x       = (const float*)d_in[0];
  const float* conv1_w = (const float*)d_in[1];
  const float* bn1_g   = (const float*)d_in[2];
  const float* bn1_b   = (const float*)d_in[3];
  const float* conv2_w = (const float*)d_in[4];
  const float* bn2_g   = (const float*)d_in[5];
  const float* bn2_b   = (const float*)d_in[6];
  const float* le0_w1  = (const float*)d_in[7];
  const float* le0_g1  = (const float*)d_in[8];
  const float* le0_b1  = (const float*)d_in[9];
  const float* le0_w2  = (const float*)d_in[10];
  const float* le0_g2  = (const float*)d_in[11];
  const float* le0_b2  = (const float*)d_in[12];
  const float* le1_w1  = (const float*)d_in[13];
  const float* le1_g1  = (const float*)d_in[14];
  const float* le1_b1  = (const float*)d_in[15];
  const float* le1_w2  = (const float*)d_in[16];
  const float* le1_g2  = (const float*)d_in[17];
  const float* le1_b2  = (const float*)d_in[18];

  float* ws   = (float*)d_ws;
  float* t1   = ws + OFF_T1;      // conv1 out; later 'pts' (bn2 output)
  float* ybuf = ws + OFF_YBUF;    // LE y buffer; t2 aliases its start
  float* t2   = ybuf;
  float* pts1 = ws + OFF_PTS1;
  float* nxyz = ws + OFF_NXYZ;
  float* wt2c = ws + OFF_WT2C;
  short* bw0a = (short*)(ws + OFF_BW0A);
  short* bw0b = (short*)(ws + OFF_BW0B);
  short* bw1a = (short*)(ws + OFF_BW1A);
  short* bw1b = (short*)(ws + OFF_BW1B);
  float* stats = ws + OFF_STAT;
  int* fps1 = (int*)(ws + OFF_INT);
  int* fps2 = fps1 + 4096;
  int* knn1 = fps2 + 2048;
  int* knn2 = knn1 + 131072;

  hipMemsetAsync(stats, 0, S_TOTAL*sizeof(float), stream);
  prep_kernel<<<96, 256, 0, stream>>>(conv2_w, le0_w1, le0_w2, le1_w1, le1_w2,
                                      wt2c, bw0a, bw0b, bw1a, bw1b);
  conv1_kernel<<<512, 256, 0, stream>>>(x, conv1_w, t1, stats);
  conv2_kernel<<<512, 256, 0, stream>>>(t1, bn1_g, bn1_b, wt2c, t2, stats);
  bn2fin_kernel<<<8192, 256, 0, stream>>>(t2, bn2_g, bn2_b, stats, t1);  // pts -> t1

  fps_fused_kernel<4096, 512, 256, 256><<<8, 256, 0, stream>>>(x, fps1, nxyz, fps2);
  knn_kernel<4096, 512, 256, true ><<<4096, 256, 0, stream>>>(x, nxyz, nullptr, knn1);
  knn_kernel< 512, 256, 256, false><<<2048, 256, 0, stream>>>(nxyz, nxyz, fps2, knn2);

  gemm1_kernel<128,  64, 512, 4096, S_L0A><<<2048, 256, 0, stream>>>(t1, knn1, fps1, bw0a, ybuf, stats);
  gemm2_kernel<128, S_L0A, S_L0B, 131072><<<2048, 256, 0, stream>>>(le0_g1, le0_b1, bw0b, ybuf, stats);
  le3_kernel<128, 512, S_L0B, 131072, false><<<4096, 128, 0, stream>>>(le0_g2, le0_b2, ybuf, stats, pts1);

  gemm1_kernel<256, 128, 256,  512, S_L1A><<<1024, 256, 0, stream>>>(pts1, knn2, fps2, bw1a, ybuf, stats);
  gemm2_kernel<256, S_L1A, S_L1B, 65536><<<1024, 256, 0, stream>>>(le1_g1, le1_b1, bw1b, ybuf, stats);
  le3_kernel<256, 256, S_L1B, 65536, true><<<2048, 256, 0, stream>>>(le1_g2, le1_b2, ybuf, stats, (float*)d_out);
}

// Round 7
// 1020.319 us; speedup vs baseline: 4.4927x; 1.1073x over previous
//
#include <hip/hip_runtime.h>

constexpr int B_  = 8;
constexpr int N_  = 4096;
constexpr int NP1 = 512;
constexpr int NP2 = 256;
constexpr float EPS_ = 1e-5f;

typedef __attribute__((ext_vector_type(8))) short bhalf8;
typedef __attribute__((ext_vector_type(4))) float f32x4;

__device__ inline short f2bf(float f) {
  union { float fv; unsigned u; } v; v.fv = f;
  unsigned r = v.u + 0x7FFFu + ((v.u >> 16) & 1u);
  return (short)(r >> 16);
}

// packed argmax helpers: key = (khi<<32) | klo, take max
template<int CTRL>
__device__ inline void dpp_amax(unsigned &khi, unsigned &klo) {
  unsigned ohi = (unsigned)__builtin_amdgcn_mov_dpp((int)khi, CTRL, 0xF, 0xF, false);
  unsigned olo = (unsigned)__builtin_amdgcn_mov_dpp((int)klo, CTRL, 0xF, 0xF, false);
  if (ohi > khi || (ohi == khi && olo > klo)) { khi = ohi; klo = olo; }
}
__device__ inline void swz16_amax(unsigned &khi, unsigned &klo) {
  unsigned ohi = (unsigned)__builtin_amdgcn_ds_swizzle((int)khi, 0x401F);
  unsigned olo = (unsigned)__builtin_amdgcn_ds_swizzle((int)klo, 0x401F);
  if (ohi > khi || (ohi == khi && olo > klo)) { khi = ohi; klo = olo; }
}
__device__ inline void x32_amax(unsigned &khi, unsigned &klo) {
  unsigned ohi = (unsigned)__shfl_xor((int)khi, 32);
  unsigned olo = (unsigned)__shfl_xor((int)klo, 32);
  if (ohi > khi || (ohi == khi && olo > klo)) { khi = ohi; klo = olo; }
}
// monotone uint order for arbitrary-sign floats
__device__ inline unsigned ford(float f) {
  unsigned u = __float_as_uint(f);
  return u ^ (((unsigned)((int)u >> 31)) | 0x80000000u);
}

// stats layout (floats): [sum, sumsq] pairs per stage
constexpr int S_BN1 = 0;      // 64+64
constexpr int S_BN2 = 128;    // 64+64
constexpr int S_L0A = 256;    // 128+128
constexpr int S_L0B = 512;    // 128+128
constexpr int S_L1A = 768;    // 256+256
constexpr int S_L1B = 1280;   // 256+256
constexpr int S_TOTAL = 1792;

// ws layout (float offsets)
constexpr size_t OFF_T1   = 0;                          // 2,097,152  (t1; later 'pts'; later mm)
constexpr size_t OFF_YBUF = OFF_T1   + 2097152;         // 16,777,216 (t2 aliases start)
constexpr size_t OFF_PTS1 = OFF_YBUF + 16777216;        // 524,288
constexpr size_t OFF_NXYZ = OFF_PTS1 + 524288;          // 12,288
constexpr size_t OFF_WT2C = OFF_NXYZ + 12288;           // 4,096
constexpr size_t OFF_BW0A = OFF_WT2C + 4096;            // 8,192 floats (128*128 bf16)
constexpr size_t OFF_BW0B = OFF_BW0A + 8192;            // 8,192
constexpr size_t OFF_BW1A = OFF_BW0B + 8192;            // 32,768 (256*256 bf16)
constexpr size_t OFF_BW1B = OFF_BW1A + 32768;           // 32,768
constexpr size_t OFF_STAT = OFF_BW1B + 32768;           // 1,792
constexpr size_t OFF_INT  = OFF_STAT + 1792;            // ints from here

// ---------------- weight prep: conv2 transpose + bf16 fragment-order weights ----------------
__global__ void prep_kernel(const float* __restrict__ conv2w,
                            const float* __restrict__ w0a, const float* __restrict__ w0b,
                            const float* __restrict__ w1a, const float* __restrict__ w1b,
                            float* __restrict__ wt2c,
                            short* __restrict__ b0a, short* __restrict__ b0b,
                            short* __restrict__ b1a, short* __restrict__ b1b) {
  int idx = blockIdx.x * 256 + threadIdx.x;
  if (idx < 4096) { int d = idx >> 6, o = idx & 63; wt2c[idx] = conv2w[o*64 + d]; return; }
  idx -= 4096;
  const float* w; short* dst; int D;
  if      (idx <  2048) { w = w0a; dst = b0a; D = 128; }
  else if (idx <  4096) { w = w0b; dst = b0b; D = 128; idx -= 2048; }
  else if (idx < 12288) { w = w1a; dst = b1a; D = 256; idx -= 4096; }
  else if (idx < 20480) { w = w1b; dst = b1b; D = 256; idx -= 12288; }
  else return;
  int kblk = idx / D, o = idx % D;
  const float* src = w + (size_t)o*D + kblk*8;
  bhalf8 pk;
#pragma unroll
  for (int j = 0; j < 8; ++j) pk[j] = f2bf(src[j]);
  *(bhalf8*)&dst[(size_t)idx*8] = pk;
}

// ---------------- conv1 (3->64) + bn1 stats ----------------
__global__ __launch_bounds__(256) void conv1_kernel(
    const float* __restrict__ x, const float* __restrict__ w,
    float* __restrict__ t1, float* __restrict__ stats) {
  __shared__ float xs[3][64];
  __shared__ float redS[4][64], redQ[4][64];
  int blk = blockIdx.x;
  int b = blk >> 6, n0 = (blk & 63) << 6;
  int t = threadIdx.x;
  if (t < 192) { int c = t >> 6, nl = t & 63; xs[c][nl] = x[((size_t)b*3 + c)*N_ + n0 + nl]; }
  __syncthreads();
  int o = t & 63, ng = t >> 6;
  float w0 = w[o*3+0], w1 = w[o*3+1], w2 = w[o*3+2];
  float ls = 0.f, lq = 0.f;
#pragma unroll
  for (int k = 0; k < 16; ++k) {
    int nl = ng*16 + k;
    float y = xs[0][nl]*w0 + xs[1][nl]*w1 + xs[2][nl]*w2;
    t1[((size_t)b*N_ + n0 + nl)*64 + o] = y;
    ls += y; lq += y*y;
  }
  redS[ng][o] = ls; redQ[ng][o] = lq;
  __syncthreads();
  if (t < 64) {
    float s = redS[0][t]+redS[1][t]+redS[2][t]+redS[3][t];
    float q = redQ[0][t]+redQ[1][t]+redQ[2][t]+redQ[3][t];
    atomicAdd(&stats[S_BN1 + t], s);
    atomicAdd(&stats[S_BN1 + 64 + t], q);
  }
}

// ---------------- bn1+relu + conv2 (64->64) + bn2 stats ----------------
__global__ __launch_bounds__(256) void conv2_kernel(
    const float* __restrict__ t1, const float* __restrict__ g1, const float* __restrict__ b1,
    const float* __restrict__ wt2c, float* __restrict__ t2, float* __restrict__ stats) {
  constexpr int P = 68;
  __shared__ float at[64*P];
  __shared__ float sc[64], sh[64];
  __shared__ float redS[4][64], redQ[4][64];
  int blk = blockIdx.x;
  int b = blk >> 6, n0 = (blk & 63) << 6;
  int t = threadIdx.x;
  if (t < 64) {
    float m = stats[S_BN1 + t] * (1.f/32768.f);
    float v = stats[S_BN1 + 64 + t] * (1.f/32768.f) - m*m;
    float s = g1[t] * rsqrtf(v + EPS_);
    sc[t] = s; sh[t] = b1[t] - m*s;
  }
  __syncthreads();
  for (int e = t; e < 4096; e += 256) {
    int nl = e >> 6, c = e & 63;
    float v = t1[((size_t)b*N_ + n0 + nl)*64 + c];
    at[c*P + nl] = fmaxf(v*sc[c] + sh[c], 0.f);
  }
  __syncthreads();
  int o = t & 63, ng = t >> 6;
  float acc[16];
#pragma unroll
  for (int k = 0; k < 16; ++k) acc[k] = 0.f;
  for (int i = 0; i < 64; ++i) {
    float wv = wt2c[i*64 + o];
    const float* ar = &at[i*P + ng*16];
#pragma unroll
    for (int k = 0; k < 16; k += 4) {
      float4 a4 = *(const float4*)(ar + k);
      acc[k+0] += a4.x*wv; acc[k+1] += a4.y*wv;
      acc[k+2] += a4.z*wv; acc[k+3] += a4.w*wv;
    }
  }
  float ls = 0.f, lq = 0.f;
#pragma unroll
  for (int k = 0; k < 16; ++k) {
    float y = acc[k];
    t2[((size_t)b*N_ + n0 + ng*16 + k)*64 + o] = y;
    ls += y; lq += y*y;
  }
  redS[ng][o] = ls; redQ[ng][o] = lq;
  __syncthreads();
  if (t < 64) {
    float s = redS[0][t]+redS[1][t]+redS[2][t]+redS[3][t];
    float q = redQ[0][t]+redQ[1][t]+redQ[2][t]+redQ[3][t];
    atomicAdd(&stats[S_BN2 + t], s);
    atomicAdd(&stats[S_BN2 + 64 + t], q);
  }
}

// ---------------- bn2 finalize + relu -> pts ----------------
__global__ __launch_bounds__(256) void bn2fin_kernel(
    const float* __restrict__ t2, const float* __restrict__ g2, const float* __restrict__ b2,
    const float* __restrict__ stats, float* __restrict__ pts) {
  int idx = blockIdx.x*256 + threadIdx.x;
  int o = idx & 63;
  float m = stats[S_BN2 + o] * (1.f/32768.f);
  float v = stats[S_BN2 + 64 + o] * (1.f/32768.f) - m*m;
  float s = g2[o] * rsqrtf(v + EPS_);
  pts[idx] = fmaxf(t2[idx]*s + (b2[o] - m*s), 0.f);
}

// ---------------- fused FPS (round-6 proven, unchanged) ----------------
template<int NPTS, int NSEL1, int NSEL2, int NT>
__global__ __launch_bounds__(NT) void fps_fused_kernel(
    const float* __restrict__ x,      // (B,3,NPTS)
    int* __restrict__ sel1, float* __restrict__ nxyz, int* __restrict__ sel2) {
  constexpr int K  = NPTS / NT;
  constexpr int NS = NT / 32;        // u64 winner slots per parity
  __shared__ float lx[NPTS], ly[NPTS], lz[NPTS];
  __shared__ float sx[NSEL1], sy[NSEL1], sz[NSEL1];
  __shared__ unsigned long long wk[2][NS];
  __shared__ int seli1[NSEL1];
  __shared__ int seli2[NSEL2];
  int b = blockIdx.x, t = threadIdx.x;
  int lane = t & 63, wid = t >> 6;
  const float* cb = x + (size_t)b * 3 * NPTS;
  for (int i = t; i < NPTS; i += NT) {
    lx[i] = cb[i]; ly[i] = cb[NPTS + i]; lz[i] = cb[2*NPTS + i];
  }
  __syncthreads();
  float px[K], py[K], pz[K], dm[K];
#pragma unroll
  for (int k = 0; k < K; ++k) {
    int p = t + k*NT;
    px[k] = lx[p]; py[k] = ly[p]; pz[k] = lz[p];
    dm[k] = 1e10f;
  }
  float cx = lx[0], cy = ly[0], cz = lz[0];
  if (t == 0) { seli1[0] = 0; sx[0] = cx; sy[0] = cy; sz[0] = cz; }
  for (int it = 1; it < NSEL1; ++it) {
    float bv = -1.f; int bi = 0;
#pragma unroll
    for (int k = 0; k < K; ++k) {
      float dx = px[k]-cx, dy = py[k]-cy, dz = pz[k]-cz;
      float d = dx*dx + dy*dy + dz*dz;
      float nd = fminf(dm[k], d);
      dm[k] = nd;
      if (nd > bv) { bv = nd; bi = t + k*NT; }
    }
    unsigned khi = __float_as_uint(bv), klo = ~(unsigned)bi;
    dpp_amax<0xB1>(khi, klo);
    dpp_amax<0x4E>(khi, klo);
    dpp_amax<0x141>(khi, klo);
    dpp_amax<0x140>(khi, klo);
    swz16_amax(khi, klo);
    int p = it & 1;
    if ((lane & 31) == 0)
      wk[p][wid*2 + (lane >> 5)] = ((unsigned long long)khi << 32) | klo;
    __syncthreads();
    unsigned long long best = wk[p][0];
#pragma unroll
    for (int i2 = 1; i2 < NS; ++i2) { unsigned long long v2 = wk[p][i2]; if (v2 > best) best = v2; }
    int Bi = (int)(~(unsigned)best);
    cx = lx[Bi]; cy = ly[Bi]; cz = lz[Bi];
    if (t == 0) { seli1[it] = Bi; sx[it] = cx; sy[it] = cy; sz[it] = cz; }
  }
  __syncthreads();
  if (t < 64) {
    constexpr int K2 = NSEL1 / 64;
    float qx[K2], qy[K2], qz[K2], dm2[K2];
#pragma unroll
    for (int k = 0; k < K2; ++k) {
      int p = t + k*64;
      qx[k] = sx[p]; qy[k] = sy[p]; qz[k] = sz[p];
      dm2[k] = 1e10f;
    }
    cx = sx[0]; cy = sy[0]; cz = sz[0];
    if (t == 0) seli2[0] = 0;
    for (int it = 1; it < NSEL2; ++it) {
      float bv = -1.f; int bi = 0;
#pragma unroll
      for (int k = 0; k < K2; ++k) {
        float dx = qx[k]-cx, dy = qy[k]-cy, dz = qz[k]-cz;
        float d = dx*dx + dy*dy + dz*dz;
        float nd = fminf(dm2[k], d);
        dm2[k] = nd;
        if (nd > bv) { bv = nd; bi = t + k*64; }
      }
      unsigned khi = __float_as_uint(bv), klo = ~(unsigned)bi;
      dpp_amax<0xB1>(khi, klo);
      dpp_amax<0x4E>(khi, klo);
      dpp_amax<0x141>(khi, klo);
      dpp_amax<0x140>(khi, klo);
      swz16_amax(khi, klo);
      x32_amax(khi, klo);
      int Bi = (int)~klo;
      cx = sx[Bi]; cy = sy[Bi]; cz = sz[Bi];
      if (t == 0) seli2[it] = Bi;
    }
  } else {
    for (int i = t - 64; i < NSEL1; i += NT - 64) {
      sel1[(size_t)b*NSEL1 + i] = seli1[i];
      float* q = nxyz + ((size_t)b*NSEL1 + i)*3;
      q[0] = sx[i]; q[1] = sy[i]; q[2] = sz[i];
    }
  }
  __syncthreads();
  for (int i = t; i < NSEL2; i += NT) sel2[(size_t)b*NSEL2 + i] = seli2[i];
}

// ---------------- kNN: register-resident d2, FPS-style packed-key argmin ----------------
// key = (~ford(v), ~idx), take max -> min value, tie -> lowest index (== top_k semantics;
// downstream is permutation-invariant so only the set matters, order preserved anyway).
template<int NDST, int NQ, int NT, bool XLAY>
__global__ __launch_bounds__(NT) void knn_kernel(
    const float* __restrict__ dst, const float* __restrict__ nxyz,
    const int* __restrict__ qmap, int* __restrict__ knn_out) {
  constexpr int K  = NDST / NT;
  constexpr int NS = NT / 32;
  __shared__ unsigned long long wk[2][NS];
  __shared__ int kos[32];
  int blk = blockIdx.x, t = threadIdx.x;
  int b = blk / NQ, q = blk % NQ;
  int qrow = b*NP1 + (qmap ? qmap[b*NQ + q] : q);
  float qx = nxyz[qrow*3+0], qy = nxyz[qrow*3+1], qz = nxyz[qrow*3+2];
  float q2 = (qx*qx + qy*qy) + qz*qz;
  const float* db = dst + (size_t)b * (XLAY ? 3*NDST : NDST*3);
  float d2r[K];
#pragma unroll
  for (int k = 0; k < K; ++k) {
    int j = t + k*NT;
    float xx, yy, zz;
    if (XLAY) { xx = db[j]; yy = db[NDST + j]; zz = db[2*NDST + j]; }
    else      { xx = db[j*3]; yy = db[j*3+1]; zz = db[j*3+2]; }
    float dot = (qx*xx + qy*yy) + qz*zz;
    float p2  = (xx*xx + yy*yy) + zz*zz;
    d2r[k] = (q2 - 2.f*dot) + p2;     // same expansion as reference
  }
  for (int r = 0; r < 32; ++r) {
    float bv = 3e38f; int bi = t;
#pragma unroll
    for (int k = 0; k < K; ++k) {
      float v = d2r[k];
      if (v < bv) { bv = v; bi = t + k*NT; }   // k ascending => lowest index on tie
    }
    unsigned khi = ~ford(bv), klo = ~(unsigned)bi;
    dpp_amax<0xB1>(khi, klo);
    dpp_amax<0x4E>(khi, klo);
    dpp_amax<0x141>(khi, klo);
    dpp_amax<0x140>(khi, klo);
    swz16_amax(khi, klo);
    int p = r & 1;
    if ((t & 31) == 0)
      wk[p][t >> 5] = ((unsigned long long)khi << 32) | klo;
    __syncthreads();
    unsigned long long best = wk[p][0];
#pragma unroll
    for (int i2 = 1; i2 < NS; ++i2) { unsigned long long v2 = wk[p][i2]; if (v2 > best) best = v2; }
    int Bi = (int)(~(unsigned)best);
    if (t == 0) kos[r] = Bi;
#pragma unroll
    for (int k = 0; k < K; ++k)
      if (t + k*NT == Bi) d2r[k] = 3e38f;      // local poison, no LDS
  }
  __syncthreads();
  if (t < 32) knn_out[((size_t)b*NQ + q)*32 + t] = kos[t];
}

// ---------------- GEMM1: gather(+center-sub) -> bf16 MFMA -> y + stats ----------------
template<int D, int PW, int NP, int SRCN, int SOFF>
__global__ __launch_bounds__(256) void gemm1_kernel(
    const float* __restrict__ pts, const int* __restrict__ knn,
    const int* __restrict__ cent, const short* __restrict__ bw,
    float* __restrict__ ybuf, float* __restrict__ stats) {
  constexpr int KB = D/8;
  __shared__ __align__(16) short As[64*D];
  __shared__ float cen_s[2*PW];
  __shared__ int kid_s[64];
  __shared__ float sstat[2*D];
  int t = threadIdx.x, blk = blockIdx.x;
  int g0 = blk*2;
  if (t < 64) {
    int grp = t >> 5, s = t & 31;
    kid_s[t] = knn[((size_t)(g0+grp))*32 + s];
  }
  for (int i = t; i < 2*PW; i += 256) {
    int grp = i / PW, d = i % PW;
    int g = g0 + grp; int b = g / NP; int ci = cent[g];
    cen_s[i] = pts[((size_t)b*SRCN + ci)*PW + d];
  }
  for (int i = t; i < 2*D; i += 256) sstat[i] = 0.f;
  __syncthreads();
  for (int task = t; task < 64*KB; task += 256) {
    int row = task / KB, c = task % KB;
    int grp = row >> 5;
    int g = g0 + grp; int b = g / NP;
    int d = c*8;
    float v0,v1,v2,v3,v4,v5,v6,v7;
    if (d < PW) {
      const float* src = pts + ((size_t)b*SRCN + kid_s[row])*PW + d;
      float4 x0 = *(const float4*)src, x1 = *(const float4*)(src+4);
      const float* cc = &cen_s[grp*PW + d];
      v0=x0.x-cc[0]; v1=x0.y-cc[1]; v2=x0.z-cc[2]; v3=x0.w-cc[3];
      v4=x1.x-cc[4]; v5=x1.y-cc[5]; v6=x1.z-cc[6]; v7=x1.w-cc[7];
    } else {
      const float* cc = &cen_s[grp*PW + d - PW];
      v0=cc[0]; v1=cc[1]; v2=cc[2]; v3=cc[3]; v4=cc[4]; v5=cc[5]; v6=cc[6]; v7=cc[7];
    }
    bhalf8 pk;
    pk[0]=f2bf(v0); pk[1]=f2bf(v1); pk[2]=f2bf(v2); pk[3]=f2bf(v3);
    pk[4]=f2bf(v4); pk[5]=f2bf(v5); pk[6]=f2bf(v6); pk[7]=f2bf(v7);
    int a16 = row*KB + (c ^ (row & 7));
    *(bhalf8*)&As[a16*8] = pk;
  }
  __syncthreads();
  int w = t >> 6, l = t & 63, lr = l & 15, lg = l >> 4;
  f32x4 acc[D/16];
#pragma unroll
  for (int ct = 0; ct < D/16; ++ct) acc[ct] = (f32x4){0.f,0.f,0.f,0.f};
  int r = w*16 + lr;
#pragma unroll
  for (int kg = 0; kg < D/32; ++kg) {
    int c = (kg*4 + lg) ^ (r & 7);
    bhalf8 af = *(const bhalf8*)&As[(r*KB + c)*8];
#pragma unroll
    for (int ct = 0; ct < D/16; ++ct) {
      bhalf8 bf = *(const bhalf8*)&bw[((size_t)(kg*4 + lg)*D + ct*16 + lr)*8];
      acc[ct] = __builtin_amdgcn_mfma_f32_16x16x32_bf16(af, bf, acc[ct], 0, 0, 0);
    }
  }
  size_t rb = (size_t)blk*64 + w*16 + lg*4;
#pragma unroll
  for (int ct = 0; ct < D/16; ++ct) {
    int col = ct*16 + lr;
    f32x4 a = acc[ct];
    float* yp = ybuf + rb*D + col;
    yp[0] = a[0]; yp[(size_t)D] = a[1]; yp[(size_t)2*D] = a[2]; yp[(size_t)3*D] = a[3];
    float s = a[0]+a[1]+a[2]+a[3];
    float q = a[0]*a[0]+a[1]*a[1]+a[2]*a[2]+a[3]*a[3];
    s += __shfl_xor(s, 16); q += __shfl_xor(q, 16);
    s += __shfl_xor(s, 32); q += __shfl_xor(q, 32);
    if (lg == 0) { atomicAdd(&sstat[col], s); atomicAdd(&sstat[D+col], q); }
  }
  __syncthreads();
  for (int i = t; i < 2*D; i += 256) atomicAdd(&stats[SOFF+i], sstat[i]);
}

// ---------------- GEMM2: bn+relu on the fly -> bf16 MFMA -> per-group max/min + stats ----------------
// Output: mm[(group)*2*D + {0:max,D:min}] of raw y2 per column; y2 itself is never stored.
// Exactness: max_k relu(fma(s,y_k,sh)) == relu(fma(s, max_k y_k, sh)) for s>=0 (monotone
// rounding); min for s<0 — resolved in le3.
template<int D, int SIN, int SOUT, int CNT>
__global__ __launch_bounds__(256) void gemm2_kernel(
    const float* __restrict__ g1, const float* __restrict__ b1,
    const short* __restrict__ bw, const float* __restrict__ ybuf,
    float* __restrict__ mm, float* __restrict__ stats) {
  __shared__ __align__(16) float scsh[2*D];
  __shared__ float sstat[2*D];
  __shared__ float wmax[4][D], wmin[4][D];
  int t = threadIdx.x, blk = blockIdx.x;
  for (int i = t; i < D; i += 256) {
    float m = stats[SIN + i] * (1.f/(float)CNT);
    float v = stats[SIN + D + i] * (1.f/(float)CNT) - m*m;
    float s = g1[i] * rsqrtf(v + EPS_);
    scsh[i] = s; scsh[D+i] = b1[i] - m*s;
  }
  for (int i = t; i < 2*D; i += 256) sstat[i] = 0.f;
  __syncthreads();
  int w = t >> 6, l = t & 63, lr = l & 15, lg = l >> 4;
  size_t row = (size_t)blk*64 + w*16 + lr;
  const float* yrow = ybuf + row*D;
  f32x4 acc[D/16];
#pragma unroll
  for (int ct = 0; ct < D/16; ++ct) acc[ct] = (f32x4){0.f,0.f,0.f,0.f};
#pragma unroll
  for (int kg = 0; kg < D/32; ++kg) {
    int k = kg*32 + lg*8;
    float4 y0 = *(const float4*)(yrow + k);
    float4 y1 = *(const float4*)(yrow + k + 4);
    bhalf8 af;
    af[0] = f2bf(fmaxf(y0.x*scsh[k+0] + scsh[D+k+0], 0.f));
    af[1] = f2bf(fmaxf(y0.y*scsh[k+1] + scsh[D+k+1], 0.f));
    af[2] = f2bf(fmaxf(y0.z*scsh[k+2] + scsh[D+k+2], 0.f));
    af[3] = f2bf(fmaxf(y0.w*scsh[k+3] + scsh[D+k+3], 0.f));
    af[4] = f2bf(fmaxf(y1.x*scsh[k+4] + scsh[D+k+4], 0.f));
    af[5] = f2bf(fmaxf(y1.y*scsh[k+5] + scsh[D+k+5], 0.f));
    af[6] = f2bf(fmaxf(y1.z*scsh[k+6] + scsh[D+k+6], 0.f));
    af[7] = f2bf(fmaxf(y1.w*scsh[k+7] + scsh[D+k+7], 0.f));
#pragma unroll
    for (int ct = 0; ct < D/16; ++ct) {
      bhalf8 bf = *(const bhalf8*)&bw[((size_t)(kg*4 + lg)*D + ct*16 + lr)*8];
      acc[ct] = __builtin_amdgcn_mfma_f32_16x16x32_bf16(af, bf, acc[ct], 0, 0, 0);
    }
  }
#pragma unroll
  for (int ct = 0; ct < D/16; ++ct) {
    int col = ct*16 + lr;
    f32x4 a = acc[ct];
    // per-wave (16-row) max/min per column
    float mx = fmaxf(fmaxf(a[0], a[1]), fmaxf(a[2], a[3]));
    float mn = fminf(fminf(a[0], a[1]), fminf(a[2], a[3]));
    mx = fmaxf(mx, __shfl_xor(mx, 16)); mn = fminf(mn, __shfl_xor(mn, 16));
    mx = fmaxf(mx, __shfl_xor(mx, 32)); mn = fminf(mn, __shfl_xor(mn, 32));
    if (lg == 0) { wmax[w][col] = mx; wmin[w][col] = mn; }
    float s = a[0]+a[1]+a[2]+a[3];
    float q = a[0]*a[0]+a[1]*a[1]+a[2]*a[2]+a[3]*a[3];
    s += __shfl_xor(s, 16); q += __shfl_xor(q, 16);
    s += __shfl_xor(s, 32); q += __shfl_xor(q, 32);
    if (lg == 0) { atomicAdd(&sstat[col], s); atomicAdd(&sstat[D+col], q); }
  }
  __syncthreads();
  for (int i = t; i < 2*D; i += 256) {
    int g = i / D, col = i - g*D;     // g: group 0 (waves 0,1) / group 1 (waves 2,3)
    float mx = fmaxf(wmax[2*g][col], wmax[2*g+1][col]);
    float mn = fminf(wmin[2*g][col], wmin[2*g+1][col]);
    float* mp = mm + ((size_t)blk*2 + g)*2*D;
    mp[col] = mx; mp[D + col] = mn;
    atomicAdd(&stats[SOUT+i], sstat[i]);
  }
}

// ---------------- finish: bn2 + relu applied to per-group max/min (exact, elementwise) ----------------
template<int D, int NP, int SOFF, int CNT, bool TR>
__global__ __launch_bounds__(256) void le3_kernel(
    const float* __restrict__ g2, const float* __restrict__ b2,
    const float* __restrict__ mm, const float* __restrict__ stats,
    float* __restrict__ out) {
  int idx = blockIdx.x*256 + threadIdx.x;   // over (B_*NP)*D
  int g = idx / D, o = idx - g*D;
  float m = stats[SOFF + o] * (1.f/(float)CNT);
  float v = stats[SOFF + D + o] * (1.f/(float)CNT) - m*m;
  float s = g2[o] * rsqrtf(v + EPS_);
  float sh = b2[o] - m*s;
  const float* mp = mm + (size_t)g*2*D;
  float pick = (s >= 0.f) ? mp[o] : mp[D + o];
  float r = fmaxf(pick*s + sh, 0.f);
  if (TR) { int b = g / NP, n = g - b*NP; out[((size_t)b*D + o)*NP + n] = r; }
  else    out[(size_t)g*D + o] = r;
}

// ---------------- host ----------------
extern "C" void kernel_launch(void* const* d_in, const int* in_sizes, int n_in,
                              void* d_out, int out_size, void* d_ws, size_t ws_size,
                              hipStream_t stream) {
  (void)in_sizes; (void)n_in; (void)out_size; (void)ws_size;
  const float* x       = (const float*)d_in[0];
  const float* conv1_w = (const float*)d_in[1];
  const float* bn1_g   = (const float*)d_in[2];
  const float* bn1_b   = (const float*)d_in[3];
  const float* conv2_w = (const float*)d_in[4];
  const float* bn2_g   = (const float*)d_in[5];
  const float* bn2_b   = (const float*)d_in[6];
  const float* le0_w1  = (const float*)d_in[7];
  const float* le0_g1  = (const float*)d_in[8];
  const float* le0_b1  = (const float*)d_in[9];
  const float* le0_w2  = (const float*)d_in[10];
  const float* le0_g2  = (const float*)d_in[11];
  const float* le0_b2  = (const float*)d_in[12];
  const float* le1_w1  = (const float*)d_in[13];
  const float* le1_g1  = (const float*)d_in[14];
  const float* le1_b1  = (const float*)d_in[15];
  const float* le1_w2  = (const float*)d_in[16];
  const float* le1_g2  = (const float*)d_in[17];
  const float* le1_b2  = (const float*)d_in[18];

  float* ws   = (float*)d_ws;
  float* t1   = ws + OFF_T1;      // conv1 out; later 'pts'; after gemm1a: mm buffer
  float* ybuf = ws + OFF_YBUF;    // LE y1 buffer; t2 aliases its start
  float* t2   = ybuf;
  float* mm   = t1;               // pts dead after gemm1 of each level
  float* pts1 = ws + OFF_PTS1;
  float* nxyz = ws + OFF_NXYZ;
  float* wt2c = ws + OFF_WT2C;
  short* bw0a = (short*)(ws + OFF_BW0A);
  short* bw0b = (short*)(ws + OFF_BW0B);
  short* bw1a = (short*)(ws + OFF_BW1A);
  short* bw1b = (short*)(ws + OFF_BW1B);
  float* stats = ws + OFF_STAT;
  int* fps1 = (int*)(ws + OFF_INT);
  int* fps2 = fps1 + 4096;
  int* knn1 = fps2 + 2048;
  int* knn2 = knn1 + 131072;

  hipMemsetAsync(stats, 0, S_TOTAL*sizeof(float), stream);
  prep_kernel<<<96, 256, 0, stream>>>(conv2_w, le0_w1, le0_w2, le1_w1, le1_w2,
                                      wt2c, bw0a, bw0b, bw1a, bw1b);
  conv1_kernel<<<512, 256, 0, stream>>>(x, conv1_w, t1, stats);
  conv2_kernel<<<512, 256, 0, stream>>>(t1, bn1_g, bn1_b, wt2c, t2, stats);
  bn2fin_kernel<<<8192, 256, 0, stream>>>(t2, bn2_g, bn2_b, stats, t1);  // pts -> t1

  fps_fused_kernel<4096, 512, 256, 256><<<8, 256, 0, stream>>>(x, fps1, nxyz, fps2);
  knn_kernel<4096, 512, 256, true ><<<4096, 256, 0, stream>>>(x, nxyz, nullptr, knn1);
  knn_kernel< 512, 256, 256, false><<<2048, 256, 0, stream>>>(nxyz, nxyz, fps2, knn2);

  gemm1_kernel<128,  64, 512, 4096, S_L0A><<<2048, 256, 0, stream>>>(t1, knn1, fps1, bw0a, ybuf, stats);
  gemm2_kernel<128, S_L0A, S_L0B, 131072><<<2048, 256, 0, stream>>>(le0_g1, le0_b1, bw0b, ybuf, mm, stats);
  le3_kernel<128, 512, S_L0B, 131072, false><<<2048, 256, 0, stream>>>(le0_g2, le0_b2, mm, stats, pts1);

  gemm1_kernel<256, 128, 256,  512, S_L1A><<<1024, 256, 0, stream>>>(pts1, knn2, fps2, bw1a, ybuf, stats);
  gemm2_kernel<256, S_L1A, S_L1B, 65536><<<1024, 256, 0, stream>>>(le1_g1, le1_b1, bw1b, ybuf, mm, stats);
  le3_kernel<256, 256, S_L1B, 65536, true><<<2048, 256, 0, stream>>>(le1_g2, le1_b2, mm, stats, (float*)d_out);
}

// Round 8
// 973.021 us; speedup vs baseline: 4.7111x; 1.0486x over previous
//
#include <hip/hip_runtime.h>

constexpr int B_  = 8;
constexpr int N_  = 4096;
constexpr int NP1 = 512;
constexpr int NP2 = 256;
constexpr float EPS_ = 1e-5f;

typedef __attribute__((ext_vector_type(8))) short bhalf8;
typedef __attribute__((ext_vector_type(4))) float f32x4;

__device__ inline short f2bf(float f) {
  union { float fv; unsigned u; } v; v.fv = f;
  unsigned r = v.u + 0x7FFFu + ((v.u >> 16) & 1u);
  return (short)(r >> 16);
}

// packed argmax helpers: key = (khi<<32) | klo, take max
template<int CTRL>
__device__ inline void dpp_amax(unsigned &khi, unsigned &klo) {
  unsigned ohi = (unsigned)__builtin_amdgcn_mov_dpp((int)khi, CTRL, 0xF, 0xF, false);
  unsigned olo = (unsigned)__builtin_amdgcn_mov_dpp((int)klo, CTRL, 0xF, 0xF, false);
  if (ohi > khi || (ohi == khi && olo > klo)) { khi = ohi; klo = olo; }
}
__device__ inline void swz16_amax(unsigned &khi, unsigned &klo) {
  unsigned ohi = (unsigned)__builtin_amdgcn_ds_swizzle((int)khi, 0x401F);
  unsigned olo = (unsigned)__builtin_amdgcn_ds_swizzle((int)klo, 0x401F);
  if (ohi > khi || (ohi == khi && olo > klo)) { khi = ohi; klo = olo; }
}
__device__ inline void x32_amax(unsigned &khi, unsigned &klo) {
  unsigned ohi = (unsigned)__shfl_xor((int)khi, 32);
  unsigned olo = (unsigned)__shfl_xor((int)klo, 32);
  if (ohi > khi || (ohi == khi && olo > klo)) { khi = ohi; klo = olo; }
}
// monotone uint order for arbitrary-sign floats
__device__ inline unsigned ford(float f) {
  unsigned u = __float_as_uint(f);
  return u ^ (((unsigned)((int)u >> 31)) | 0x80000000u);
}

// stats layout (floats): [sum, sumsq] pairs per stage
constexpr int S_BN1 = 0;      // 64+64
constexpr int S_BN2 = 128;    // 64+64
constexpr int S_L0A = 256;    // 128+128
constexpr int S_L0B = 512;    // 128+128
constexpr int S_L1A = 768;    // 256+256
constexpr int S_L1B = 1280;   // 256+256
constexpr int S_TOTAL = 1792;

// ws layout (float offsets)
constexpr size_t OFF_T1   = 0;                          // 2,097,152  (conv1 out; later 'pts'; later mm)
constexpr size_t OFF_YBUF = OFF_T1   + 2097152;         // 16,777,216 (t2 aliases start)
constexpr size_t OFF_PTS1 = OFF_YBUF + 16777216;        // 524,288
constexpr size_t OFF_NXYZ = OFF_PTS1 + 524288;          // 12,288
constexpr size_t OFF_WT2C = OFF_NXYZ + 12288;           // 4,096
constexpr size_t OFF_BW0A = OFF_WT2C + 4096;            // 8,192 floats (128*128 bf16)
constexpr size_t OFF_BW0B = OFF_BW0A + 8192;            // 8,192
constexpr size_t OFF_BW1A = OFF_BW0B + 8192;            // 32,768 (256*256 bf16)
constexpr size_t OFF_BW1B = OFF_BW1A + 32768;           // 32,768
constexpr size_t OFF_STAT = OFF_BW1B + 32768;           // 1,792 stats + 16 (2 barrier counters, padded)
constexpr size_t OFF_CNT  = OFF_STAT + S_TOTAL;
constexpr size_t OFF_INT  = OFF_CNT + 16;               // ints from here

__device__ inline void prep_elem(int idx, const float* __restrict__ conv2w,
                                 const float* __restrict__ w0a, const float* __restrict__ w0b,
                                 const float* __restrict__ w1a, const float* __restrict__ w1b,
                                 float* __restrict__ wt2c,
                                 short* __restrict__ b0a, short* __restrict__ b0b,
                                 short* __restrict__ b1a, short* __restrict__ b1b) {
  if (idx < 4096) { int d = idx >> 6, o = idx & 63; wt2c[idx] = conv2w[o*64 + d]; return; }
  idx -= 4096;
  const float* w; short* dst; int D;
  if      (idx <  2048) { w = w0a; dst = b0a; D = 128; }
  else if (idx <  4096) { w = w0b; dst = b0b; D = 128; idx -= 2048; }
  else if (idx < 12288) { w = w1a; dst = b1a; D = 256; idx -= 4096; }
  else                  { w = w1b; dst = b1b; D = 256; idx -= 12288; }
  int kblk = idx / D, o = idx % D;
  const float* src = w + (size_t)o*D + kblk*8;
  bhalf8 pk;
#pragma unroll
  for (int j = 0; j < 8; ++j) pk[j] = f2bf(src[j]);
  *(bhalf8*)&dst[(size_t)idx*8] = pk;
}

struct FpsSmem {
  float lx[4096], ly[4096], lz[4096];
  float sx[512], sy[512], sz[512];
  unsigned long long wk[2][8];
  int seli1[512];
  int seli2[256];
};
struct ConvSmem {
  float xs[3][64];
  float redS[4][64], redQ[4][64];
  float sc[64], sh[64];
  float at[64*68];
};

// ---------------- front: FPS (blocks 0-7) || prep+conv1+conv2+bn2fin (blocks 8-263) ----------------
// FPS blocks are fully independent. Conv blocks sync among THEMSELVES (256 blocks) via
// device-scope counter barriers; all cross-block conv data is the atomic stats. t1/t2
// tiles are block-self. 264 blocks x 58.5KB LDS => 2 blocks/CU => capacity 512 >= 264:
// co-residency has 2x margin (deadlock-safe).
__global__ __launch_bounds__(256) void front_kernel(
    const float* __restrict__ x,
    const float* __restrict__ conv1w, const float* __restrict__ bn1g, const float* __restrict__ bn1b,
    const float* __restrict__ conv2w, const float* __restrict__ bn2g, const float* __restrict__ bn2b,
    const float* __restrict__ w0a, const float* __restrict__ w0b,
    const float* __restrict__ w1a, const float* __restrict__ w1b,
    float* __restrict__ wt2c,
    short* __restrict__ b0a, short* __restrict__ b0b,
    short* __restrict__ b1a, short* __restrict__ b1b,
    float* __restrict__ t1, float* __restrict__ t2,
    float* __restrict__ stats, int* __restrict__ cnt,
    int* __restrict__ sel1, float* __restrict__ nxyz, int* __restrict__ sel2) {
  __shared__ __align__(16) char smem_raw[sizeof(FpsSmem)];
  int t = threadIdx.x;
  if (blockIdx.x < 8) {
    // ================= FPS path (round-6 proven logic) =================
    constexpr int NPTS = 4096, NSEL1 = 512, NSEL2 = 256, NT = 256;
    constexpr int K = NPTS / NT, NS = NT / 32;
    FpsSmem& S = *reinterpret_cast<FpsSmem*>(smem_raw);
    int b = blockIdx.x;
    int lane = t & 63, wid = t >> 6;
    const float* cb = x + (size_t)b * 3 * NPTS;
    for (int i = t; i < NPTS; i += NT) {
      S.lx[i] = cb[i]; S.ly[i] = cb[NPTS + i]; S.lz[i] = cb[2*NPTS + i];
    }
    __syncthreads();
    float px[K], py[K], pz[K], dm[K];
#pragma unroll
    for (int k = 0; k < K; ++k) {
      int p = t + k*NT;
      px[k] = S.lx[p]; py[k] = S.ly[p]; pz[k] = S.lz[p];
      dm[k] = 1e10f;
    }
    float cx = S.lx[0], cy = S.ly[0], cz = S.lz[0];
    if (t == 0) { S.seli1[0] = 0; S.sx[0] = cx; S.sy[0] = cy; S.sz[0] = cz; }
    for (int it = 1; it < NSEL1; ++it) {
      float bv = -1.f; int bi = 0;
#pragma unroll
      for (int k = 0; k < K; ++k) {
        float dx = px[k]-cx, dy = py[k]-cy, dz = pz[k]-cz;
        float d = dx*dx + dy*dy + dz*dz;
        float nd = fminf(dm[k], d);
        dm[k] = nd;
        if (nd > bv) { bv = nd; bi = t + k*NT; }
      }
      unsigned khi = __float_as_uint(bv), klo = ~(unsigned)bi;
      dpp_amax<0xB1>(khi, klo);
      dpp_amax<0x4E>(khi, klo);
      dpp_amax<0x141>(khi, klo);
      dpp_amax<0x140>(khi, klo);
      swz16_amax(khi, klo);
      int p = it & 1;
      if ((lane & 31) == 0)
        S.wk[p][wid*2 + (lane >> 5)] = ((unsigned long long)khi << 32) | klo;
      __syncthreads();
      unsigned long long best = S.wk[p][0];
#pragma unroll
      for (int i2 = 1; i2 < NS; ++i2) { unsigned long long v2 = S.wk[p][i2]; if (v2 > best) best = v2; }
      int Bi = (int)(~(unsigned)best);
      cx = S.lx[Bi]; cy = S.ly[Bi]; cz = S.lz[Bi];
      if (t == 0) { S.seli1[it] = Bi; S.sx[it] = cx; S.sy[it] = cy; S.sz[it] = cz; }
    }
    __syncthreads();
    if (t < 64) {
      constexpr int K2 = NSEL1 / 64;
      float qx[K2], qy[K2], qz[K2], dm2[K2];
#pragma unroll
      for (int k = 0; k < K2; ++k) {
        int p = t + k*64;
        qx[k] = S.sx[p]; qy[k] = S.sy[p]; qz[k] = S.sz[p];
        dm2[k] = 1e10f;
      }
      cx = S.sx[0]; cy = S.sy[0]; cz = S.sz[0];
      if (t == 0) S.seli2[0] = 0;
      for (int it = 1; it < NSEL2; ++it) {
        float bv = -1.f; int bi = 0;
#pragma unroll
        for (int k = 0; k < K2; ++k) {
          float dx = qx[k]-cx, dy = qy[k]-cy, dz = qz[k]-cz;
          float d = dx*dx + dy*dy + dz*dz;
          float nd = fminf(dm2[k], d);
          dm2[k] = nd;
          if (nd > bv) { bv = nd; bi = t + k*64; }
        }
        unsigned khi = __float_as_uint(bv), klo = ~(unsigned)bi;
        dpp_amax<0xB1>(khi, klo);
        dpp_amax<0x4E>(khi, klo);
        dpp_amax<0x141>(khi, klo);
        dpp_amax<0x140>(khi, klo);
        swz16_amax(khi, klo);
        x32_amax(khi, klo);
        int Bi = (int)~klo;
        cx = S.sx[Bi]; cy = S.sy[Bi]; cz = S.sz[Bi];
        if (t == 0) S.seli2[it] = Bi;
      }
    } else {
      for (int i = t - 64; i < NSEL1; i += NT - 64) {
        sel1[(size_t)b*NSEL1 + i] = S.seli1[i];
        float* q = nxyz + ((size_t)b*NSEL1 + i)*3;
        q[0] = S.sx[i]; q[1] = S.sy[i]; q[2] = S.sz[i];
      }
    }
    __syncthreads();
    for (int i = t; i < NSEL2; i += NT) sel2[(size_t)b*NSEL2 + i] = S.seli2[i];
    return;
  }
  // ================= conv path =================
  ConvSmem& C = *reinterpret_cast<ConvSmem*>(smem_raw);
  int cb = blockIdx.x - 8;   // 0..255
  // prep (first 96 blocks' worth of tasks)
  { int idx = cb*256 + t;
    if (idx < 24576) prep_elem(idx, conv2w, w0a, w0b, w1a, w1b, wt2c, b0a, b0b, b1a, b1b); }
  // conv1: two tiles per block
  for (int tile = cb; tile < 512; tile += 256) {
    int b = tile >> 6, n0 = (tile & 63) << 6;
    if (t < 192) { int c = t >> 6, nl = t & 63; C.xs[c][nl] = x[((size_t)b*3 + c)*N_ + n0 + nl]; }
    __syncthreads();
    int o = t & 63, ng = t >> 6;
    float w0 = conv1w[o*3+0], w1 = conv1w[o*3+1], w2 = conv1w[o*3+2];
    float ls = 0.f, lq = 0.f;
#pragma unroll
    for (int k = 0; k < 16; ++k) {
      int nl = ng*16 + k;
      float y = C.xs[0][nl]*w0 + C.xs[1][nl]*w1 + C.xs[2][nl]*w2;
      t1[((size_t)b*N_ + n0 + nl)*64 + o] = y;
      ls += y; lq += y*y;
    }
    C.redS[ng][o] = ls; C.redQ[ng][o] = lq;
    __syncthreads();
    if (t < 64) {
      float s = C.redS[0][t]+C.redS[1][t]+C.redS[2][t]+C.redS[3][t];
      float q = C.redQ[0][t]+C.redQ[1][t]+C.redQ[2][t]+C.redQ[3][t];
      atomicAdd(&stats[S_BN1 + t], s);
      atomicAdd(&stats[S_BN1 + 64 + t], q);
    }
    __syncthreads();
  }
  // barrier A among 256 conv blocks
  if (t == 0) {
    __threadfence();
    __hip_atomic_fetch_add(&cnt[0], 1, __ATOMIC_ACQ_REL, __HIP_MEMORY_SCOPE_AGENT);
    while (__hip_atomic_load(&cnt[0], __ATOMIC_ACQUIRE, __HIP_MEMORY_SCOPE_AGENT) < 256)
      __builtin_amdgcn_s_sleep(8);
    __threadfence();
  }
  __syncthreads();
  // conv2: bn1 scale/shift once, then two tiles
  if (t < 64) {
    float m = stats[S_BN1 + t] * (1.f/32768.f);
    float v = stats[S_BN1 + 64 + t] * (1.f/32768.f) - m*m;
    float s = bn1g[t] * rsqrtf(v + EPS_);
    C.sc[t] = s; C.sh[t] = bn1b[t] - m*s;
  }
  __syncthreads();
  for (int tile = cb; tile < 512; tile += 256) {
    int b = tile >> 6, n0 = (tile & 63) << 6;
    constexpr int P = 68;
    for (int e = t; e < 4096; e += 256) {
      int nl = e >> 6, c = e & 63;
      float v = t1[((size_t)b*N_ + n0 + nl)*64 + c];
      C.at[c*P + nl] = fmaxf(v*C.sc[c] + C.sh[c], 0.f);
    }
    __syncthreads();
    int o = t & 63, ng = t >> 6;
    float acc[16];
#pragma unroll
    for (int k = 0; k < 16; ++k) acc[k] = 0.f;
    for (int i = 0; i < 64; ++i) {
      float wv = wt2c[i*64 + o];
      const float* ar = &C.at[i*P + ng*16];
#pragma unroll
      for (int k = 0; k < 16; k += 4) {
        float4 a4 = *(const float4*)(ar + k);
        acc[k+0] += a4.x*wv; acc[k+1] += a4.y*wv;
        acc[k+2] += a4.z*wv; acc[k+3] += a4.w*wv;
      }
    }
    float ls = 0.f, lq = 0.f;
#pragma unroll
    for (int k = 0; k < 16; ++k) {
      float y = acc[k];
      t2[((size_t)b*N_ + n0 + ng*16 + k)*64 + o] = y;
      ls += y; lq += y*y;
    }
    C.redS[ng][o] = ls; C.redQ[ng][o] = lq;
    __syncthreads();
    if (t < 64) {
      float s = C.redS[0][t]+C.redS[1][t]+C.redS[2][t]+C.redS[3][t];
      float q = C.redQ[0][t]+C.redQ[1][t]+C.redQ[2][t]+C.redQ[3][t];
      atomicAdd(&stats[S_BN2 + t], s);
      atomicAdd(&stats[S_BN2 + 64 + t], q);
    }
    __syncthreads();
  }
  // barrier B
  if (t == 0) {
    __threadfence();
    __hip_atomic_fetch_add(&cnt[1], 1, __ATOMIC_ACQ_REL, __HIP_MEMORY_SCOPE_AGENT);
    while (__hip_atomic_load(&cnt[1], __ATOMIC_ACQUIRE, __HIP_MEMORY_SCOPE_AGENT) < 256)
      __builtin_amdgcn_s_sleep(8);
    __threadfence();
  }
  __syncthreads();
  // bn2 finalize + relu -> pts (into t1), self tiles only
  {
    int o = t & 63;
    float m = stats[S_BN2 + o] * (1.f/32768.f);
    float v = stats[S_BN2 + 64 + o] * (1.f/32768.f) - m*m;
    float s = bn2g[o] * rsqrtf(v + EPS_);
    float sh = bn2b[o] - m*s;
    for (int tile = cb; tile < 512; tile += 256)
#pragma unroll
      for (int j = 0; j < 16; ++j) {
        size_t idx = (size_t)tile*4096 + j*256 + t;
        t1[idx] = fmaxf(t2[idx]*s + sh, 0.f);
      }
  }
}

// ---------------- kNN: register-resident d2, FPS-style packed-key argmin ----------------
template<int NDST, int NQ, int NT, bool XLAY>
__global__ __launch_bounds__(NT) void knn_kernel(
    const float* __restrict__ dst, const float* __restrict__ nxyz,
    const int* __restrict__ qmap, int* __restrict__ knn_out) {
  constexpr int K  = NDST / NT;
  constexpr int NS = NT / 32;
  __shared__ unsigned long long wk[2][NS];
  __shared__ int kos[32];
  int blk = blockIdx.x, t = threadIdx.x;
  int b = blk / NQ, q = blk % NQ;
  int qrow = b*NP1 + (qmap ? qmap[b*NQ + q] : q);
  float qx = nxyz[qrow*3+0], qy = nxyz[qrow*3+1], qz = nxyz[qrow*3+2];
  float q2 = (qx*qx + qy*qy) + qz*qz;
  const float* db = dst + (size_t)b * (XLAY ? 3*NDST : NDST*3);
  float d2r[K];
#pragma unroll
  for (int k = 0; k < K; ++k) {
    int j = t + k*NT;
    float xx, yy, zz;
    if (XLAY) { xx = db[j]; yy = db[NDST + j]; zz = db[2*NDST + j]; }
    else      { xx = db[j*3]; yy = db[j*3+1]; zz = db[j*3+2]; }
    float dot = (qx*xx + qy*yy) + qz*zz;
    float p2  = (xx*xx + yy*yy) + zz*zz;
    d2r[k] = (q2 - 2.f*dot) + p2;
  }
  for (int r = 0; r < 32; ++r) {
    float bv = 3e38f; int bi = t;
#pragma unroll
    for (int k = 0; k < K; ++k) {
      float v = d2r[k];
      if (v < bv) { bv = v; bi = t + k*NT; }
    }
    unsigned khi = ~ford(bv), klo = ~(unsigned)bi;
    dpp_amax<0xB1>(khi, klo);
    dpp_amax<0x4E>(khi, klo);
    dpp_amax<0x141>(khi, klo);
    dpp_amax<0x140>(khi, klo);
    swz16_amax(khi, klo);
    int p = r & 1;
    if ((t & 31) == 0)
      wk[p][t >> 5] = ((unsigned long long)khi << 32) | klo;
    __syncthreads();
    unsigned long long best = wk[p][0];
#pragma unroll
    for (int i2 = 1; i2 < NS; ++i2) { unsigned long long v2 = wk[p][i2]; if (v2 > best) best = v2; }
    int Bi = (int)(~(unsigned)best);
    if (t == 0) kos[r] = Bi;
#pragma unroll
    for (int k = 0; k < K; ++k)
      if (t + k*NT == Bi) d2r[k] = 3e38f;
  }
  __syncthreads();
  if (t < 32) knn_out[((size_t)b*NQ + q)*32 + t] = kos[t];
}

// ---------------- GEMM1: gather(+center-sub) -> bf16 MFMA -> y + stats ----------------
template<int D, int PW, int NP, int SRCN, int SOFF>
__global__ __launch_bounds__(256) void gemm1_kernel(
    const float* __restrict__ pts, const int* __restrict__ knn,
    const int* __restrict__ cent, const short* __restrict__ bw,
    float* __restrict__ ybuf, float* __restrict__ stats) {
  constexpr int KB = D/8;
  __shared__ __align__(16) short As[64*D];
  __shared__ float cen_s[2*PW];
  __shared__ int kid_s[64];
  __shared__ float sstat[2*D];
  int t = threadIdx.x, blk = blockIdx.x;
  int g0 = blk*2;
  if (t < 64) {
    int grp = t >> 5, s = t & 31;
    kid_s[t] = knn[((size_t)(g0+grp))*32 + s];
  }
  for (int i = t; i < 2*PW; i += 256) {
    int grp = i / PW, d = i % PW;
    int g = g0 + grp; int b = g / NP; int ci = cent[g];
    cen_s[i] = pts[((size_t)b*SRCN + ci)*PW + d];
  }
  for (int i = t; i < 2*D; i += 256) sstat[i] = 0.f;
  __syncthreads();
  for (int task = t; task < 64*KB; task += 256) {
    int row = task / KB, c = task % KB;
    int grp = row >> 5;
    int g = g0 + grp; int b = g / NP;
    int d = c*8;
    float v0,v1,v2,v3,v4,v5,v6,v7;
    if (d < PW) {
      const float* src = pts + ((size_t)b*SRCN + kid_s[row])*PW + d;
      float4 x0 = *(const float4*)src, x1 = *(const float4*)(src+4);
      const float* cc = &cen_s[grp*PW + d];
      v0=x0.x-cc[0]; v1=x0.y-cc[1]; v2=x0.z-cc[2]; v3=x0.w-cc[3];
      v4=x1.x-cc[4]; v5=x1.y-cc[5]; v6=x1.z-cc[6]; v7=x1.w-cc[7];
    } else {
      const float* cc = &cen_s[grp*PW + d - PW];
      v0=cc[0]; v1=cc[1]; v2=cc[2]; v3=cc[3]; v4=cc[4]; v5=cc[5]; v6=cc[6]; v7=cc[7];
    }
    bhalf8 pk;
    pk[0]=f2bf(v0); pk[1]=f2bf(v1); pk[2]=f2bf(v2); pk[3]=f2bf(v3);
    pk[4]=f2bf(v4); pk[5]=f2bf(v5); pk[6]=f2bf(v6); pk[7]=f2bf(v7);
    int a16 = row*KB + (c ^ (row & 7));
    *(bhalf8*)&As[a16*8] = pk;
  }
  __syncthreads();
  int w = t >> 6, l = t & 63, lr = l & 15, lg = l >> 4;
  f32x4 acc[D/16];
#pragma unroll
  for (int ct = 0; ct < D/16; ++ct) acc[ct] = (f32x4){0.f,0.f,0.f,0.f};
  int r = w*16 + lr;
#pragma unroll
  for (int kg = 0; kg < D/32; ++kg) {
    int c = (kg*4 + lg) ^ (r & 7);
    bhalf8 af = *(const bhalf8*)&As[(r*KB + c)*8];
#pragma unroll
    for (int ct = 0; ct < D/16; ++ct) {
      bhalf8 bf = *(const bhalf8*)&bw[((size_t)(kg*4 + lg)*D + ct*16 + lr)*8];
      acc[ct] = __builtin_amdgcn_mfma_f32_16x16x32_bf16(af, bf, acc[ct], 0, 0, 0);
    }
  }
  size_t rb = (size_t)blk*64 + w*16 + lg*4;
#pragma unroll
  for (int ct = 0; ct < D/16; ++ct) {
    int col = ct*16 + lr;
    f32x4 a = acc[ct];
    float* yp = ybuf + rb*D + col;
    yp[0] = a[0]; yp[(size_t)D] = a[1]; yp[(size_t)2*D] = a[2]; yp[(size_t)3*D] = a[3];
    float s = a[0]+a[1]+a[2]+a[3];
    float q = a[0]*a[0]+a[1]*a[1]+a[2]*a[2]+a[3]*a[3];
    s += __shfl_xor(s, 16); q += __shfl_xor(q, 16);
    s += __shfl_xor(s, 32); q += __shfl_xor(q, 32);
    if (lg == 0) { atomicAdd(&sstat[col], s); atomicAdd(&sstat[D+col], q); }
  }
  __syncthreads();
  for (int i = t; i < 2*D; i += 256) atomicAdd(&stats[SOFF+i], sstat[i]);
}

// ---------------- GEMM2: bn+relu on the fly -> bf16 MFMA -> per-group max/min + stats ----------------
template<int D, int SIN, int SOUT, int CNT>
__global__ __launch_bounds__(256) void gemm2_kernel(
    const float* __restrict__ g1, const float* __restrict__ b1,
    const short* __restrict__ bw, const float* __restrict__ ybuf,
    float* __restrict__ mm, float* __restrict__ stats) {
  __shared__ __align__(16) float scsh[2*D];
  __shared__ float sstat[2*D];
  __shared__ float wmax[4][D], wmin[4][D];
  int t = threadIdx.x, blk = blockIdx.x;
  for (int i = t; i < D; i += 256) {
    float m = stats[SIN + i] * (1.f/(float)CNT);
    float v = stats[SIN + D + i] * (1.f/(float)CNT) - m*m;
    float s = g1[i] * rsqrtf(v + EPS_);
    scsh[i] = s; scsh[D+i] = b1[i] - m*s;
  }
  for (int i = t; i < 2*D; i += 256) sstat[i] = 0.f;
  __syncthreads();
  int w = t >> 6, l = t & 63, lr = l & 15, lg = l >> 4;
  size_t row = (size_t)blk*64 + w*16 + lr;
  const float* yrow = ybuf + row*D;
  f32x4 acc[D/16];
#pragma unroll
  for (int ct = 0; ct < D/16; ++ct) acc[ct] = (f32x4){0.f,0.f,0.f,0.f};
#pragma unroll
  for (int kg = 0; kg < D/32; ++kg) {
    int k = kg*32 + lg*8;
    float4 y0 = *(const float4*)(yrow + k);
    float4 y1 = *(const float4*)(yrow + k + 4);
    bhalf8 af;
    af[0] = f2bf(fmaxf(y0.x*scsh[k+0] + scsh[D+k+0], 0.f));
    af[1] = f2bf(fmaxf(y0.y*scsh[k+1] + scsh[D+k+1], 0.f));
    af[2] = f2bf(fmaxf(y0.z*scsh[k+2] + scsh[D+k+2], 0.f));
    af[3] = f2bf(fmaxf(y0.w*scsh[k+3] + scsh[D+k+3], 0.f));
    af[4] = f2bf(fmaxf(y1.x*scsh[k+4] + scsh[D+k+4], 0.f));
    af[5] = f2bf(fmaxf(y1.y*scsh[k+5] + scsh[D+k+5], 0.f));
    af[6] = f2bf(fmaxf(y1.z*scsh[k+6] + scsh[D+k+6], 0.f));
    af[7] = f2bf(fmaxf(y1.w*scsh[k+7] + scsh[D+k+7], 0.f));
#pragma unroll
    for (int ct = 0; ct < D/16; ++ct) {
      bhalf8 bf = *(const bhalf8*)&bw[((size_t)(kg*4 + lg)*D + ct*16 + lr)*8];
      acc[ct] = __builtin_amdgcn_mfma_f32_16x16x32_bf16(af, bf, acc[ct], 0, 0, 0);
    }
  }
#pragma unroll
  for (int ct = 0; ct < D/16; ++ct) {
    int col = ct*16 + lr;
    f32x4 a = acc[ct];
    float mx = fmaxf(fmaxf(a[0], a[1]), fmaxf(a[2], a[3]));
    float mn = fminf(fminf(a[0], a[1]), fminf(a[2], a[3]));
    mx = fmaxf(mx, __shfl_xor(mx, 16)); mn = fminf(mn, __shfl_xor(mn, 16));
    mx = fmaxf(mx, __shfl_xor(mx, 32)); mn = fminf(mn, __shfl_xor(mn, 32));
    if (lg == 0) { wmax[w][col] = mx; wmin[w][col] = mn; }
    float s = a[0]+a[1]+a[2]+a[3];
    float q = a[0]*a[0]+a[1]*a[1]+a[2]*a[2]+a[3]*a[3];
    s += __shfl_xor(s, 16); q += __shfl_xor(q, 16);
    s += __shfl_xor(s, 32); q += __shfl_xor(q, 32);
    if (lg == 0) { atomicAdd(&sstat[col], s); atomicAdd(&sstat[D+col], q); }
  }
  __syncthreads();
  for (int i = t; i < 2*D; i += 256) {
    int g = i / D, col = i - g*D;
    float mx = fmaxf(wmax[2*g][col], wmax[2*g+1][col]);
    float mn = fminf(wmin[2*g][col], wmin[2*g+1][col]);
    float* mp = mm + ((size_t)blk*2 + g)*2*D;
    mp[col] = mx; mp[D + col] = mn;
    atomicAdd(&stats[SOUT+i], sstat[i]);
  }
}

// ---------------- finish: bn2 + relu applied to per-group max/min (exact, elementwise) ----------------
template<int D, int NP, int SOFF, int CNT, bool TR>
__global__ __launch_bounds__(256) void le3_kernel(
    const float* __restrict__ g2, const float* __restrict__ b2,
    const float* __restrict__ mm, const float* __restrict__ stats,
    float* __restrict__ out) {
  int idx = blockIdx.x*256 + threadIdx.x;
  int g = idx / D, o = idx - g*D;
  float m = stats[SOFF + o] * (1.f/(float)CNT);
  float v = stats[SOFF + D + o] * (1.f/(float)CNT) - m*m;
  float s = g2[o] * rsqrtf(v + EPS_);
  float sh = b2[o] - m*s;
  const float* mp = mm + (size_t)g*2*D;
  float pick = (s >= 0.f) ? mp[o] : mp[D + o];
  float r = fmaxf(pick*s + sh, 0.f);
  if (TR) { int b = g / NP, n = g - b*NP; out[((size_t)b*D + o)*NP + n] = r; }
  else    out[(size_t)g*D + o] = r;
}

// ---------------- host ----------------
extern "C" void kernel_launch(void* const* d_in, const int* in_sizes, int n_in,
                              void* d_out, int out_size, void* d_ws, size_t ws_size,
                              hipStream_t stream) {
  (void)in_sizes; (void)n_in; (void)out_size; (void)ws_size;
  const float* x       = (const float*)d_in[0];
  const float* conv1_w = (const float*)d_in[1];
  const float* bn1_g   = (const float*)d_in[2];
  const float* bn1_b   = (const float*)d_in[3];
  const float* conv2_w = (const float*)d_in[4];
  const float* bn2_g   = (const float*)d_in[5];
  const float* bn2_b   = (const float*)d_in[6];
  const float* le0_w1  = (const float*)d_in[7];
  const float* le0_g1  = (const float*)d_in[8];
  const float* le0_b1  = (const float*)d_in[9];
  const float* le0_w2  = (const float*)d_in[10];
  const float* le0_g2  = (const float*)d_in[11];
  const float* le0_b2  = (const float*)d_in[12];
  const float* le1_w1  = (const float*)d_in[13];
  const float* le1_g1  = (const float*)d_in[14];
  const float* le1_b1  = (const float*)d_in[15];
  const float* le1_w2  = (const float*)d_in[16];
  const float* le1_g2  = (const float*)d_in[17];
  const float* le1_b2  = (const float*)d_in[18];

  float* ws   = (float*)d_ws;
  float* t1   = ws + OFF_T1;      // conv1 out; then 'pts'; later mm buffer
  float* ybuf = ws + OFF_YBUF;    // LE y1 buffer; t2 aliases its start
  float* t2   = ybuf;
  float* mm   = t1;
  float* pts1 = ws + OFF_PTS1;
  float* nxyz = ws + OFF_NXYZ;
  float* wt2c = ws + OFF_WT2C;
  short* bw0a = (short*)(ws + OFF_BW0A);
  short* bw0b = (short*)(ws + OFF_BW0B);
  short* bw1a = (short*)(ws + OFF_BW1A);
  short* bw1b = (short*)(ws + OFF_BW1B);
  float* stats = ws + OFF_STAT;
  int*   cnt   = (int*)(ws + OFF_CNT);
  int* fps1 = (int*)(ws + OFF_INT);
  int* fps2 = fps1 + 4096;
  int* knn1 = fps2 + 2048;
  int* knn2 = knn1 + 131072;

  // zero stats + barrier counters (captured; re-zeroed on every replay)
  hipMemsetAsync(stats, 0, (S_TOTAL + 16)*sizeof(float), stream);
  front_kernel<<<264, 256, 0, stream>>>(x,
      conv1_w, bn1_g, bn1_b, conv2_w, bn2_g, bn2_b,
      le0_w1, le0_w2, le1_w1, le1_w2,
      wt2c, bw0a, bw0b, bw1a, bw1b,
      t1, t2, stats, cnt, fps1, nxyz, fps2);

  knn_kernel<4096, 512, 256, true ><<<4096, 256, 0, stream>>>(x, nxyz, nullptr, knn1);
  knn_kernel< 512, 256, 256, false><<<2048, 256, 0, stream>>>(nxyz, nxyz, fps2, knn2);

  gemm1_kernel<128,  64, 512, 4096, S_L0A><<<2048, 256, 0, stream>>>(t1, knn1, fps1, bw0a, ybuf, stats);
  gemm2_kernel<128, S_L0A, S_L0B, 131072><<<2048, 256, 0, stream>>>(le0_g1, le0_b1, bw0b, ybuf, mm, stats);
  le3_kernel<128, 512, S_L0B, 131072, false><<<2048, 256, 0, stream>>>(le0_g2, le0_b2, mm, stats, pts1);

  gemm1_kernel<256, 128, 256,  512, S_L1A><<<1024, 256, 0, stream>>>(pts1, knn2, fps2, bw1a, ybuf, stats);
  gemm2_kernel<256, S_L1A, S_L1B, 65536><<<1024, 256, 0, stream>>>(le1_g1, le1_b1, bw1b, ybuf, mm, stats);
  le3_kernel<256, 256, S_L1B, 65536, true><<<2048, 256, 0, stream>>>(le1_g2, le1_b2, mm, stats, (float*)d_out);
}